// Round 4
// baseline (893.310 us; speedup 1.0000x reference)
//
#include <hip/hip_runtime.h>

typedef unsigned short u16;
typedef unsigned int   u32;
typedef __attribute__((ext_vector_type(8))) short bf16x8;
typedef __attribute__((ext_vector_type(4))) float f32x4;
typedef __attribute__((ext_vector_type(4))) u32   u32x4;

// Problem constants
constexpr int Bc = 2, Cc = 512, Nc = 2048, Mc = 512, Sc = 2560, Kc = 16, PH = 64, AH = 1024;
constexpr int RT = Bc * Nc * Kc;  // 65536 rows (b,n,k)
constexpr float EPS = 1e-5f;

__device__ __forceinline__ u16 f2bf(float f) {
    u32 u = __float_as_uint(f);
    u32 r = (u + 0x7fffu + ((u >> 16) & 1u)) >> 16;  // RNE
    return (u16)r;
}
__device__ __forceinline__ float bf2f(u16 h) { return __uint_as_float(((u32)h) << 16); }

__device__ __forceinline__ void gload_lds16(const void* g, void* l) {
    __builtin_amdgcn_global_load_lds((const __attribute__((address_space(1))) u32*)g,
                                     (__attribute__((address_space(3))) u32*)l, 16, 0, 0);
}

// ---------------------------------------------------------------------------
// Transpose fusion_feat [B,C,S(split)] f32 -> featT [B,S,C] f32
// ---------------------------------------------------------------------------
__global__ __launch_bounds__(256) void transpose_kernel(const float* __restrict__ feat,
                                                        const float* __restrict__ feat_db,
                                                        float* __restrict__ featT) {
    __shared__ float tile[64][65];
    int bid = blockIdx.x;
    int b = bid / (40 * 8);
    int rem = bid - b * (40 * 8);
    int st = rem >> 3, ct = rem & 7;
    int t = threadIdx.x, lane = t & 63, g = t >> 6;
    int s0 = st * 64, c0 = ct * 64;
    const float* src;
    int sl0, stride;
    if (s0 < Nc) { src = feat + (size_t)b * Cc * Nc; sl0 = s0; stride = Nc; }
    else         { src = feat_db + (size_t)b * Cc * Mc; sl0 = s0 - Nc; stride = Mc; }
#pragma unroll
    for (int i = 0; i < 16; i++) {
        int cl = g * 16 + i;
        tile[cl][lane] = src[(size_t)(c0 + cl) * stride + sl0 + lane];
    }
    __syncthreads();
#pragma unroll
    for (int i = 0; i < 16; i++) {
        int sl = g * 16 + i;
        featT[((size_t)b * Sc + s0 + sl) * Cc + c0 + lane] = tile[lane][sl];
    }
}

// ---------------------------------------------------------------------------
// Weight prep: fold attn BN into W1/bias1, cast W1,W2 to bf16
// ---------------------------------------------------------------------------
__global__ __launch_bounds__(256) void prep_kernel(const float* __restrict__ aw1, const float* __restrict__ ab1,
                                                   const float* __restrict__ ag, const float* __restrict__ abb,
                                                   const float* __restrict__ am, const float* __restrict__ av,
                                                   const float* __restrict__ aw2,
                                                   u16* __restrict__ W1b, float* __restrict__ bias1,
                                                   u16* __restrict__ W2b) {
    int i = blockIdx.x * 256 + threadIdx.x;  // grid covers 524288
    if (i < AH * Cc) {
        int o = i >> 9;
        float inv = ag[o] / sqrtf(av[o] + EPS);
        W1b[i] = f2bf(aw1[i] * inv);
    }
    if (i < AH) {
        float inv = ag[i] / sqrtf(av[i] + EPS);
        bias1[i] = ab1[i] * inv + abb[i] - am[i] * inv;
    }
    if (i < Cc * AH) W2b[i] = f2bf(aw2[i]);
}

// ---------------------------------------------------------------------------
// KNN: one wave per query; distances mirror the reference decomposition
// qq + ss - 2*dot with no fma contraction; ties -> smaller index (top_k).
// ---------------------------------------------------------------------------
__global__ __launch_bounds__(256) void knn_kernel(const float* __restrict__ pcd,
                                                  const float* __restrict__ pcd_db,
                                                  int* __restrict__ idxout) {
    int t = threadIdx.x, w = t >> 6, l = t & 63;
    int q = blockIdx.x * 4 + w;  // 0..4095
    int b = q >> 11, n = q & (Nc - 1);
    const float* pc = pcd + (size_t)b * 3 * Nc;
    const float* pd = pcd_db + (size_t)b * 3 * Mc;
    float qx = pc[n], qy = pc[Nc + n], qz = pc[2 * Nc + n];
    float qq = __fadd_rn(__fadd_rn(__fmul_rn(qx, qx), __fmul_rn(qy, qy)), __fmul_rn(qz, qz));
    float dist[40];
#pragma unroll
    for (int j = 0; j < 40; j++) {
        int s = j * 64 + l;
        float sx, sy, sz;
        if (s < Nc) { sx = pc[s]; sy = pc[Nc + s]; sz = pc[2 * Nc + s]; }
        else { int ss = s - Nc; sx = pd[ss]; sy = pd[Mc + ss]; sz = pd[2 * Mc + ss]; }
        float ss2 = __fadd_rn(__fadd_rn(__fmul_rn(sx, sx), __fmul_rn(sy, sy)), __fmul_rn(sz, sz));
        float dt  = __fadd_rn(__fadd_rn(__fmul_rn(qx, sx), __fmul_rn(qy, sy)), __fmul_rn(qz, sz));
        dist[j] = __fsub_rn(__fadd_rn(qq, ss2), __fmul_rn(2.0f, dt));
    }
    for (int r = 0; r < 16; r++) {
        float bd = 1e30f;
        int bs = 1 << 30;
#pragma unroll
        for (int j = 0; j < 40; j++) {
            int s = j * 64 + l;
            bool better = (dist[j] < bd) || (dist[j] == bd && s < bs);
            bd = better ? dist[j] : bd;
            bs = better ? s : bs;
        }
        for (int off = 32; off; off >>= 1) {
            float od = __shfl_xor(bd, off);
            int   os = __shfl_xor(bs, off);
            bool better = (od < bd) || (od == bd && os < bs);
            bd = better ? od : bd;
            bs = better ? os : bs;
        }
        if (l == 0) idxout[q * 16 + r] = bs;
        int wj = bs >> 6, wl = bs & 63;
        if (l == wl) {
#pragma unroll
            for (int j = 0; j < 40; j++)
                if (j == wj) dist[j] = 1e30f;
        }
    }
}

// ---------------------------------------------------------------------------
// BUILD: per row (b,n,k): pos-MLP -> p[512]; X = f-g+p (bf16), V = g+p (bf16)
// W2(pos) staged in LDS bf16 with 16B-chunk XOR swizzle (bank-conflict fix).
// ---------------------------------------------------------------------------
__global__ __launch_bounds__(256) void build_kernel(
    const float* __restrict__ featT, const int* __restrict__ idxb,
    const float* __restrict__ pcd, const float* __restrict__ pcd_db,
    const float* __restrict__ pw1, const float* __restrict__ pb1,
    const float* __restrict__ pg, const float* __restrict__ pbb,
    const float* __restrict__ pm, const float* __restrict__ pv,
    const float* __restrict__ pw2, const float* __restrict__ pb2,
    u16* __restrict__ X, u16* __restrict__ V, int row0) {
    __shared__ u16 W2s[512 * 64];
    __shared__ float hbuf[4][64];
    const int t = threadIdx.x, w = t >> 6, l = t & 63;

    // stage pos_w2 [512][64] f32 -> LDS bf16, chunk-swizzled
#pragma unroll
    for (int i = 0; i < 16; i++) {
        int e = (i * 256 + t) * 8;  // elem offset, multiple of 8, rows of 64
        int c = e >> 6;
        int t16 = (e & 63) >> 3;
        float4 a = *(const float4*)(pw2 + e);
        float4 b = *(const float4*)(pw2 + e + 4);
        u32x4 pk;
        pk.x = (u32)f2bf(a.x) | ((u32)f2bf(a.y) << 16);
        pk.y = (u32)f2bf(a.z) | ((u32)f2bf(a.w) << 16);
        pk.z = (u32)f2bf(b.x) | ((u32)f2bf(b.y) << 16);
        pk.w = (u32)f2bf(b.z) | ((u32)f2bf(b.w) << 16);
        int sw = t16 ^ ((c >> 3) & 7);
        *(u32x4*)&W2s[c * 64 + sw * 8] = pk;
    }
    // fold pos BN into per-lane W1 row (lane l owns hidden unit l)
    float inv = pg[l] / sqrtf(pv[l] + EPS);
    float w1x = pw1[l * 3 + 0] * inv, w1y = pw1[l * 3 + 1] * inv, w1z = pw1[l * 3 + 2] * inv;
    float b1c = pb1[l] * inv + pbb[l] - pm[l] * inv;
    __syncthreads();

#pragma unroll 1
    for (int i = 0; i < 4; i++) {
        int lr = blockIdx.x * 16 + w * 4 + i;  // chunk-local row
        int r = row0 + lr;                     // global row
        int b = r >> 15;
        int n = (r >> 4) & (Nc - 1);
        int s = idxb[r];
        const float* pc = pcd + (size_t)b * 3 * Nc;
        float qx = pc[n], qy = pc[Nc + n], qz = pc[2 * Nc + n];
        float sx, sy, sz;
        if (s < Nc) { sx = pc[s]; sy = pc[Nc + s]; sz = pc[2 * Nc + s]; }
        else {
            const float* pd = pcd_db + (size_t)b * 3 * Mc;
            int ss = s - Nc;
            sx = pd[ss]; sy = pd[Mc + ss]; sz = pd[2 * Mc + ss];
        }
        float h = fmaxf(0.f, w1x * (qx - sx) + w1y * (qy - sy) + w1z * (qz - sz) + b1c);
        hbuf[w][l] = h;  // wave-local, in-order LDS: no barrier needed

        const float* frow = featT + ((size_t)b * Sc + n) * Cc + l * 8;
        const float* grow = featT + ((size_t)b * Sc + s) * Cc + l * 8;
        float4 fa = *(const float4*)frow, fb = *(const float4*)(frow + 4);
        float4 ga = *(const float4*)grow, gb = *(const float4*)(grow + 4);
        float4 pa = *(const float4*)(pb2 + l * 8), pbv = *(const float4*)(pb2 + l * 8 + 4);
        float p[8] = {pa.x, pa.y, pa.z, pa.w, pbv.x, pbv.y, pbv.z, pbv.w};
#pragma unroll
        for (int t16 = 0; t16 < 8; t16++) {
            float4 h0 = *(const float4*)&hbuf[w][t16 * 8];
            float4 h1 = *(const float4*)&hbuf[w][t16 * 8 + 4];
            int sw = t16 ^ (l & 7);
#pragma unroll
            for (int j = 0; j < 8; j++) {
                u32x4 wv = *(const u32x4*)&W2s[(l * 8 + j) * 64 + sw * 8];
                p[j] += __uint_as_float(wv.x << 16) * h0.x + __uint_as_float(wv.x & 0xffff0000u) * h0.y
                      + __uint_as_float(wv.y << 16) * h0.z + __uint_as_float(wv.y & 0xffff0000u) * h0.w
                      + __uint_as_float(wv.z << 16) * h1.x + __uint_as_float(wv.z & 0xffff0000u) * h1.y
                      + __uint_as_float(wv.w << 16) * h1.z + __uint_as_float(wv.w & 0xffff0000u) * h1.w;
            }
        }
        float fv[8] = {fa.x, fa.y, fa.z, fa.w, fb.x, fb.y, fb.z, fb.w};
        float gv[8] = {ga.x, ga.y, ga.z, ga.w, gb.x, gb.y, gb.z, gb.w};
        u32x4 xp, vp;
        u16 xe[8], ve[8];
#pragma unroll
        for (int j = 0; j < 8; j++) {
            xe[j] = f2bf(fv[j] - gv[j] + p[j]);
            ve[j] = f2bf(gv[j] + p[j]);
        }
        xp.x = (u32)xe[0] | ((u32)xe[1] << 16); xp.y = (u32)xe[2] | ((u32)xe[3] << 16);
        xp.z = (u32)xe[4] | ((u32)xe[5] << 16); xp.w = (u32)xe[6] | ((u32)xe[7] << 16);
        vp.x = (u32)ve[0] | ((u32)ve[1] << 16); vp.y = (u32)ve[2] | ((u32)ve[3] << 16);
        vp.z = (u32)ve[4] | ((u32)ve[5] << 16); vp.w = (u32)ve[6] | ((u32)ve[7] << 16);
        *(u32x4*)(X + (size_t)lr * Cc + l * 8) = xp;
        *(u32x4*)(V + (size_t)lr * Cc + l * 8) = vp;
    }
}

// ---------------------------------------------------------------------------
// GEMM (m97 structure): C[m][n] = f(sum_k A[m][k]*B[n][k] + bias[n])
// A [M][Kd] bf16, B [N][Kd] bf16 (i.e. B^T layout), 128x128 tile, BK=64.
// ---------------------------------------------------------------------------
template <bool RELU, bool OBF16>
__global__ __launch_bounds__(256) void gemm_bt(const u16* __restrict__ Ag, const u16* __restrict__ Bg,
                                               const float* __restrict__ bias, void* __restrict__ Cg,
                                               int M, int N, int Kd) {
    __shared__ u16 As[128 * 64];
    __shared__ u16 Bs[128 * 64];
    const int t = threadIdx.x;
    const int bm = blockIdx.x, bn = blockIdx.y;
    const int w = t >> 6, l = t & 63;
    const int wr = w >> 1, wc = w & 1;
    const int fr = l & 15, fq = l >> 4;
    f32x4 acc[4][4];
#pragma unroll
    for (int i = 0; i < 4; i++)
#pragma unroll
        for (int j = 0; j < 4; j++) {
            f32x4 z = {0.f, 0.f, 0.f, 0.f};
            acc[i][j] = z;
        }
    const char* Abase = (const char*)Ag + (size_t)bm * 128 * (size_t)Kd * 2;
    const char* Bbase = (const char*)Bg + (size_t)bn * 128 * (size_t)Kd * 2;
    const size_t ldb = (size_t)Kd * 2;

    for (int kt = 0; kt < Kd; kt += 64) {
#pragma unroll
        for (int i = 0; i < 4; i++) {
            int chunk = i * 256 + t;
            int row = chunk >> 3;
            int cb = (chunk & 7) * 16;
            gload_lds16(Abase + (size_t)row * ldb + (size_t)kt * 2 + cb, (char*)As + chunk * 16);
        }
#pragma unroll
        for (int i = 0; i < 4; i++) {
            int chunk = i * 256 + t;
            int row = chunk >> 3;
            int cb = (chunk & 7) * 16;
            gload_lds16(Bbase + (size_t)row * ldb + (size_t)kt * 2 + cb, (char*)Bs + chunk * 16);
        }
        __syncthreads();
        bf16x8 af[4][2], bfv[4][2];
#pragma unroll
        for (int mf = 0; mf < 4; mf++)
#pragma unroll
            for (int ks = 0; ks < 2; ks++)
                af[mf][ks] = *(const bf16x8*)&As[(wr * 64 + mf * 16 + fr) * 64 + ks * 32 + fq * 8];
#pragma unroll
        for (int nf = 0; nf < 4; nf++)
#pragma unroll
            for (int ks = 0; ks < 2; ks++)
                bfv[nf][ks] = *(const bf16x8*)&Bs[(wc * 64 + nf * 16 + fr) * 64 + ks * 32 + fq * 8];
#pragma unroll
        for (int mf = 0; mf < 4; mf++)
#pragma unroll
            for (int nf = 0; nf < 4; nf++)
#pragma unroll
                for (int ks = 0; ks < 2; ks++)
                    acc[mf][nf] = __builtin_amdgcn_mfma_f32_16x16x32_bf16(af[mf][ks], bfv[nf][ks], acc[mf][nf], 0, 0, 0);
        __syncthreads();
    }
#pragma unroll
    for (int mf = 0; mf < 4; mf++) {
#pragma unroll
        for (int nf = 0; nf < 4; nf++) {
            int gn = bn * 128 + wc * 64 + nf * 16 + fr;
            float bi = bias[gn];
            int gm0 = bm * 128 + wr * 64 + mf * 16 + fq * 4;
#pragma unroll
            for (int r = 0; r < 4; r++) {
                float v = acc[mf][nf][r] + bi;
                if (RELU) v = fmaxf(v, 0.f);
                size_t o = (size_t)(gm0 + r) * N + gn;
                if (OBF16) ((u16*)Cg)[o] = f2bf(v);
                else ((float*)Cg)[o] = v;
            }
        }
    }
}

// ---------------------------------------------------------------------------
// FINAL: per point (16 rows), per channel: softmax over k, weighted sum of V
// ---------------------------------------------------------------------------
__global__ __launch_bounds__(256) void final_kernel(const float* __restrict__ L, const u16* __restrict__ V,
                                                    float* __restrict__ out, int row0) {
    int t = threadIdx.x, w = t >> 6, l = t & 63;
    int p = blockIdx.x * 4 + w;  // chunk-local point
    int lr = p * 16;
    int gp = row0 / 16 + p;
    int b = gp >> 11, n = gp & (Nc - 1);
    const float* Lp = L + (size_t)lr * Cc;
    const u16* Vp = V + (size_t)lr * Cc;
#pragma unroll 1
    for (int j = 0; j < 8; j++) {
        int c = l + 64 * j;
        float lv[16];
#pragma unroll
        for (int k = 0; k < 16; k++) lv[k] = Lp[(size_t)k * Cc + c];
        float mx = lv[0];
#pragma unroll
        for (int k = 1; k < 16; k++) mx = fmaxf(mx, lv[k]);
        float ssum = 0.f;
#pragma unroll
        for (int k = 0; k < 16; k++) {
            lv[k] = __expf(lv[k] - mx);
            ssum += lv[k];
        }
        float acc = 0.f;
#pragma unroll
        for (int k = 0; k < 16; k++) acc += lv[k] * bf2f(Vp[(size_t)k * Cc + c]);
        out[((size_t)b * Cc + c) * Nc + n] = acc / ssum;
    }
}

// ---------------------------------------------------------------------------
extern "C" void kernel_launch(void* const* d_in, const int* in_sizes, int n_in,
                              void* d_out, int out_size, void* d_ws, size_t ws_size,
                              hipStream_t stream) {
    (void)in_sizes; (void)n_in; (void)out_size;
    const float* pcd     = (const float*)d_in[0];
    const float* feat    = (const float*)d_in[1];
    const float* pcd_db  = (const float*)d_in[2];
    const float* feat_db = (const float*)d_in[3];
    const float* pw1 = (const float*)d_in[4];
    const float* pb1 = (const float*)d_in[5];
    const float* pg  = (const float*)d_in[6];
    const float* pbb = (const float*)d_in[7];
    const float* pm  = (const float*)d_in[8];
    const float* pv  = (const float*)d_in[9];
    const float* pw2 = (const float*)d_in[10];
    const float* pb2 = (const float*)d_in[11];
    const float* aw1 = (const float*)d_in[12];
    const float* ab1 = (const float*)d_in[13];
    const float* ag  = (const float*)d_in[14];
    const float* abb = (const float*)d_in[15];
    const float* am  = (const float*)d_in[16];
    const float* av  = (const float*)d_in[17];
    const float* aw2 = (const float*)d_in[18];
    const float* ab2 = (const float*)d_in[19];
    float* out = (float*)d_out;

    char* base = (char*)d_ws;
    size_t off = 0;
    auto alloc = [&](size_t bytes) -> char* {
        char* r = base + off;
        off = (off + bytes + 255) & ~(size_t)255;
        return r;
    };
    int*   idxb  = (int*)alloc((size_t)RT * 4);
    float* featT = (float*)alloc((size_t)Bc * Sc * Cc * 4);
    u16*   W1b   = (u16*)alloc((size_t)AH * Cc * 2);
    float* bias1 = (float*)alloc((size_t)AH * 4);
    u16*   W2b   = (u16*)alloc((size_t)Cc * AH * 2);

    // chunked row pipeline (X,V,A,L reused per chunk) in case ws is small
    const size_t perrow = 1024 + 1024 + 2048 + 2048;  // X,V bf16 + A bf16 + L f32
    int cr = RT;
    size_t avail = ws_size > off ? ws_size - off : 0;
    if (avail < (size_t)RT * perrow) {
        cr = (int)((avail / perrow) & ~(size_t)127);
        if (cr < 128) cr = 128;
    }
    u16*   Xb = (u16*)alloc((size_t)cr * Cc * 2);
    u16*   Vb = (u16*)alloc((size_t)cr * Cc * 2);
    u16*   Ab = (u16*)alloc((size_t)cr * AH * 2);
    float* Lb = (float*)alloc((size_t)cr * Cc * 4);

    transpose_kernel<<<dim3(Bc * 40 * 8), dim3(256), 0, stream>>>(feat, feat_db, featT);
    prep_kernel<<<dim3((AH * Cc) / 256), dim3(256), 0, stream>>>(aw1, ab1, ag, abb, am, av, aw2, W1b, bias1, W2b);
    knn_kernel<<<dim3(Bc * Nc / 4), dim3(256), 0, stream>>>(pcd, pcd_db, idxb);

    for (int r0 = 0; r0 < RT; r0 += cr) {
        int rows = (RT - r0 < cr) ? (RT - r0) : cr;
        build_kernel<<<dim3(rows / 16), dim3(256), 0, stream>>>(featT, idxb, pcd, pcd_db,
                                                                pw1, pb1, pg, pbb, pm, pv, pw2, pb2,
                                                                Xb, Vb, r0);
        gemm_bt<true, true><<<dim3(rows / 128, AH / 128), dim3(256), 0, stream>>>(Xb, W1b, bias1, Ab, rows, AH, Cc);
        gemm_bt<false, false><<<dim3(rows / 128, Cc / 128), dim3(256), 0, stream>>>(Ab, W2b, ab2, Lb, rows, Cc, AH);
        final_kernel<<<dim3(rows / 64), dim3(256), 0, stream>>>(Lb, Vb, out, r0);
    }
}

// Round 6
// 466.503 us; speedup vs baseline: 1.9149x; 1.9149x over previous
//
#include <hip/hip_runtime.h>

typedef unsigned short u16;
typedef unsigned int   u32;
typedef __attribute__((ext_vector_type(8))) short bf16x8;
typedef __attribute__((ext_vector_type(4))) float f32x4;
typedef __attribute__((ext_vector_type(4))) u32   u32x4;

// Problem constants
constexpr int Bc = 2, Cc = 512, Nc = 2048, Mc = 512, Sc = 2560, Kc = 16, PH = 64, AH = 1024;
constexpr int RT = Bc * Nc * Kc;  // 65536 rows (b,n,k)
constexpr float EPS = 1e-5f;

__device__ __forceinline__ u16 f2bf(float f) {
    u32 u = __float_as_uint(f);
    u32 r = (u + 0x7fffu + ((u >> 16) & 1u)) >> 16;  // RNE
    return (u16)r;
}
__device__ __forceinline__ float bf2f(u16 h) { return __uint_as_float(((u32)h) << 16); }

__device__ __forceinline__ void gload_lds16(const void* g, void* l) {
    __builtin_amdgcn_global_load_lds((const __attribute__((address_space(1))) u32*)g,
                                     (__attribute__((address_space(3))) u32*)l, 16, 0, 0);
}

// ---------------------------------------------------------------------------
// Transpose fusion_feat [B,C,S(split)] f32 -> featT [B,S,C] f32
// ---------------------------------------------------------------------------
__global__ __launch_bounds__(256) void transpose_kernel(const float* __restrict__ feat,
                                                        const float* __restrict__ feat_db,
                                                        float* __restrict__ featT) {
    __shared__ float tile[64][65];
    int bid = blockIdx.x;
    int b = bid / (40 * 8);
    int rem = bid - b * (40 * 8);
    int st = rem >> 3, ct = rem & 7;
    int t = threadIdx.x, lane = t & 63, g = t >> 6;
    int s0 = st * 64, c0 = ct * 64;
    const float* src;
    int sl0, stride;
    if (s0 < Nc) { src = feat + (size_t)b * Cc * Nc; sl0 = s0; stride = Nc; }
    else         { src = feat_db + (size_t)b * Cc * Mc; sl0 = s0 - Nc; stride = Mc; }
#pragma unroll
    for (int i = 0; i < 16; i++) {
        int cl = g * 16 + i;
        tile[cl][lane] = src[(size_t)(c0 + cl) * stride + sl0 + lane];
    }
    __syncthreads();
#pragma unroll
    for (int i = 0; i < 16; i++) {
        int sl = g * 16 + i;
        featT[((size_t)b * Sc + s0 + sl) * Cc + c0 + lane] = tile[lane][sl];
    }
}

// ---------------------------------------------------------------------------
// Weight prep: fold attn BN into W1/bias1, cast attn W1/W2 + pos W2 to bf16
// ---------------------------------------------------------------------------
__global__ __launch_bounds__(256) void prep_kernel(const float* __restrict__ aw1, const float* __restrict__ ab1,
                                                   const float* __restrict__ ag, const float* __restrict__ abb,
                                                   const float* __restrict__ am, const float* __restrict__ av,
                                                   const float* __restrict__ aw2, const float* __restrict__ pw2,
                                                   u16* __restrict__ W1b, float* __restrict__ bias1,
                                                   u16* __restrict__ W2b, u16* __restrict__ PW2b) {
    int i = blockIdx.x * 256 + threadIdx.x;  // grid covers 524288
    if (i < AH * Cc) {
        int o = i >> 9;
        float inv = ag[o] / sqrtf(av[o] + EPS);
        W1b[i] = f2bf(aw1[i] * inv);
    }
    if (i < AH) {
        float inv = ag[i] / sqrtf(av[i] + EPS);
        bias1[i] = ab1[i] * inv + abb[i] - am[i] * inv;
    }
    if (i < Cc * AH) W2b[i] = f2bf(aw2[i]);
    if (i < Cc * PH) PW2b[i] = f2bf(pw2[i]);
}

// ---------------------------------------------------------------------------
// KNN: one wave per query; distances mirror the reference decomposition
// qq + ss - 2*dot with no fma contraction; ties -> smaller index (top_k).
// ---------------------------------------------------------------------------
__global__ __launch_bounds__(256) void knn_kernel(const float* __restrict__ pcd,
                                                  const float* __restrict__ pcd_db,
                                                  int* __restrict__ idxout) {
    int t = threadIdx.x, w = t >> 6, l = t & 63;
    int q = blockIdx.x * 4 + w;  // 0..4095
    int b = q >> 11, n = q & (Nc - 1);
    const float* pc = pcd + (size_t)b * 3 * Nc;
    const float* pd = pcd_db + (size_t)b * 3 * Mc;
    float qx = pc[n], qy = pc[Nc + n], qz = pc[2 * Nc + n];
    float qq = __fadd_rn(__fadd_rn(__fmul_rn(qx, qx), __fmul_rn(qy, qy)), __fmul_rn(qz, qz));
    float dist[40];
#pragma unroll
    for (int j = 0; j < 40; j++) {
        int s = j * 64 + l;
        float sx, sy, sz;
        if (s < Nc) { sx = pc[s]; sy = pc[Nc + s]; sz = pc[2 * Nc + s]; }
        else { int ss = s - Nc; sx = pd[ss]; sy = pd[Mc + ss]; sz = pd[2 * Mc + ss]; }
        float ss2 = __fadd_rn(__fadd_rn(__fmul_rn(sx, sx), __fmul_rn(sy, sy)), __fmul_rn(sz, sz));
        float dt  = __fadd_rn(__fadd_rn(__fmul_rn(qx, sx), __fmul_rn(qy, sy)), __fmul_rn(qz, sz));
        dist[j] = __fsub_rn(__fadd_rn(qq, ss2), __fmul_rn(2.0f, dt));
    }
    for (int r = 0; r < 16; r++) {
        float bd = 1e30f;
        int bs = 1 << 30;
#pragma unroll
        for (int j = 0; j < 40; j++) {
            int s = j * 64 + l;
            bool better = (dist[j] < bd) || (dist[j] == bd && s < bs);
            bd = better ? dist[j] : bd;
            bs = better ? s : bs;
        }
        for (int off = 32; off; off >>= 1) {
            float od = __shfl_xor(bd, off);
            int   os = __shfl_xor(bs, off);
            bool better = (od < bd) || (od == bd && os < bs);
            bd = better ? od : bd;
            bs = better ? os : bs;
        }
        if (l == 0) idxout[q * 16 + r] = bs;
        int wj = bs >> 6, wl = bs & 63;
        if (l == wl) {
#pragma unroll
            for (int j = 0; j < 40; j++)
                if (j == wj) dist[j] = 1e30f;
        }
    }
}

// ---------------------------------------------------------------------------
// HKER: per row, pos-MLP layer-1: h[r][64] = relu(BN(W1 (q - s) + b1)) bf16
// ---------------------------------------------------------------------------
__global__ __launch_bounds__(256) void hker(const float* __restrict__ pcd, const float* __restrict__ pcd_db,
                                            const int* __restrict__ idxb,
                                            const float* __restrict__ pw1, const float* __restrict__ pb1,
                                            const float* __restrict__ pg, const float* __restrict__ pbb,
                                            const float* __restrict__ pm, const float* __restrict__ pv,
                                            u16* __restrict__ H) {
    __shared__ float W1s[64][4];
    int t = threadIdx.x;
    if (t < 64) {
        float inv = pg[t] / sqrtf(pv[t] + EPS);
        W1s[t][0] = pw1[t * 3 + 0] * inv;
        W1s[t][1] = pw1[t * 3 + 1] * inv;
        W1s[t][2] = pw1[t * 3 + 2] * inv;
        W1s[t][3] = pb1[t] * inv + pbb[t] - pm[t] * inv;
    }
    __syncthreads();
    int r = blockIdx.x * 256 + t;
    int b = r >> 15, n = (r >> 4) & (Nc - 1), s = idxb[r];
    const float* pc = pcd + (size_t)b * 3 * Nc;
    float qx = pc[n], qy = pc[Nc + n], qz = pc[2 * Nc + n];
    float sx, sy, sz;
    if (s < Nc) { sx = pc[s]; sy = pc[Nc + s]; sz = pc[2 * Nc + s]; }
    else {
        const float* pd = pcd_db + (size_t)b * 3 * Mc;
        int ss = s - Nc;
        sx = pd[ss]; sy = pd[Mc + ss]; sz = pd[2 * Mc + ss];
    }
    float dx = qx - sx, dy = qy - sy, dz = qz - sz;
    u16* hp = H + (size_t)r * 64;
#pragma unroll
    for (int u0 = 0; u0 < 64; u0 += 8) {
        u16 e[8];
#pragma unroll
        for (int j = 0; j < 8; j++) {
            int u = u0 + j;
            float hv = fmaxf(0.f, dx * W1s[u][0] + dy * W1s[u][1] + dz * W1s[u][2] + W1s[u][3]);
            e[j] = f2bf(hv);
        }
        u32x4 pk;
        pk.x = (u32)e[0] | ((u32)e[1] << 16); pk.y = (u32)e[2] | ((u32)e[3] << 16);
        pk.z = (u32)e[4] | ((u32)e[5] << 16); pk.w = (u32)e[6] | ((u32)e[7] << 16);
        *(u32x4*)(hp + u0) = pk;
    }
}

// ---------------------------------------------------------------------------
// PGEMM_FUSED: P = H @ PW2^T + pb2 via MFMA (M=rows, N=512, K=64), epilogue
// gathers f,g from featT and emits X = f-g+p, V = g+p (bf16).
// ---------------------------------------------------------------------------
__global__ __launch_bounds__(256) void pgemm_fused(const u16* __restrict__ Hg, const u16* __restrict__ Bg,
                                                   const float* __restrict__ pb2,
                                                   const float* __restrict__ featT, const int* __restrict__ idxb,
                                                   u16* __restrict__ X, u16* __restrict__ V, int row0) {
    __shared__ u16 As[128 * 64];
    __shared__ u16 Bs[128 * 64];
    const int t = threadIdx.x;
    const int bm = blockIdx.x, bn = blockIdx.y;
    const int w = t >> 6, l = t & 63;
    const int wr = w >> 1, wc = w & 1;
    const int fr = l & 15, fq = l >> 4;
    f32x4 acc[4][4];
#pragma unroll
    for (int i = 0; i < 4; i++)
#pragma unroll
        for (int j = 0; j < 4; j++) {
            f32x4 z = {0.f, 0.f, 0.f, 0.f};
            acc[i][j] = z;
        }
    const char* Abase = (const char*)Hg + ((size_t)row0 + (size_t)bm * 128) * 64 * 2;
    const char* Bbase = (const char*)Bg + (size_t)bn * 128 * 64 * 2;
#pragma unroll
    for (int i = 0; i < 4; i++) {
        int chunk = i * 256 + t;
        int row = chunk >> 3;
        int cb = (chunk & 7) * 16;
        gload_lds16(Abase + (size_t)row * 128 + cb, (char*)As + chunk * 16);
    }
#pragma unroll
    for (int i = 0; i < 4; i++) {
        int chunk = i * 256 + t;
        int row = chunk >> 3;
        int cb = (chunk & 7) * 16;
        gload_lds16(Bbase + (size_t)row * 128 + cb, (char*)Bs + chunk * 16);
    }
    __syncthreads();
    bf16x8 af[4][2], bfv[4][2];
#pragma unroll
    for (int mf = 0; mf < 4; mf++)
#pragma unroll
        for (int ks = 0; ks < 2; ks++)
            af[mf][ks] = *(const bf16x8*)&As[(wr * 64 + mf * 16 + fr) * 64 + ks * 32 + fq * 8];
#pragma unroll
    for (int nf = 0; nf < 4; nf++)
#pragma unroll
        for (int ks = 0; ks < 2; ks++)
            bfv[nf][ks] = *(const bf16x8*)&Bs[(wc * 64 + nf * 16 + fr) * 64 + ks * 32 + fq * 8];
#pragma unroll
    for (int mf = 0; mf < 4; mf++)
#pragma unroll
        for (int nf = 0; nf < 4; nf++)
#pragma unroll
            for (int ks = 0; ks < 2; ks++)
                acc[mf][nf] = __builtin_amdgcn_mfma_f32_16x16x32_bf16(af[mf][ks], bfv[nf][ks], acc[mf][nf], 0, 0, 0);
    // epilogue: per C-row gather f,g; emit X,V
#pragma unroll
    for (int mf = 0; mf < 4; mf++) {
#pragma unroll
        for (int r = 0; r < 4; r++) {
            int gr = bm * 128 + wr * 64 + mf * 16 + fq * 4 + r;  // chunk-local row
            int grow = row0 + gr;                                 // global row
            int b = grow >> 15;
            int n = (grow >> 4) & (Nc - 1);
            int s = idxb[grow];
            const float* frow = featT + ((size_t)b * Sc + n) * Cc;
            const float* grow_p = featT + ((size_t)b * Sc + s) * Cc;
#pragma unroll
            for (int nf = 0; nf < 4; nf++) {
                int gn = bn * 128 + wc * 64 + nf * 16 + fr;
                float p = acc[mf][nf][r] + pb2[gn];
                float fv = frow[gn];
                float gv = grow_p[gn];
                X[(size_t)gr * Cc + gn] = f2bf(fv - gv + p);
                V[(size_t)gr * Cc + gn] = f2bf(gv + p);
            }
        }
    }
}

// ---------------------------------------------------------------------------
// GEMM (m97 structure): C[m][n] = f(sum_k A[m][k]*B[n][k] + bias[n])
// A [M][Kd] bf16, B [N][Kd] bf16 (i.e. B^T layout), 128x128 tile, BK=64.
// ---------------------------------------------------------------------------
template <bool RELU, bool OBF16>
__global__ __launch_bounds__(256) void gemm_bt(const u16* __restrict__ Ag, const u16* __restrict__ Bg,
                                               const float* __restrict__ bias, void* __restrict__ Cg,
                                               int M, int N, int Kd) {
    __shared__ u16 As[128 * 64];
    __shared__ u16 Bs[128 * 64];
    const int t = threadIdx.x;
    const int bm = blockIdx.x, bn = blockIdx.y;
    const int w = t >> 6, l = t & 63;
    const int wr = w >> 1, wc = w & 1;
    const int fr = l & 15, fq = l >> 4;
    f32x4 acc[4][4];
#pragma unroll
    for (int i = 0; i < 4; i++)
#pragma unroll
        for (int j = 0; j < 4; j++) {
            f32x4 z = {0.f, 0.f, 0.f, 0.f};
            acc[i][j] = z;
        }
    const char* Abase = (const char*)Ag + (size_t)bm * 128 * (size_t)Kd * 2;
    const char* Bbase = (const char*)Bg + (size_t)bn * 128 * (size_t)Kd * 2;
    const size_t ldb = (size_t)Kd * 2;

    for (int kt = 0; kt < Kd; kt += 64) {
#pragma unroll
        for (int i = 0; i < 4; i++) {
            int chunk = i * 256 + t;
            int row = chunk >> 3;
            int cb = (chunk & 7) * 16;
            gload_lds16(Abase + (size_t)row * ldb + (size_t)kt * 2 + cb, (char*)As + chunk * 16);
        }
#pragma unroll
        for (int i = 0; i < 4; i++) {
            int chunk = i * 256 + t;
            int row = chunk >> 3;
            int cb = (chunk & 7) * 16;
            gload_lds16(Bbase + (size_t)row * ldb + (size_t)kt * 2 + cb, (char*)Bs + chunk * 16);
        }
        __syncthreads();
        bf16x8 af[4][2], bfv[4][2];
#pragma unroll
        for (int mf = 0; mf < 4; mf++)
#pragma unroll
            for (int ks = 0; ks < 2; ks++)
                af[mf][ks] = *(const bf16x8*)&As[(wr * 64 + mf * 16 + fr) * 64 + ks * 32 + fq * 8];
#pragma unroll
        for (int nf = 0; nf < 4; nf++)
#pragma unroll
            for (int ks = 0; ks < 2; ks++)
                bfv[nf][ks] = *(const bf16x8*)&Bs[(wc * 64 + nf * 16 + fr) * 64 + ks * 32 + fq * 8];
#pragma unroll
        for (int mf = 0; mf < 4; mf++)
#pragma unroll
            for (int nf = 0; nf < 4; nf++)
#pragma unroll
                for (int ks = 0; ks < 2; ks++)
                    acc[mf][nf] = __builtin_amdgcn_mfma_f32_16x16x32_bf16(af[mf][ks], bfv[nf][ks], acc[mf][nf], 0, 0, 0);
        __syncthreads();
    }
#pragma unroll
    for (int mf = 0; mf < 4; mf++) {
#pragma unroll
        for (int nf = 0; nf < 4; nf++) {
            int gn = bn * 128 + wc * 64 + nf * 16 + fr;
            float bi = bias[gn];
            int gm0 = bm * 128 + wr * 64 + mf * 16 + fq * 4;
#pragma unroll
            for (int r = 0; r < 4; r++) {
                float v = acc[mf][nf][r] + bi;
                if (RELU) v = fmaxf(v, 0.f);
                size_t o = (size_t)(gm0 + r) * N + gn;
                if (OBF16) ((u16*)Cg)[o] = f2bf(v);
                else ((float*)Cg)[o] = v;
            }
        }
    }
}

// ---------------------------------------------------------------------------
// FINAL: per point (16 rows), per channel: softmax over k, weighted sum of V
// ---------------------------------------------------------------------------
__global__ __launch_bounds__(256) void final_kernel(const float* __restrict__ L, const u16* __restrict__ V,
                                                    float* __restrict__ out, int row0) {
    int t = threadIdx.x, w = t >> 6, l = t & 63;
    int p = blockIdx.x * 4 + w;  // chunk-local point
    int lr = p * 16;
    int gp = row0 / 16 + p;
    int b = gp >> 11, n = gp & (Nc - 1);
    const float* Lp = L + (size_t)lr * Cc;
    const u16* Vp = V + (size_t)lr * Cc;
#pragma unroll 1
    for (int j = 0; j < 8; j++) {
        int c = l + 64 * j;
        float lv[16];
#pragma unroll
        for (int k = 0; k < 16; k++) lv[k] = Lp[(size_t)k * Cc + c];
        float mx = lv[0];
#pragma unroll
        for (int k = 1; k < 16; k++) mx = fmaxf(mx, lv[k]);
        float ssum = 0.f;
#pragma unroll
        for (int k = 0; k < 16; k++) {
            lv[k] = __expf(lv[k] - mx);
            ssum += lv[k];
        }
        float acc = 0.f;
#pragma unroll
        for (int k = 0; k < 16; k++) acc += lv[k] * bf2f(Vp[(size_t)k * Cc + c]);
        out[((size_t)b * Cc + c) * Nc + n] = acc / ssum;
    }
}

// ---------------------------------------------------------------------------
extern "C" void kernel_launch(void* const* d_in, const int* in_sizes, int n_in,
                              void* d_out, int out_size, void* d_ws, size_t ws_size,
                              hipStream_t stream) {
    (void)in_sizes; (void)n_in; (void)out_size;
    const float* pcd     = (const float*)d_in[0];
    const float* feat    = (const float*)d_in[1];
    const float* pcd_db  = (const float*)d_in[2];
    const float* feat_db = (const float*)d_in[3];
    const float* pw1 = (const float*)d_in[4];
    const float* pb1 = (const float*)d_in[5];
    const float* pg  = (const float*)d_in[6];
    const float* pbb = (const float*)d_in[7];
    const float* pm  = (const float*)d_in[8];
    const float* pv  = (const float*)d_in[9];
    const float* pw2 = (const float*)d_in[10];
    const float* pb2 = (const float*)d_in[11];
    const float* aw1 = (const float*)d_in[12];
    const float* ab1 = (const float*)d_in[13];
    const float* ag  = (const float*)d_in[14];
    const float* abb = (const float*)d_in[15];
    const float* am  = (const float*)d_in[16];
    const float* av  = (const float*)d_in[17];
    const float* aw2 = (const float*)d_in[18];
    const float* ab2 = (const float*)d_in[19];
    float* out = (float*)d_out;

    char* base = (char*)d_ws;
    size_t off = 0;
    auto alloc = [&](size_t bytes) -> char* {
        char* r = base + off;
        off = (off + bytes + 255) & ~(size_t)255;
        return r;
    };
    int*   idxb  = (int*)alloc((size_t)RT * 4);
    float* featT = (float*)alloc((size_t)Bc * Sc * Cc * 4);
    u16*   W1b   = (u16*)alloc((size_t)AH * Cc * 2);
    float* bias1 = (float*)alloc((size_t)AH * 4);
    u16*   W2b   = (u16*)alloc((size_t)Cc * AH * 2);
    u16*   PW2b  = (u16*)alloc((size_t)Cc * PH * 2);
    u16*   Hb    = (u16*)alloc((size_t)RT * PH * 2);

    // chunked row pipeline (X,V,A,L reused per chunk) in case ws is small
    const size_t perrow = 1024 + 1024 + 2048 + 2048;  // X,V bf16 + A bf16 + L f32
    int cr = RT;
    size_t avail = ws_size > off ? ws_size - off : 0;
    if (avail < (size_t)RT * perrow) {
        cr = (int)((avail / perrow) & ~(size_t)127);
        if (cr < 128) cr = 128;
    }
    u16*   Xb = (u16*)alloc((size_t)cr * Cc * 2);
    u16*   Vb = (u16*)alloc((size_t)cr * Cc * 2);
    u16*   Ab = (u16*)alloc((size_t)cr * AH * 2);
    float* Lb = (float*)alloc((size_t)cr * Cc * 4);

    transpose_kernel<<<dim3(Bc * 40 * 8), dim3(256), 0, stream>>>(feat, feat_db, featT);
    prep_kernel<<<dim3((AH * Cc) / 256), dim3(256), 0, stream>>>(aw1, ab1, ag, abb, am, av, aw2, pw2,
                                                                 W1b, bias1, W2b, PW2b);
    knn_kernel<<<dim3(Bc * Nc / 4), dim3(256), 0, stream>>>(pcd, pcd_db, idxb);
    hker<<<dim3(RT / 256), dim3(256), 0, stream>>>(pcd, pcd_db, idxb, pw1, pb1, pg, pbb, pm, pv, Hb);

    for (int r0 = 0; r0 < RT; r0 += cr) {
        int rows = (RT - r0 < cr) ? (RT - r0) : cr;
        pgemm_fused<<<dim3(rows / 128, Cc / 128), dim3(256), 0, stream>>>(Hb, PW2b, pb2, featT, idxb,
                                                                          Xb, Vb, r0);
        gemm_bt<true, true><<<dim3(rows / 128, AH / 128), dim3(256), 0, stream>>>(Xb, W1b, bias1, Ab, rows, AH, Cc);
        gemm_bt<false, false><<<dim3(rows / 128, Cc / 128), dim3(256), 0, stream>>>(Ab, W2b, ab2, Lb, rows, Cc, AH);
        final_kernel<<<dim3(rows / 64), dim3(256), 0, stream>>>(Lb, Vb, out, r0);
    }
}

// Round 7
// 439.076 us; speedup vs baseline: 2.0345x; 1.0625x over previous
//
#include <hip/hip_runtime.h>

typedef unsigned short u16;
typedef unsigned int   u32;
typedef __attribute__((ext_vector_type(8))) short bf16x8;
typedef __attribute__((ext_vector_type(4))) float f32x4;
typedef __attribute__((ext_vector_type(4))) u32   u32x4;

// Problem constants
constexpr int Bc = 2, Cc = 512, Nc = 2048, Mc = 512, Sc = 2560, Kc = 16, PH = 64, AH = 1024;
constexpr int RT = Bc * Nc * Kc;  // 65536 rows (b,n,k)
constexpr float EPS = 1e-5f;

__device__ __forceinline__ u16 f2bf(float f) {
    u32 u = __float_as_uint(f);
    u32 r = (u + 0x7fffu + ((u >> 16) & 1u)) >> 16;  // RNE
    return (u16)r;
}
__device__ __forceinline__ float bf2f(u16 h) { return __uint_as_float(((u32)h) << 16); }

__device__ __forceinline__ void gload_lds16(const void* g, void* l) {
    __builtin_amdgcn_global_load_lds((const __attribute__((address_space(1))) u32*)g,
                                     (__attribute__((address_space(3))) u32*)l, 16, 0, 0);
}

// Bijective XCD-aware workgroup swizzle (m204 form): same-XCD wgs get a
// contiguous run of linear ids. With bn-fastest linearization this makes an
// XCD reuse one A-panel across all bn tiles (L2 locality).
__device__ __forceinline__ void xcd_tiles(u32& bm, u32& bn) {
    u32 gdx = gridDim.x, gdy = gridDim.y;
    u32 nwg = gdx * gdy;
    u32 wg = blockIdx.x + gdx * blockIdx.y;
    u32 q = nwg >> 3, r8 = nwg & 7;
    u32 xcd = wg & 7, loc = wg >> 3;
    u32 swz = (xcd < r8 ? xcd * (q + 1) : r8 * (q + 1) + (xcd - r8) * q) + loc;
    bn = swz % gdy;   // bn fastest within an XCD's contiguous run
    bm = swz / gdy;
}

// ---------------------------------------------------------------------------
// Transpose fusion_feat [B,C,S(split)] f32 -> featT [B,S,C] f32
// ---------------------------------------------------------------------------
__global__ __launch_bounds__(256) void transpose_kernel(const float* __restrict__ feat,
                                                        const float* __restrict__ feat_db,
                                                        float* __restrict__ featT) {
    __shared__ float tile[64][65];
    int bid = blockIdx.x;
    int b = bid / (40 * 8);
    int rem = bid - b * (40 * 8);
    int st = rem >> 3, ct = rem & 7;
    int t = threadIdx.x, lane = t & 63, g = t >> 6;
    int s0 = st * 64, c0 = ct * 64;
    const float* src;
    int sl0, stride;
    if (s0 < Nc) { src = feat + (size_t)b * Cc * Nc; sl0 = s0; stride = Nc; }
    else         { src = feat_db + (size_t)b * Cc * Mc; sl0 = s0 - Nc; stride = Mc; }
#pragma unroll
    for (int i = 0; i < 16; i++) {
        int cl = g * 16 + i;
        tile[cl][lane] = src[(size_t)(c0 + cl) * stride + sl0 + lane];
    }
    __syncthreads();
#pragma unroll
    for (int i = 0; i < 16; i++) {
        int sl = g * 16 + i;
        featT[((size_t)b * Sc + s0 + sl) * Cc + c0 + lane] = tile[lane][sl];
    }
}

// ---------------------------------------------------------------------------
// Weight prep: fold attn BN into W1/bias1, cast attn W1/W2 + pos W2 to bf16
// ---------------------------------------------------------------------------
__global__ __launch_bounds__(256) void prep_kernel(const float* __restrict__ aw1, const float* __restrict__ ab1,
                                                   const float* __restrict__ ag, const float* __restrict__ abb,
                                                   const float* __restrict__ am, const float* __restrict__ av,
                                                   const float* __restrict__ aw2, const float* __restrict__ pw2,
                                                   u16* __restrict__ W1b, float* __restrict__ bias1,
                                                   u16* __restrict__ W2b, u16* __restrict__ PW2b) {
    int i = blockIdx.x * 256 + threadIdx.x;  // grid covers 524288
    if (i < AH * Cc) {
        int o = i >> 9;
        float inv = ag[o] / sqrtf(av[o] + EPS);
        W1b[i] = f2bf(aw1[i] * inv);
    }
    if (i < AH) {
        float inv = ag[i] / sqrtf(av[i] + EPS);
        bias1[i] = ab1[i] * inv + abb[i] - am[i] * inv;
    }
    if (i < Cc * AH) W2b[i] = f2bf(aw2[i]);
    if (i < Cc * PH) PW2b[i] = f2bf(pw2[i]);
}

// ---------------------------------------------------------------------------
// KNN: one wave per query; distances mirror the reference decomposition
// qq + ss - 2*dot with no fma contraction; ties -> smaller index (top_k).
// ---------------------------------------------------------------------------
__global__ __launch_bounds__(256) void knn_kernel(const float* __restrict__ pcd,
                                                  const float* __restrict__ pcd_db,
                                                  int* __restrict__ idxout) {
    int t = threadIdx.x, w = t >> 6, l = t & 63;
    int q = blockIdx.x * 4 + w;  // 0..4095
    int b = q >> 11, n = q & (Nc - 1);
    const float* pc = pcd + (size_t)b * 3 * Nc;
    const float* pd = pcd_db + (size_t)b * 3 * Mc;
    float qx = pc[n], qy = pc[Nc + n], qz = pc[2 * Nc + n];
    float qq = __fadd_rn(__fadd_rn(__fmul_rn(qx, qx), __fmul_rn(qy, qy)), __fmul_rn(qz, qz));
    float dist[40];
#pragma unroll
    for (int j = 0; j < 40; j++) {
        int s = j * 64 + l;
        float sx, sy, sz;
        if (s < Nc) { sx = pc[s]; sy = pc[Nc + s]; sz = pc[2 * Nc + s]; }
        else { int ss = s - Nc; sx = pd[ss]; sy = pd[Mc + ss]; sz = pd[2 * Mc + ss]; }
        float ss2 = __fadd_rn(__fadd_rn(__fmul_rn(sx, sx), __fmul_rn(sy, sy)), __fmul_rn(sz, sz));
        float dt  = __fadd_rn(__fadd_rn(__fmul_rn(qx, sx), __fmul_rn(qy, sy)), __fmul_rn(qz, sz));
        dist[j] = __fsub_rn(__fadd_rn(qq, ss2), __fmul_rn(2.0f, dt));
    }
    for (int r = 0; r < 16; r++) {
        float bd = 1e30f;
        int bs = 1 << 30;
#pragma unroll
        for (int j = 0; j < 40; j++) {
            int s = j * 64 + l;
            bool better = (dist[j] < bd) || (dist[j] == bd && s < bs);
            bd = better ? dist[j] : bd;
            bs = better ? s : bs;
        }
        for (int off = 32; off; off >>= 1) {
            float od = __shfl_xor(bd, off);
            int   os = __shfl_xor(bs, off);
            bool better = (od < bd) || (od == bd && os < bs);
            bd = better ? od : bd;
            bs = better ? os : bs;
        }
        if (l == 0) idxout[q * 16 + r] = bs;
        int wj = bs >> 6, wl = bs & 63;
        if (l == wl) {
#pragma unroll
            for (int j = 0; j < 40; j++)
                if (j == wj) dist[j] = 1e30f;
        }
    }
}

// ---------------------------------------------------------------------------
// HKER: per row, pos-MLP layer-1: h[r][64] = relu(BN(W1 (q - s) + b1)) bf16
// ---------------------------------------------------------------------------
__global__ __launch_bounds__(256) void hker(const float* __restrict__ pcd, const float* __restrict__ pcd_db,
                                            const int* __restrict__ idxb,
                                            const float* __restrict__ pw1, const float* __restrict__ pb1,
                                            const float* __restrict__ pg, const float* __restrict__ pbb,
                                            const float* __restrict__ pm, const float* __restrict__ pv,
                                            u16* __restrict__ H) {
    __shared__ float W1s[64][4];
    int t = threadIdx.x;
    if (t < 64) {
        float inv = pg[t] / sqrtf(pv[t] + EPS);
        W1s[t][0] = pw1[t * 3 + 0] * inv;
        W1s[t][1] = pw1[t * 3 + 1] * inv;
        W1s[t][2] = pw1[t * 3 + 2] * inv;
        W1s[t][3] = pb1[t] * inv + pbb[t] - pm[t] * inv;
    }
    __syncthreads();
    int r = blockIdx.x * 256 + t;
    int b = r >> 15, n = (r >> 4) & (Nc - 1), s = idxb[r];
    const float* pc = pcd + (size_t)b * 3 * Nc;
    float qx = pc[n], qy = pc[Nc + n], qz = pc[2 * Nc + n];
    float sx, sy, sz;
    if (s < Nc) { sx = pc[s]; sy = pc[Nc + s]; sz = pc[2 * Nc + s]; }
    else {
        const float* pd = pcd_db + (size_t)b * 3 * Mc;
        int ss = s - Nc;
        sx = pd[ss]; sy = pd[Mc + ss]; sz = pd[2 * Mc + ss];
    }
    float dx = qx - sx, dy = qy - sy, dz = qz - sz;
    u16* hp = H + (size_t)r * 64;
#pragma unroll
    for (int u0 = 0; u0 < 64; u0 += 8) {
        u16 e[8];
#pragma unroll
        for (int j = 0; j < 8; j++) {
            int u = u0 + j;
            float hv = fmaxf(0.f, dx * W1s[u][0] + dy * W1s[u][1] + dz * W1s[u][2] + W1s[u][3]);
            e[j] = f2bf(hv);
        }
        u32x4 pk;
        pk.x = (u32)e[0] | ((u32)e[1] << 16); pk.y = (u32)e[2] | ((u32)e[3] << 16);
        pk.z = (u32)e[4] | ((u32)e[5] << 16); pk.w = (u32)e[6] | ((u32)e[7] << 16);
        *(u32x4*)(hp + u0) = pk;
    }
}

// ---------------------------------------------------------------------------
// PGEMM_FUSED: P = H @ PW2^T + pb2 via MFMA (M=rows, N=512, K=64), epilogue
// gathers f,g from featT and emits X = f-g+p, V = g+p (bf16).
// ---------------------------------------------------------------------------
__global__ __launch_bounds__(256) void pgemm_fused(const u16* __restrict__ Hg, const u16* __restrict__ Bg,
                                                   const float* __restrict__ pb2,
                                                   const float* __restrict__ featT, const int* __restrict__ idxb,
                                                   u16* __restrict__ X, u16* __restrict__ V, int row0) {
    __shared__ u16 As[128 * 64];
    __shared__ u16 Bs[128 * 64];
    const int t = threadIdx.x;
    u32 bmu, bnu;
    xcd_tiles(bmu, bnu);
    const int bm = (int)bmu, bn = (int)bnu;
    const int w = t >> 6, l = t & 63;
    const int wr = w >> 1, wc = w & 1;
    const int fr = l & 15, fq = l >> 4;
    f32x4 acc[4][4];
#pragma unroll
    for (int i = 0; i < 4; i++)
#pragma unroll
        for (int j = 0; j < 4; j++) {
            f32x4 z = {0.f, 0.f, 0.f, 0.f};
            acc[i][j] = z;
        }
    const char* Abase = (const char*)Hg + ((size_t)row0 + (size_t)bm * 128) * 64 * 2;
    const char* Bbase = (const char*)Bg + (size_t)bn * 128 * 64 * 2;
#pragma unroll
    for (int i = 0; i < 4; i++) {
        int chunk = i * 256 + t;
        int row = chunk >> 3;
        int cb = (chunk & 7) * 16;
        gload_lds16(Abase + (size_t)row * 128 + cb, (char*)As + chunk * 16);
    }
#pragma unroll
    for (int i = 0; i < 4; i++) {
        int chunk = i * 256 + t;
        int row = chunk >> 3;
        int cb = (chunk & 7) * 16;
        gload_lds16(Bbase + (size_t)row * 128 + cb, (char*)Bs + chunk * 16);
    }
    __syncthreads();
    bf16x8 af[4][2], bfv[4][2];
#pragma unroll
    for (int mf = 0; mf < 4; mf++)
#pragma unroll
        for (int ks = 0; ks < 2; ks++)
            af[mf][ks] = *(const bf16x8*)&As[(wr * 64 + mf * 16 + fr) * 64 + ks * 32 + fq * 8];
#pragma unroll
    for (int nf = 0; nf < 4; nf++)
#pragma unroll
        for (int ks = 0; ks < 2; ks++)
            bfv[nf][ks] = *(const bf16x8*)&Bs[(wc * 64 + nf * 16 + fr) * 64 + ks * 32 + fq * 8];
#pragma unroll
    for (int mf = 0; mf < 4; mf++)
#pragma unroll
        for (int nf = 0; nf < 4; nf++)
#pragma unroll
            for (int ks = 0; ks < 2; ks++)
                acc[mf][nf] = __builtin_amdgcn_mfma_f32_16x16x32_bf16(af[mf][ks], bfv[nf][ks], acc[mf][nf], 0, 0, 0);
    // epilogue: per C-row gather f,g; emit X,V
#pragma unroll
    for (int mf = 0; mf < 4; mf++) {
#pragma unroll
        for (int r = 0; r < 4; r++) {
            int gr = bm * 128 + wr * 64 + mf * 16 + fq * 4 + r;  // chunk-local row
            int grow = row0 + gr;                                 // global row
            int b = grow >> 15;
            int n = (grow >> 4) & (Nc - 1);
            int s = idxb[grow];
            const float* frow = featT + ((size_t)b * Sc + n) * Cc;
            const float* grow_p = featT + ((size_t)b * Sc + s) * Cc;
#pragma unroll
            for (int nf = 0; nf < 4; nf++) {
                int gn = bn * 128 + wc * 64 + nf * 16 + fr;
                float p = acc[mf][nf][r] + pb2[gn];
                float fv = frow[gn];
                float gv = grow_p[gn];
                X[(size_t)gr * Cc + gn] = f2bf(fv - gv + p);
                V[(size_t)gr * Cc + gn] = f2bf(gv + p);
            }
        }
    }
}

// ---------------------------------------------------------------------------
// GEMM (m97 structure + XCD swizzle): C[m][n] = f(sum_k A[m][k]*B[n][k]+bias)
// A [M][Kd] bf16, B [N][Kd] bf16 (i.e. B^T layout), 128x128 tile, BK=64.
// ---------------------------------------------------------------------------
template <bool RELU, bool OBF16>
__global__ __launch_bounds__(256) void gemm_bt(const u16* __restrict__ Ag, const u16* __restrict__ Bg,
                                               const float* __restrict__ bias, void* __restrict__ Cg,
                                               int M, int N, int Kd) {
    __shared__ u16 As[128 * 64];
    __shared__ u16 Bs[128 * 64];
    const int t = threadIdx.x;
    u32 bmu, bnu;
    xcd_tiles(bmu, bnu);
    const int bm = (int)bmu, bn = (int)bnu;
    const int w = t >> 6, l = t & 63;
    const int wr = w >> 1, wc = w & 1;
    const int fr = l & 15, fq = l >> 4;
    f32x4 acc[4][4];
#pragma unroll
    for (int i = 0; i < 4; i++)
#pragma unroll
        for (int j = 0; j < 4; j++) {
            f32x4 z = {0.f, 0.f, 0.f, 0.f};
            acc[i][j] = z;
        }
    const char* Abase = (const char*)Ag + (size_t)bm * 128 * (size_t)Kd * 2;
    const char* Bbase = (const char*)Bg + (size_t)bn * 128 * (size_t)Kd * 2;
    const size_t ldb = (size_t)Kd * 2;

    for (int kt = 0; kt < Kd; kt += 64) {
#pragma unroll
        for (int i = 0; i < 4; i++) {
            int chunk = i * 256 + t;
            int row = chunk >> 3;
            int cb = (chunk & 7) * 16;
            gload_lds16(Abase + (size_t)row * ldb + (size_t)kt * 2 + cb, (char*)As + chunk * 16);
        }
#pragma unroll
        for (int i = 0; i < 4; i++) {
            int chunk = i * 256 + t;
            int row = chunk >> 3;
            int cb = (chunk & 7) * 16;
            gload_lds16(Bbase + (size_t)row * ldb + (size_t)kt * 2 + cb, (char*)Bs + chunk * 16);
        }
        __syncthreads();
        bf16x8 af[4][2], bfv[4][2];
#pragma unroll
        for (int mf = 0; mf < 4; mf++)
#pragma unroll
            for (int ks = 0; ks < 2; ks++)
                af[mf][ks] = *(const bf16x8*)&As[(wr * 64 + mf * 16 + fr) * 64 + ks * 32 + fq * 8];
#pragma unroll
        for (int nf = 0; nf < 4; nf++)
#pragma unroll
            for (int ks = 0; ks < 2; ks++)
                bfv[nf][ks] = *(const bf16x8*)&Bs[(wc * 64 + nf * 16 + fr) * 64 + ks * 32 + fq * 8];
#pragma unroll
        for (int mf = 0; mf < 4; mf++)
#pragma unroll
            for (int nf = 0; nf < 4; nf++)
#pragma unroll
                for (int ks = 0; ks < 2; ks++)
                    acc[mf][nf] = __builtin_amdgcn_mfma_f32_16x16x32_bf16(af[mf][ks], bfv[nf][ks], acc[mf][nf], 0, 0, 0);
        __syncthreads();
    }
#pragma unroll
    for (int mf = 0; mf < 4; mf++) {
#pragma unroll
        for (int nf = 0; nf < 4; nf++) {
            int gn = bn * 128 + wc * 64 + nf * 16 + fr;
            float bi = bias[gn];
            int gm0 = bm * 128 + wr * 64 + mf * 16 + fq * 4;
#pragma unroll
            for (int r = 0; r < 4; r++) {
                float v = acc[mf][nf][r] + bi;
                if (RELU) v = fmaxf(v, 0.f);
                size_t o = (size_t)(gm0 + r) * N + gn;
                if (OBF16) ((u16*)Cg)[o] = f2bf(v);
                else ((float*)Cg)[o] = v;
            }
        }
    }
}

// ---------------------------------------------------------------------------
// FINAL: per point (16 rows), per channel: softmax over k, weighted sum of V
// ---------------------------------------------------------------------------
__global__ __launch_bounds__(256) void final_kernel(const float* __restrict__ L, const u16* __restrict__ V,
                                                    float* __restrict__ out, int row0) {
    int t = threadIdx.x, w = t >> 6, l = t & 63;
    int p = blockIdx.x * 4 + w;  // chunk-local point
    int lr = p * 16;
    int gp = row0 / 16 + p;
    int b = gp >> 11, n = gp & (Nc - 1);
    const float* Lp = L + (size_t)lr * Cc;
    const u16* Vp = V + (size_t)lr * Cc;
#pragma unroll 1
    for (int j = 0; j < 8; j++) {
        int c = l + 64 * j;
        float lv[16];
#pragma unroll
        for (int k = 0; k < 16; k++) lv[k] = Lp[(size_t)k * Cc + c];
        float mx = lv[0];
#pragma unroll
        for (int k = 1; k < 16; k++) mx = fmaxf(mx, lv[k]);
        float ssum = 0.f;
#pragma unroll
        for (int k = 0; k < 16; k++) {
            lv[k] = __expf(lv[k] - mx);
            ssum += lv[k];
        }
        float acc = 0.f;
#pragma unroll
        for (int k = 0; k < 16; k++) acc += lv[k] * bf2f(Vp[(size_t)k * Cc + c]);
        out[((size_t)b * Cc + c) * Nc + n] = acc / ssum;
    }
}

// ---------------------------------------------------------------------------
extern "C" void kernel_launch(void* const* d_in, const int* in_sizes, int n_in,
                              void* d_out, int out_size, void* d_ws, size_t ws_size,
                              hipStream_t stream) {
    (void)in_sizes; (void)n_in; (void)out_size;
    const float* pcd     = (const float*)d_in[0];
    const float* feat    = (const float*)d_in[1];
    const float* pcd_db  = (const float*)d_in[2];
    const float* feat_db = (const float*)d_in[3];
    const float* pw1 = (const float*)d_in[4];
    const float* pb1 = (const float*)d_in[5];
    const float* pg  = (const float*)d_in[6];
    const float* pbb = (const float*)d_in[7];
    const float* pm  = (const float*)d_in[8];
    const float* pv  = (const float*)d_in[9];
    const float* pw2 = (const float*)d_in[10];
    const float* pb2 = (const float*)d_in[11];
    const float* aw1 = (const float*)d_in[12];
    const float* ab1 = (const float*)d_in[13];
    const float* ag  = (const float*)d_in[14];
    const float* abb = (const float*)d_in[15];
    const float* am  = (const float*)d_in[16];
    const float* av  = (const float*)d_in[17];
    const float* aw2 = (const float*)d_in[18];
    const float* ab2 = (const float*)d_in[19];
    float* out = (float*)d_out;

    char* base = (char*)d_ws;
    size_t off = 0;
    auto alloc = [&](size_t bytes) -> char* {
        char* r = base + off;
        off = (off + bytes + 255) & ~(size_t)255;
        return r;
    };
    int*   idxb  = (int*)alloc((size_t)RT * 4);
    float* featT = (float*)alloc((size_t)Bc * Sc * Cc * 4);
    u16*   W1b   = (u16*)alloc((size_t)AH * Cc * 2);
    float* bias1 = (float*)alloc((size_t)AH * 4);
    u16*   W2b   = (u16*)alloc((size_t)Cc * AH * 2);
    u16*   PW2b  = (u16*)alloc((size_t)Cc * PH * 2);
    u16*   Hb    = (u16*)alloc((size_t)RT * PH * 2);

    // chunked row pipeline: cap chunk at 16384 rows so Xb+Vb+Ab+Lb (~96 MB)
    // stays L3-resident between producer/consumer kernels.
    const size_t perrow = 1024 + 1024 + 2048 + 2048;  // X,V bf16 + A bf16 + L f32
    int cr = 16384;
    size_t avail = ws_size > off ? ws_size - off : 0;
    if (avail < (size_t)cr * perrow) {
        cr = (int)((avail / perrow) & ~(size_t)127);
        if (cr < 128) cr = 128;
    }
    u16*   Xb = (u16*)alloc((size_t)cr * Cc * 2);
    u16*   Vb = (u16*)alloc((size_t)cr * Cc * 2);
    u16*   Ab = (u16*)alloc((size_t)cr * AH * 2);
    float* Lb = (float*)alloc((size_t)cr * Cc * 4);

    transpose_kernel<<<dim3(Bc * 40 * 8), dim3(256), 0, stream>>>(feat, feat_db, featT);
    prep_kernel<<<dim3((AH * Cc) / 256), dim3(256), 0, stream>>>(aw1, ab1, ag, abb, am, av, aw2, pw2,
                                                                 W1b, bias1, W2b, PW2b);
    knn_kernel<<<dim3(Bc * Nc / 4), dim3(256), 0, stream>>>(pcd, pcd_db, idxb);
    hker<<<dim3(RT / 256), dim3(256), 0, stream>>>(pcd, pcd_db, idxb, pw1, pb1, pg, pbb, pm, pv, Hb);

    for (int r0 = 0; r0 < RT; r0 += cr) {
        int rows = (RT - r0 < cr) ? (RT - r0) : cr;
        pgemm_fused<<<dim3(rows / 128, Cc / 128), dim3(256), 0, stream>>>(Hb, PW2b, pb2, featT, idxb,
                                                                          Xb, Vb, r0);
        gemm_bt<true, true><<<dim3(rows / 128, AH / 128), dim3(256), 0, stream>>>(Xb, W1b, bias1, Ab, rows, AH, Cc);
        gemm_bt<false, false><<<dim3(rows / 128, Cc / 128), dim3(256), 0, stream>>>(Ab, W2b, ab2, Lb, rows, Cc, AH);
        final_kernel<<<dim3(rows / 64), dim3(256), 0, stream>>>(Lb, Vb, out, r0);
    }
}

// Round 10
// 438.415 us; speedup vs baseline: 2.0376x; 1.0015x over previous
//
#include <hip/hip_runtime.h>

typedef unsigned short u16;
typedef unsigned int   u32;
typedef __attribute__((ext_vector_type(8))) short bf16x8;
typedef __attribute__((ext_vector_type(4))) float f32x4;
typedef __attribute__((ext_vector_type(4))) u32   u32x4;

// Problem constants
constexpr int Bc = 2, Cc = 512, Nc = 2048, Mc = 512, Sc = 2560, Kc = 16, PH = 64, AH = 1024;
constexpr int RT = Bc * Nc * Kc;  // 65536 rows (b,n,k)
constexpr float EPS = 1e-5f;

__device__ __forceinline__ u16 f2bf(float f) {
    u32 u = __float_as_uint(f);
    u32 r = (u + 0x7fffu + ((u >> 16) & 1u)) >> 16;  // RNE
    return (u16)r;
}
__device__ __forceinline__ float bf2f(u16 h) { return __uint_as_float(((u32)h) << 16); }

__device__ __forceinline__ void gload_lds16(const void* g, void* l) {
    __builtin_amdgcn_global_load_lds((const __attribute__((address_space(1))) u32*)g,
                                     (__attribute__((address_space(3))) u32*)l, 16, 0, 0);
}

// Bijective XCD-aware workgroup swizzle (m204 form): same-XCD wgs get a
// contiguous run of linear ids. With bn-fastest linearization this makes an
// XCD reuse one A-panel across all bn tiles (L2 locality).
__device__ __forceinline__ void xcd_tiles(u32& bm, u32& bn) {
    u32 gdx = gridDim.x, gdy = gridDim.y;
    u32 nwg = gdx * gdy;
    u32 wg = blockIdx.x + gdx * blockIdx.y;
    u32 q = nwg >> 3, r8 = nwg & 7;
    u32 xcd = wg & 7, loc = wg >> 3;
    u32 swz = (xcd < r8 ? xcd * (q + 1) : r8 * (q + 1) + (xcd - r8) * q) + loc;
    bn = swz % gdy;   // bn fastest within an XCD's contiguous run
    bm = swz / gdy;
}

// ---------------------------------------------------------------------------
// Transpose fusion_feat [B,C,S(split)] f32 -> featT [B,S,C] f32
// ---------------------------------------------------------------------------
__global__ __launch_bounds__(256) void transpose_kernel(const float* __restrict__ feat,
                                                        const float* __restrict__ feat_db,
                                                        float* __restrict__ featT) {
    __shared__ float tile[64][65];
    int bid = blockIdx.x;
    int b = bid / (40 * 8);
    int rem = bid - b * (40 * 8);
    int st = rem >> 3, ct = rem & 7;
    int t = threadIdx.x, lane = t & 63, g = t >> 6;
    int s0 = st * 64, c0 = ct * 64;
    const float* src;
    int sl0, stride;
    if (s0 < Nc) { src = feat + (size_t)b * Cc * Nc; sl0 = s0; stride = Nc; }
    else         { src = feat_db + (size_t)b * Cc * Mc; sl0 = s0 - Nc; stride = Mc; }
#pragma unroll
    for (int i = 0; i < 16; i++) {
        int cl = g * 16 + i;
        tile[cl][lane] = src[(size_t)(c0 + cl) * stride + sl0 + lane];
    }
    __syncthreads();
#pragma unroll
    for (int i = 0; i < 16; i++) {
        int sl = g * 16 + i;
        featT[((size_t)b * Sc + s0 + sl) * Cc + c0 + lane] = tile[lane][sl];
    }
}

// ---------------------------------------------------------------------------
// Weight prep: fold attn BN into W1/bias1, cast attn W1/W2 + pos W2 to bf16
// ---------------------------------------------------------------------------
__global__ __launch_bounds__(256) void prep_kernel(const float* __restrict__ aw1, const float* __restrict__ ab1,
                                                   const float* __restrict__ ag, const float* __restrict__ abb,
                                                   const float* __restrict__ am, const float* __restrict__ av,
                                                   const float* __restrict__ aw2, const float* __restrict__ pw2,
                                                   u16* __restrict__ W1b, float* __restrict__ bias1,
                                                   u16* __restrict__ W2b, u16* __restrict__ PW2b) {
    int i = blockIdx.x * 256 + threadIdx.x;  // grid covers 524288
    if (i < AH * Cc) {
        int o = i >> 9;
        float inv = ag[o] / sqrtf(av[o] + EPS);
        W1b[i] = f2bf(aw1[i] * inv);
    }
    if (i < AH) {
        float inv = ag[i] / sqrtf(av[i] + EPS);
        bias1[i] = ab1[i] * inv + abb[i] - am[i] * inv;
    }
    if (i < Cc * AH) W2b[i] = f2bf(aw2[i]);
    if (i < Cc * PH) PW2b[i] = f2bf(pw2[i]);
}

// ---------------------------------------------------------------------------
// KNN (v1, proven): one wave per query; distances mirror the reference
// decomposition qq + ss - 2*dot, no fma contraction; ties -> smaller index.
// ---------------------------------------------------------------------------
__global__ __launch_bounds__(256) void knn_kernel(const float* __restrict__ pcd,
                                                  const float* __restrict__ pcd_db,
                                                  int* __restrict__ idxout) {
    int t = threadIdx.x, w = t >> 6, l = t & 63;
    int q = blockIdx.x * 4 + w;  // 0..4095
    int b = q >> 11, n = q & (Nc - 1);
    const float* pc = pcd + (size_t)b * 3 * Nc;
    const float* pd = pcd_db + (size_t)b * 3 * Mc;
    float qx = pc[n], qy = pc[Nc + n], qz = pc[2 * Nc + n];
    float qq = __fadd_rn(__fadd_rn(__fmul_rn(qx, qx), __fmul_rn(qy, qy)), __fmul_rn(qz, qz));
    float dist[40];
#pragma unroll
    for (int j = 0; j < 40; j++) {
        int s = j * 64 + l;
        float sx, sy, sz;
        if (s < Nc) { sx = pc[s]; sy = pc[Nc + s]; sz = pc[2 * Nc + s]; }
        else { int ss = s - Nc; sx = pd[ss]; sy = pd[Mc + ss]; sz = pd[2 * Mc + ss]; }
        float ss2 = __fadd_rn(__fadd_rn(__fmul_rn(sx, sx), __fmul_rn(sy, sy)), __fmul_rn(sz, sz));
        float dt  = __fadd_rn(__fadd_rn(__fmul_rn(qx, sx), __fmul_rn(qy, sy)), __fmul_rn(qz, sz));
        dist[j] = __fsub_rn(__fadd_rn(qq, ss2), __fmul_rn(2.0f, dt));
    }
    for (int r = 0; r < 16; r++) {
        float bd = 1e30f;
        int bs = 1 << 30;
#pragma unroll
        for (int j = 0; j < 40; j++) {
            int s = j * 64 + l;
            bool better = (dist[j] < bd) || (dist[j] == bd && s < bs);
            bd = better ? dist[j] : bd;
            bs = better ? s : bs;
        }
        for (int off = 32; off; off >>= 1) {
            float od = __shfl_xor(bd, off);
            int   os = __shfl_xor(bs, off);
            bool better = (od < bd) || (od == bd && os < bs);
            bd = better ? od : bd;
            bs = better ? os : bs;
        }
        if (l == 0) idxout[q * 16 + r] = bs;
        int wj = bs >> 6, wl = bs & 63;
        if (l == wl) {
#pragma unroll
            for (int j = 0; j < 40; j++)
                if (j == wj) dist[j] = 1e30f;
        }
    }
}

// ---------------------------------------------------------------------------
// HKER: per row, pos-MLP layer-1: h[r][64] = relu(BN(W1 (q - s) + b1)) bf16
// ---------------------------------------------------------------------------
__global__ __launch_bounds__(256) void hker(const float* __restrict__ pcd, const float* __restrict__ pcd_db,
                                            const int* __restrict__ idxb,
                                            const float* __restrict__ pw1, const float* __restrict__ pb1,
                                            const float* __restrict__ pg, const float* __restrict__ pbb,
                                            const float* __restrict__ pm, const float* __restrict__ pv,
                                            u16* __restrict__ H) {
    __shared__ float W1s[64][4];
    int t = threadIdx.x;
    if (t < 64) {
        float inv = pg[t] / sqrtf(pv[t] + EPS);
        W1s[t][0] = pw1[t * 3 + 0] * inv;
        W1s[t][1] = pw1[t * 3 + 1] * inv;
        W1s[t][2] = pw1[t * 3 + 2] * inv;
        W1s[t][3] = pb1[t] * inv + pbb[t] - pm[t] * inv;
    }
    __syncthreads();
    int r = blockIdx.x * 256 + t;
    int b = r >> 15, n = (r >> 4) & (Nc - 1), s = idxb[r];
    const float* pc = pcd + (size_t)b * 3 * Nc;
    float qx = pc[n], qy = pc[Nc + n], qz = pc[2 * Nc + n];
    float sx, sy, sz;
    if (s < Nc) { sx = pc[s]; sy = pc[Nc + s]; sz = pc[2 * Nc + s]; }
    else {
        const float* pd = pcd_db + (size_t)b * 3 * Mc;
        int ss = s - Nc;
        sx = pd[ss]; sy = pd[Mc + ss]; sz = pd[2 * Mc + ss];
    }
    float dx = qx - sx, dy = qy - sy, dz = qz - sz;
    u16* hp = H + (size_t)r * 64;
#pragma unroll
    for (int u0 = 0; u0 < 64; u0 += 8) {
        u16 e[8];
#pragma unroll
        for (int j = 0; j < 8; j++) {
            int u = u0 + j;
            float hv = fmaxf(0.f, dx * W1s[u][0] + dy * W1s[u][1] + dz * W1s[u][2] + W1s[u][3]);
            e[j] = f2bf(hv);
        }
        u32x4 pk;
        pk.x = (u32)e[0] | ((u32)e[1] << 16); pk.y = (u32)e[2] | ((u32)e[3] << 16);
        pk.z = (u32)e[4] | ((u32)e[5] << 16); pk.w = (u32)e[6] | ((u32)e[7] << 16);
        *(u32x4*)(hp + u0) = pk;
    }
}

// ---------------------------------------------------------------------------
// PGEMM_FUSED: P = H @ PW2^T + pb2 via MFMA (M=rows, N=512, K=64), epilogue
// gathers f,g from featT and emits X = f-g+p, V = g+p (bf16).
// ---------------------------------------------------------------------------
__global__ __launch_bounds__(256) void pgemm_fused(const u16* __restrict__ Hg, const u16* __restrict__ Bg,
                                                   const float* __restrict__ pb2,
                                                   const float* __restrict__ featT, const int* __restrict__ idxb,
                                                   u16* __restrict__ X, u16* __restrict__ V, int row0) {
    __shared__ u16 As[128 * 64];
    __shared__ u16 Bs[128 * 64];
    const int t = threadIdx.x;
    u32 bmu, bnu;
    xcd_tiles(bmu, bnu);
    const int bm = (int)bmu, bn = (int)bnu;
    const int w = t >> 6, l = t & 63;
    const int wr = w >> 1, wc = w & 1;
    const int fr = l & 15, fq = l >> 4;
    f32x4 acc[4][4];
#pragma unroll
    for (int i = 0; i < 4; i++)
#pragma unroll
        for (int j = 0; j < 4; j++) {
            f32x4 z = {0.f, 0.f, 0.f, 0.f};
            acc[i][j] = z;
        }
    const char* Abase = (const char*)Hg + ((size_t)row0 + (size_t)bm * 128) * 64 * 2;
    const char* Bbase = (const char*)Bg + (size_t)bn * 128 * 64 * 2;
#pragma unroll
    for (int i = 0; i < 4; i++) {
        int chunk = i * 256 + t;
        int row = chunk >> 3;
        int cb = (chunk & 7) * 16;
        gload_lds16(Abase + (size_t)row * 128 + cb, (char*)As + chunk * 16);
    }
#pragma unroll
    for (int i = 0; i < 4; i++) {
        int chunk = i * 256 + t;
        int row = chunk >> 3;
        int cb = (chunk & 7) * 16;
        gload_lds16(Bbase + (size_t)row * 128 + cb, (char*)Bs + chunk * 16);
    }
    __syncthreads();
    bf16x8 af[4][2], bfv[4][2];
#pragma unroll
    for (int mf = 0; mf < 4; mf++)
#pragma unroll
        for (int ks = 0; ks < 2; ks++)
            af[mf][ks] = *(const bf16x8*)&As[(wr * 64 + mf * 16 + fr) * 64 + ks * 32 + fq * 8];
#pragma unroll
    for (int nf = 0; nf < 4; nf++)
#pragma unroll
        for (int ks = 0; ks < 2; ks++)
            bfv[nf][ks] = *(const bf16x8*)&Bs[(wc * 64 + nf * 16 + fr) * 64 + ks * 32 + fq * 8];
#pragma unroll
    for (int mf = 0; mf < 4; mf++)
#pragma unroll
        for (int nf = 0; nf < 4; nf++)
#pragma unroll
            for (int ks = 0; ks < 2; ks++)
                acc[mf][nf] = __builtin_amdgcn_mfma_f32_16x16x32_bf16(af[mf][ks], bfv[nf][ks], acc[mf][nf], 0, 0, 0);
    // epilogue: per C-row gather f,g; emit X,V
#pragma unroll
    for (int mf = 0; mf < 4; mf++) {
#pragma unroll
        for (int r = 0; r < 4; r++) {
            int gr = bm * 128 + wr * 64 + mf * 16 + fq * 4 + r;  // chunk-local row
            int grow = row0 + gr;                                 // global row
            int b = grow >> 15;
            int n = (grow >> 4) & (Nc - 1);
            int s = idxb[grow];
            const float* frow = featT + ((size_t)b * Sc + n) * Cc;
            const float* grow_p = featT + ((size_t)b * Sc + s) * Cc;
#pragma unroll
            for (int nf = 0; nf < 4; nf++) {
                int gn = bn * 128 + wc * 64 + nf * 16 + fr;
                float p = acc[mf][nf][r] + pb2[gn];
                float fv = frow[gn];
                float gv = grow_p[gn];
                X[(size_t)gr * Cc + gn] = f2bf(fv - gv + p);
                V[(size_t)gr * Cc + gn] = f2bf(gv + p);
            }
        }
    }
}

// ---------------------------------------------------------------------------
// GEMM (m97 structure + XCD swizzle): C[m][n] = f(sum_k A[m][k]*B[n][k]+bias)
// A [M][Kd] bf16, B [N][Kd] bf16 (i.e. B^T layout), 128x128 tile, BK=64.
// ---------------------------------------------------------------------------
template <bool RELU, bool OBF16>
__global__ __launch_bounds__(256) void gemm_bt(const u16* __restrict__ Ag, const u16* __restrict__ Bg,
                                               const float* __restrict__ bias, void* __restrict__ Cg,
                                               int M, int N, int Kd) {
    __shared__ u16 As[128 * 64];
    __shared__ u16 Bs[128 * 64];
    const int t = threadIdx.x;
    u32 bmu, bnu;
    xcd_tiles(bmu, bnu);
    const int bm = (int)bmu, bn = (int)bnu;
    const int w = t >> 6, l = t & 63;
    const int wr = w >> 1, wc = w & 1;
    const int fr = l & 15, fq = l >> 4;
    f32x4 acc[4][4];
#pragma unroll
    for (int i = 0; i < 4; i++)
#pragma unroll
        for (int j = 0; j < 4; j++) {
            f32x4 z = {0.f, 0.f, 0.f, 0.f};
            acc[i][j] = z;
        }
    const char* Abase = (const char*)Ag + (size_t)bm * 128 * (size_t)Kd * 2;
    const char* Bbase = (const char*)Bg + (size_t)bn * 128 * (size_t)Kd * 2;
    const size_t ldb = (size_t)Kd * 2;

    for (int kt = 0; kt < Kd; kt += 64) {
#pragma unroll
        for (int i = 0; i < 4; i++) {
            int chunk = i * 256 + t;
            int row = chunk >> 3;
            int cb = (chunk & 7) * 16;
            gload_lds16(Abase + (size_t)row * ldb + (size_t)kt * 2 + cb, (char*)As + chunk * 16);
        }
#pragma unroll
        for (int i = 0; i < 4; i++) {
            int chunk = i * 256 + t;
            int row = chunk >> 3;
            int cb = (chunk & 7) * 16;
            gload_lds16(Bbase + (size_t)row * ldb + (size_t)kt * 2 + cb, (char*)Bs + chunk * 16);
        }
        __syncthreads();
        bf16x8 af[4][2], bfv[4][2];
#pragma unroll
        for (int mf = 0; mf < 4; mf++)
#pragma unroll
            for (int ks = 0; ks < 2; ks++)
                af[mf][ks] = *(const bf16x8*)&As[(wr * 64 + mf * 16 + fr) * 64 + ks * 32 + fq * 8];
#pragma unroll
        for (int nf = 0; nf < 4; nf++)
#pragma unroll
            for (int ks = 0; ks < 2; ks++)
                bfv[nf][ks] = *(const bf16x8*)&Bs[(wc * 64 + nf * 16 + fr) * 64 + ks * 32 + fq * 8];
#pragma unroll
        for (int mf = 0; mf < 4; mf++)
#pragma unroll
            for (int nf = 0; nf < 4; nf++)
#pragma unroll
                for (int ks = 0; ks < 2; ks++)
                    acc[mf][nf] = __builtin_amdgcn_mfma_f32_16x16x32_bf16(af[mf][ks], bfv[nf][ks], acc[mf][nf], 0, 0, 0);
        __syncthreads();
    }
#pragma unroll
    for (int mf = 0; mf < 4; mf++) {
#pragma unroll
        for (int nf = 0; nf < 4; nf++) {
            int gn = bn * 128 + wc * 64 + nf * 16 + fr;
            float bi = bias[gn];
            int gm0 = bm * 128 + wr * 64 + mf * 16 + fq * 4;
#pragma unroll
            for (int r = 0; r < 4; r++) {
                float v = acc[mf][nf][r] + bi;
                if (RELU) v = fmaxf(v, 0.f);
                size_t o = (size_t)(gm0 + r) * N + gn;
                if (OBF16) ((u16*)Cg)[o] = f2bf(v);
                else ((float*)Cg)[o] = v;
            }
        }
    }
}

// ---------------------------------------------------------------------------
// FINAL: per point (16 rows), per channel: softmax over k, weighted sum of V
// ---------------------------------------------------------------------------
__global__ __launch_bounds__(256) void final_kernel(const float* __restrict__ L, const u16* __restrict__ V,
                                                    float* __restrict__ out, int row0) {
    int t = threadIdx.x, w = t >> 6, l = t & 63;
    int p = blockIdx.x * 4 + w;  // chunk-local point
    int lr = p * 16;
    int gp = row0 / 16 + p;
    int b = gp >> 11, n = gp & (Nc - 1);
    const float* Lp = L + (size_t)lr * Cc;
    const u16* Vp = V + (size_t)lr * Cc;
#pragma unroll 1
    for (int j = 0; j < 8; j++) {
        int c = l + 64 * j;
        float lv[16];
#pragma unroll
        for (int k = 0; k < 16; k++) lv[k] = Lp[(size_t)k * Cc + c];
        float mx = lv[0];
#pragma unroll
        for (int k = 1; k < 16; k++) mx = fmaxf(mx, lv[k]);
        float ssum = 0.f;
#pragma unroll
        for (int k = 0; k < 16; k++) {
            lv[k] = __expf(lv[k] - mx);
            ssum += lv[k];
        }
        float acc = 0.f;
#pragma unroll
        for (int k = 0; k < 16; k++) acc += lv[k] * bf2f(Vp[(size_t)k * Cc + c]);
        out[((size_t)b * Cc + c) * Nc + n] = acc / ssum;
    }
}

// ---------------------------------------------------------------------------
extern "C" void kernel_launch(void* const* d_in, const int* in_sizes, int n_in,
                              void* d_out, int out_size, void* d_ws, size_t ws_size,
                              hipStream_t stream) {
    (void)in_sizes; (void)n_in; (void)out_size;
    const float* pcd     = (const float*)d_in[0];
    const float* feat    = (const float*)d_in[1];
    const float* pcd_db  = (const float*)d_in[2];
    const float* feat_db = (const float*)d_in[3];
    const float* pw1 = (const float*)d_in[4];
    const float* pb1 = (const float*)d_in[5];
    const float* pg  = (const float*)d_in[6];
    const float* pbb = (const float*)d_in[7];
    const float* pm  = (const float*)d_in[8];
    const float* pv  = (const float*)d_in[9];
    const float* pw2 = (const float*)d_in[10];
    const float* pb2 = (const float*)d_in[11];
    const float* aw1 = (const float*)d_in[12];
    const float* ab1 = (const float*)d_in[13];
    const float* ag  = (const float*)d_in[14];
    const float* abb = (const float*)d_in[15];
    const float* am  = (const float*)d_in[16];
    const float* av  = (const float*)d_in[17];
    const float* aw2 = (const float*)d_in[18];
    const float* ab2 = (const float*)d_in[19];
    float* out = (float*)d_out;

    char* base = (char*)d_ws;
    size_t off = 0;
    auto alloc = [&](size_t bytes) -> char* {
        char* r = base + off;
        off = (off + bytes + 255) & ~(size_t)255;
        return r;
    };
    int*   idxb  = (int*)alloc((size_t)RT * 4);
    float* featT = (float*)alloc((size_t)Bc * Sc * Cc * 4);
    u16*   W1b   = (u16*)alloc((size_t)AH * Cc * 2);
    float* bias1 = (float*)alloc((size_t)AH * 4);
    u16*   W2b   = (u16*)alloc((size_t)Cc * AH * 2);
    u16*   PW2b  = (u16*)alloc((size_t)Cc * PH * 2);
    u16*   Hb    = (u16*)alloc((size_t)RT * PH * 2);

    // chunked row pipeline: cap chunk at 16384 rows so Xb+Vb+Ab+Lb (~96 MB)
    // stays L3-resident between producer/consumer kernels.
    const size_t perrow = 1024 + 1024 + 2048 + 2048;  // X,V bf16 + A bf16 + L f32
    int cr = 16384;
    size_t avail = ws_size > off ? ws_size - off : 0;
    if (avail < (size_t)cr * perrow) {
        cr = (int)((avail / perrow) & ~(size_t)127);
        if (cr < 128) cr = 128;
    }
    u16*   Xb = (u16*)alloc((size_t)cr * Cc * 2);
    u16*   Vb = (u16*)alloc((size_t)cr * Cc * 2);
    u16*   Ab = (u16*)alloc((size_t)cr * AH * 2);
    float* Lb = (float*)alloc((size_t)cr * Cc * 4);

    transpose_kernel<<<dim3(Bc * 40 * 8), dim3(256), 0, stream>>>(feat, feat_db, featT);
    prep_kernel<<<dim3((AH * Cc) / 256), dim3(256), 0, stream>>>(aw1, ab1, ag, abb, am, av, aw2, pw2,
                                                                 W1b, bias1, W2b, PW2b);
    knn_kernel<<<dim3(Bc * Nc / 4), dim3(256), 0, stream>>>(pcd, pcd_db, idxb);
    hker<<<dim3(RT / 256), dim3(256), 0, stream>>>(pcd, pcd_db, idxb, pw1, pb1, pg, pbb, pm, pv, Hb);

    for (int r0 = 0; r0 < RT; r0 += cr) {
        int rows = (RT - r0 < cr) ? (RT - r0) : cr;
        pgemm_fused<<<dim3(rows / 128, Cc / 128), dim3(256), 0, stream>>>(Hb, PW2b, pb2, featT, idxb,
                                                                          Xb, Vb, r0);
        gemm_bt<true, true><<<dim3(rows / 128, AH / 128), dim3(256), 0, stream>>>(Xb, W1b, bias1, Ab, rows, AH, Cc);
        gemm_bt<false, false><<<dim3(rows / 128, Cc / 128), dim3(256), 0, stream>>>(Ab, W2b, ab2, Lb, rows, Cc, AH);
        final_kernel<<<dim3(rows / 64), dim3(256), 0, stream>>>(Lb, Vb, out, r0);
    }
}

// Round 11
// 399.107 us; speedup vs baseline: 2.2383x; 1.0985x over previous
//
#include <hip/hip_runtime.h>

typedef unsigned short u16;
typedef unsigned int   u32;
typedef __attribute__((ext_vector_type(8))) short bf16x8;
typedef __attribute__((ext_vector_type(4))) float f32x4;
typedef __attribute__((ext_vector_type(4))) u32   u32x4;

// Problem constants
constexpr int Bc = 2, Cc = 512, Nc = 2048, Mc = 512, Sc = 2560, Kc = 16, PH = 64, AH = 1024;
constexpr int RT = Bc * Nc * Kc;  // 65536 rows (b,n,k)
constexpr float EPS = 1e-5f;

__device__ __forceinline__ u16 f2bf(float f) {
    u32 u = __float_as_uint(f);
    u32 r = (u + 0x7fffu + ((u >> 16) & 1u)) >> 16;  // RNE
    return (u16)r;
}
__device__ __forceinline__ float bf2f(u16 h) { return __uint_as_float(((u32)h) << 16); }

__device__ __forceinline__ void gload_lds16(const void* g, void* l) {
    __builtin_amdgcn_global_load_lds((const __attribute__((address_space(1))) u32*)g,
                                     (__attribute__((address_space(3))) u32*)l, 16, 0, 0);
}

// Bijective XCD-aware workgroup swizzle (m204 form): same-XCD wgs get a
// contiguous run of linear ids. With bn-fastest linearization this makes an
// XCD reuse one A-panel across all bn tiles (L2 locality).
__device__ __forceinline__ void xcd_tiles(u32& bm, u32& bn) {
    u32 gdx = gridDim.x, gdy = gridDim.y;
    u32 nwg = gdx * gdy;
    u32 wg = blockIdx.x + gdx * blockIdx.y;
    u32 q = nwg >> 3, r8 = nwg & 7;
    u32 xcd = wg & 7, loc = wg >> 3;
    u32 swz = (xcd < r8 ? xcd * (q + 1) : r8 * (q + 1) + (xcd - r8) * q) + loc;
    bn = swz % gdy;   // bn fastest within an XCD's contiguous run
    bm = swz / gdy;
}

// lex-min on (d, s): total order, associative -> tree order == scan order
__device__ __forceinline__ void lmin(float& da, int& sa, float db, int sb) {
    bool better = (db < da) || (db == da && sb < sa);
    da = better ? db : da;
    sa = better ? sb : sa;
}

// ---------------------------------------------------------------------------
// Transpose fusion_feat [B,C,S(split)] f32 -> featT [B,S,C] f32
// ---------------------------------------------------------------------------
__global__ __launch_bounds__(256) void transpose_kernel(const float* __restrict__ feat,
                                                        const float* __restrict__ feat_db,
                                                        float* __restrict__ featT) {
    __shared__ float tile[64][65];
    int bid = blockIdx.x;
    int b = bid / (40 * 8);
    int rem = bid - b * (40 * 8);
    int st = rem >> 3, ct = rem & 7;
    int t = threadIdx.x, lane = t & 63, g = t >> 6;
    int s0 = st * 64, c0 = ct * 64;
    const float* src;
    int sl0, stride;
    if (s0 < Nc) { src = feat + (size_t)b * Cc * Nc; sl0 = s0; stride = Nc; }
    else         { src = feat_db + (size_t)b * Cc * Mc; sl0 = s0 - Nc; stride = Mc; }
#pragma unroll
    for (int i = 0; i < 16; i++) {
        int cl = g * 16 + i;
        tile[cl][lane] = src[(size_t)(c0 + cl) * stride + sl0 + lane];
    }
    __syncthreads();
#pragma unroll
    for (int i = 0; i < 16; i++) {
        int sl = g * 16 + i;
        featT[((size_t)b * Sc + s0 + sl) * Cc + c0 + lane] = tile[lane][sl];
    }
}

// ---------------------------------------------------------------------------
// Weight prep: fold attn BN into W1/bias1, cast attn W1/W2 + pos W2 to bf16
// ---------------------------------------------------------------------------
__global__ __launch_bounds__(256) void prep_kernel(const float* __restrict__ aw1, const float* __restrict__ ab1,
                                                   const float* __restrict__ ag, const float* __restrict__ abb,
                                                   const float* __restrict__ am, const float* __restrict__ av,
                                                   const float* __restrict__ aw2, const float* __restrict__ pw2,
                                                   u16* __restrict__ W1b, float* __restrict__ bias1,
                                                   u16* __restrict__ W2b, u16* __restrict__ PW2b) {
    int i = blockIdx.x * 256 + threadIdx.x;  // grid covers 524288
    if (i < AH * Cc) {
        int o = i >> 9;
        float inv = ag[o] / sqrtf(av[o] + EPS);
        W1b[i] = f2bf(aw1[i] * inv);
    }
    if (i < AH) {
        float inv = ag[i] / sqrtf(av[i] + EPS);
        bias1[i] = ab1[i] * inv + abb[i] - am[i] * inv;
    }
    if (i < Cc * AH) W2b[i] = f2bf(aw2[i]);
    if (i < Cc * PH) PW2b[i] = f2bf(pw2[i]);
}

// ---------------------------------------------------------------------------
// KNN (v1 + tree-scan): one wave per query; distances mirror the reference
// decomposition qq + ss - 2*dot, no fma contraction; ties -> smaller index.
// Per-round argmin re-associated as a balanced tree (same total order ->
// bit-identical winner, ~6x shorter dependence chain).
// ---------------------------------------------------------------------------
__global__ __launch_bounds__(256) void knn_kernel(const float* __restrict__ pcd,
                                                  const float* __restrict__ pcd_db,
                                                  int* __restrict__ idxout) {
    int t = threadIdx.x, w = t >> 6, l = t & 63;
    int q = blockIdx.x * 4 + w;  // 0..4095
    int b = q >> 11, n = q & (Nc - 1);
    const float* pc = pcd + (size_t)b * 3 * Nc;
    const float* pd = pcd_db + (size_t)b * 3 * Mc;
    float qx = pc[n], qy = pc[Nc + n], qz = pc[2 * Nc + n];
    float qq = __fadd_rn(__fadd_rn(__fmul_rn(qx, qx), __fmul_rn(qy, qy)), __fmul_rn(qz, qz));
    float dist[40];
#pragma unroll
    for (int j = 0; j < 40; j++) {
        int s = j * 64 + l;
        float sx, sy, sz;
        if (s < Nc) { sx = pc[s]; sy = pc[Nc + s]; sz = pc[2 * Nc + s]; }
        else { int ss = s - Nc; sx = pd[ss]; sy = pd[Mc + ss]; sz = pd[2 * Mc + ss]; }
        float ss2 = __fadd_rn(__fadd_rn(__fmul_rn(sx, sx), __fmul_rn(sy, sy)), __fmul_rn(sz, sz));
        float dt  = __fadd_rn(__fadd_rn(__fmul_rn(qx, sx), __fmul_rn(qy, sy)), __fmul_rn(qz, sz));
        dist[j] = __fsub_rn(__fadd_rn(qq, ss2), __fmul_rn(2.0f, dt));
    }
    for (int r = 0; r < 16; r++) {
        // tree lex-min over the 40 (dist[j], j*64+l) pairs
        float td[20];
        int   ts[20];
#pragma unroll
        for (int i = 0; i < 20; i++) {
            float d0 = dist[2 * i], d1 = dist[2 * i + 1];
            int s0 = (2 * i) * 64 + l, s1 = (2 * i + 1) * 64 + l;
            bool bt = (d1 < d0) || (d1 == d0 && s1 < s0);
            td[i] = bt ? d1 : d0;
            ts[i] = bt ? s1 : s0;
        }
#pragma unroll
        for (int i = 0; i < 10; i++) lmin(td[i], ts[i], td[i + 10], ts[i + 10]);
#pragma unroll
        for (int i = 0; i < 5; i++) lmin(td[i], ts[i], td[i + 5], ts[i + 5]);
        lmin(td[0], ts[0], td[3], ts[3]);
        lmin(td[1], ts[1], td[4], ts[4]);
        lmin(td[0], ts[0], td[2], ts[2]);
        lmin(td[0], ts[0], td[1], ts[1]);
        float bd = td[0];
        int   bs = ts[0];
        for (int off = 32; off; off >>= 1) {
            float od = __shfl_xor(bd, off);
            int   os = __shfl_xor(bs, off);
            bool better = (od < bd) || (od == bd && os < bs);
            bd = better ? od : bd;
            bs = better ? os : bs;
        }
        if (l == 0) idxout[q * 16 + r] = bs;
        int wj = bs >> 6, wl = bs & 63;
        if (l == wl) {
#pragma unroll
            for (int j = 0; j < 40; j++)
                if (j == wj) dist[j] = 1e30f;
        }
    }
}

// ---------------------------------------------------------------------------
// HKER: per row, pos-MLP layer-1: h[r][64] = relu(BN(W1 (q - s) + b1)) bf16
// ---------------------------------------------------------------------------
__global__ __launch_bounds__(256) void hker(const float* __restrict__ pcd, const float* __restrict__ pcd_db,
                                            const int* __restrict__ idxb,
                                            const float* __restrict__ pw1, const float* __restrict__ pb1,
                                            const float* __restrict__ pg, const float* __restrict__ pbb,
                                            const float* __restrict__ pm, const float* __restrict__ pv,
                                            u16* __restrict__ H) {
    __shared__ float W1s[64][4];
    int t = threadIdx.x;
    if (t < 64) {
        float inv = pg[t] / sqrtf(pv[t] + EPS);
        W1s[t][0] = pw1[t * 3 + 0] * inv;
        W1s[t][1] = pw1[t * 3 + 1] * inv;
        W1s[t][2] = pw1[t * 3 + 2] * inv;
        W1s[t][3] = pb1[t] * inv + pbb[t] - pm[t] * inv;
    }
    __syncthreads();
    int r = blockIdx.x * 256 + t;
    int b = r >> 15, n = (r >> 4) & (Nc - 1), s = idxb[r];
    const float* pc = pcd + (size_t)b * 3 * Nc;
    float qx = pc[n], qy = pc[Nc + n], qz = pc[2 * Nc + n];
    float sx, sy, sz;
    if (s < Nc) { sx = pc[s]; sy = pc[Nc + s]; sz = pc[2 * Nc + s]; }
    else {
        const float* pd = pcd_db + (size_t)b * 3 * Mc;
        int ss = s - Nc;
        sx = pd[ss]; sy = pd[Mc + ss]; sz = pd[2 * Mc + ss];
    }
    float dx = qx - sx, dy = qy - sy, dz = qz - sz;
    u16* hp = H + (size_t)r * 64;
#pragma unroll
    for (int u0 = 0; u0 < 64; u0 += 8) {
        u16 e[8];
#pragma unroll
        for (int j = 0; j < 8; j++) {
            int u = u0 + j;
            float hv = fmaxf(0.f, dx * W1s[u][0] + dy * W1s[u][1] + dz * W1s[u][2] + W1s[u][3]);
            e[j] = f2bf(hv);
        }
        u32x4 pk;
        pk.x = (u32)e[0] | ((u32)e[1] << 16); pk.y = (u32)e[2] | ((u32)e[3] << 16);
        pk.z = (u32)e[4] | ((u32)e[5] << 16); pk.w = (u32)e[6] | ((u32)e[7] << 16);
        *(u32x4*)(hp + u0) = pk;
    }
}

// ---------------------------------------------------------------------------
// PGEMM_FUSED: P = H @ PW2^T + pb2 via MFMA (M=rows, N=512, K=64), epilogue
// gathers f,g from featT and emits X = f-g+p, V = g+p (bf16).
// ---------------------------------------------------------------------------
__global__ __launch_bounds__(256) void pgemm_fused(const u16* __restrict__ Hg, const u16* __restrict__ Bg,
                                                   const float* __restrict__ pb2,
                                                   const float* __restrict__ featT, const int* __restrict__ idxb,
                                                   u16* __restrict__ X, u16* __restrict__ V, int row0) {
    __shared__ u16 As[128 * 64];
    __shared__ u16 Bs[128 * 64];
    const int t = threadIdx.x;
    u32 bmu, bnu;
    xcd_tiles(bmu, bnu);
    const int bm = (int)bmu, bn = (int)bnu;
    const int w = t >> 6, l = t & 63;
    const int wr = w >> 1, wc = w & 1;
    const int fr = l & 15, fq = l >> 4;
    f32x4 acc[4][4];
#pragma unroll
    for (int i = 0; i < 4; i++)
#pragma unroll
        for (int j = 0; j < 4; j++) {
            f32x4 z = {0.f, 0.f, 0.f, 0.f};
            acc[i][j] = z;
        }
    const char* Abase = (const char*)Hg + ((size_t)row0 + (size_t)bm * 128) * 64 * 2;
    const char* Bbase = (const char*)Bg + (size_t)bn * 128 * 64 * 2;
#pragma unroll
    for (int i = 0; i < 4; i++) {
        int chunk = i * 256 + t;
        int row = chunk >> 3;
        int cb = (chunk & 7) * 16;
        gload_lds16(Abase + (size_t)row * 128 + cb, (char*)As + chunk * 16);
    }
#pragma unroll
    for (int i = 0; i < 4; i++) {
        int chunk = i * 256 + t;
        int row = chunk >> 3;
        int cb = (chunk & 7) * 16;
        gload_lds16(Bbase + (size_t)row * 128 + cb, (char*)Bs + chunk * 16);
    }
    __syncthreads();
    bf16x8 af[4][2], bfv[4][2];
#pragma unroll
    for (int mf = 0; mf < 4; mf++)
#pragma unroll
        for (int ks = 0; ks < 2; ks++)
            af[mf][ks] = *(const bf16x8*)&As[(wr * 64 + mf * 16 + fr) * 64 + ks * 32 + fq * 8];
#pragma unroll
    for (int nf = 0; nf < 4; nf++)
#pragma unroll
        for (int ks = 0; ks < 2; ks++)
            bfv[nf][ks] = *(const bf16x8*)&Bs[(wc * 64 + nf * 16 + fr) * 64 + ks * 32 + fq * 8];
#pragma unroll
    for (int mf = 0; mf < 4; mf++)
#pragma unroll
        for (int nf = 0; nf < 4; nf++)
#pragma unroll
            for (int ks = 0; ks < 2; ks++)
                acc[mf][nf] = __builtin_amdgcn_mfma_f32_16x16x32_bf16(af[mf][ks], bfv[nf][ks], acc[mf][nf], 0, 0, 0);
    // epilogue: per C-row gather f,g; emit X,V
#pragma unroll
    for (int mf = 0; mf < 4; mf++) {
#pragma unroll
        for (int r = 0; r < 4; r++) {
            int gr = bm * 128 + wr * 64 + mf * 16 + fq * 4 + r;  // chunk-local row
            int grow = row0 + gr;                                 // global row
            int b = grow >> 15;
            int n = (grow >> 4) & (Nc - 1);
            int s = idxb[grow];
            const float* frow = featT + ((size_t)b * Sc + n) * Cc;
            const float* grow_p = featT + ((size_t)b * Sc + s) * Cc;
#pragma unroll
            for (int nf = 0; nf < 4; nf++) {
                int gn = bn * 128 + wc * 64 + nf * 16 + fr;
                float p = acc[mf][nf][r] + pb2[gn];
                float fv = frow[gn];
                float gv = grow_p[gn];
                X[(size_t)gr * Cc + gn] = f2bf(fv - gv + p);
                V[(size_t)gr * Cc + gn] = f2bf(gv + p);
            }
        }
    }
}

// ---------------------------------------------------------------------------
// GEMM (m97 structure + XCD swizzle): C[m][n] = f(sum_k A[m][k]*B[n][k]+bias)
// A [M][Kd] bf16, B [N][Kd] bf16 (i.e. B^T layout), 128x128 tile, BK=64.
// ---------------------------------------------------------------------------
template <bool RELU, bool OBF16>
__global__ __launch_bounds__(256) void gemm_bt(const u16* __restrict__ Ag, const u16* __restrict__ Bg,
                                               const float* __restrict__ bias, void* __restrict__ Cg,
                                               int M, int N, int Kd) {
    __shared__ u16 As[128 * 64];
    __shared__ u16 Bs[128 * 64];
    const int t = threadIdx.x;
    u32 bmu, bnu;
    xcd_tiles(bmu, bnu);
    const int bm = (int)bmu, bn = (int)bnu;
    const int w = t >> 6, l = t & 63;
    const int wr = w >> 1, wc = w & 1;
    const int fr = l & 15, fq = l >> 4;
    f32x4 acc[4][4];
#pragma unroll
    for (int i = 0; i < 4; i++)
#pragma unroll
        for (int j = 0; j < 4; j++) {
            f32x4 z = {0.f, 0.f, 0.f, 0.f};
            acc[i][j] = z;
        }
    const char* Abase = (const char*)Ag + (size_t)bm * 128 * (size_t)Kd * 2;
    const char* Bbase = (const char*)Bg + (size_t)bn * 128 * (size_t)Kd * 2;
    const size_t ldb = (size_t)Kd * 2;

    for (int kt = 0; kt < Kd; kt += 64) {
#pragma unroll
        for (int i = 0; i < 4; i++) {
            int chunk = i * 256 + t;
            int row = chunk >> 3;
            int cb = (chunk & 7) * 16;
            gload_lds16(Abase + (size_t)row * ldb + (size_t)kt * 2 + cb, (char*)As + chunk * 16);
        }
#pragma unroll
        for (int i = 0; i < 4; i++) {
            int chunk = i * 256 + t;
            int row = chunk >> 3;
            int cb = (chunk & 7) * 16;
            gload_lds16(Bbase + (size_t)row * ldb + (size_t)kt * 2 + cb, (char*)Bs + chunk * 16);
        }
        __syncthreads();
        bf16x8 af[4][2], bfv[4][2];
#pragma unroll
        for (int mf = 0; mf < 4; mf++)
#pragma unroll
            for (int ks = 0; ks < 2; ks++)
                af[mf][ks] = *(const bf16x8*)&As[(wr * 64 + mf * 16 + fr) * 64 + ks * 32 + fq * 8];
#pragma unroll
        for (int nf = 0; nf < 4; nf++)
#pragma unroll
            for (int ks = 0; ks < 2; ks++)
                bfv[nf][ks] = *(const bf16x8*)&Bs[(wc * 64 + nf * 16 + fr) * 64 + ks * 32 + fq * 8];
#pragma unroll
        for (int mf = 0; mf < 4; mf++)
#pragma unroll
            for (int nf = 0; nf < 4; nf++)
#pragma unroll
                for (int ks = 0; ks < 2; ks++)
                    acc[mf][nf] = __builtin_amdgcn_mfma_f32_16x16x32_bf16(af[mf][ks], bfv[nf][ks], acc[mf][nf], 0, 0, 0);
        __syncthreads();
    }
#pragma unroll
    for (int mf = 0; mf < 4; mf++) {
#pragma unroll
        for (int nf = 0; nf < 4; nf++) {
            int gn = bn * 128 + wc * 64 + nf * 16 + fr;
            float bi = bias[gn];
            int gm0 = bm * 128 + wr * 64 + mf * 16 + fq * 4;
#pragma unroll
            for (int r = 0; r < 4; r++) {
                float v = acc[mf][nf][r] + bi;
                if (RELU) v = fmaxf(v, 0.f);
                size_t o = (size_t)(gm0 + r) * N + gn;
                if (OBF16) ((u16*)Cg)[o] = f2bf(v);
                else ((float*)Cg)[o] = v;
            }
        }
    }
}

// ---------------------------------------------------------------------------
// FINAL: per point (16 rows), per channel: softmax over k, weighted sum of V
// ---------------------------------------------------------------------------
__global__ __launch_bounds__(256) void final_kernel(const float* __restrict__ L, const u16* __restrict__ V,
                                                    float* __restrict__ out, int row0) {
    int t = threadIdx.x, w = t >> 6, l = t & 63;
    int p = blockIdx.x * 4 + w;  // chunk-local point
    int lr = p * 16;
    int gp = row0 / 16 + p;
    int b = gp >> 11, n = gp & (Nc - 1);
    const float* Lp = L + (size_t)lr * Cc;
    const u16* Vp = V + (size_t)lr * Cc;
#pragma unroll 1
    for (int j = 0; j < 8; j++) {
        int c = l + 64 * j;
        float lv[16];
#pragma unroll
        for (int k = 0; k < 16; k++) lv[k] = Lp[(size_t)k * Cc + c];
        float mx = lv[0];
#pragma unroll
        for (int k = 1; k < 16; k++) mx = fmaxf(mx, lv[k]);
        float ssum = 0.f;
#pragma unroll
        for (int k = 0; k < 16; k++) {
            lv[k] = __expf(lv[k] - mx);
            ssum += lv[k];
        }
        float acc = 0.f;
#pragma unroll
        for (int k = 0; k < 16; k++) acc += lv[k] * bf2f(Vp[(size_t)k * Cc + c]);
        out[((size_t)b * Cc + c) * Nc + n] = acc / ssum;
    }
}

// ---------------------------------------------------------------------------
extern "C" void kernel_launch(void* const* d_in, const int* in_sizes, int n_in,
                              void* d_out, int out_size, void* d_ws, size_t ws_size,
                              hipStream_t stream) {
    (void)in_sizes; (void)n_in; (void)out_size;
    const float* pcd     = (const float*)d_in[0];
    const float* feat    = (const float*)d_in[1];
    const float* pcd_db  = (const float*)d_in[2];
    const float* feat_db = (const float*)d_in[3];
    const float* pw1 = (const float*)d_in[4];
    const float* pb1 = (const float*)d_in[5];
    const float* pg  = (const float*)d_in[6];
    const float* pbb = (const float*)d_in[7];
    const float* pm  = (const float*)d_in[8];
    const float* pv  = (const float*)d_in[9];
    const float* pw2 = (const float*)d_in[10];
    const float* pb2 = (const float*)d_in[11];
    const float* aw1 = (const float*)d_in[12];
    const float* ab1 = (const float*)d_in[13];
    const float* ag  = (const float*)d_in[14];
    const float* abb = (const float*)d_in[15];
    const float* am  = (const float*)d_in[16];
    const float* av  = (const float*)d_in[17];
    const float* aw2 = (const float*)d_in[18];
    const float* ab2 = (const float*)d_in[19];
    float* out = (float*)d_out;

    char* base = (char*)d_ws;
    size_t off = 0;
    auto alloc = [&](size_t bytes) -> char* {
        char* r = base + off;
        off = (off + bytes + 255) & ~(size_t)255;
        return r;
    };
    int*   idxb  = (int*)alloc((size_t)RT * 4);
    float* featT = (float*)alloc((size_t)Bc * Sc * Cc * 4);
    u16*   W1b   = (u16*)alloc((size_t)AH * Cc * 2);
    float* bias1 = (float*)alloc((size_t)AH * 4);
    u16*   W2b   = (u16*)alloc((size_t)Cc * AH * 2);
    u16*   PW2b  = (u16*)alloc((size_t)Cc * PH * 2);
    u16*   Hb    = (u16*)alloc((size_t)RT * PH * 2);

    // chunked row pipeline: cap chunk at 16384 rows so Xb+Vb+Ab+Lb (~96 MB)
    // stays L3-resident between producer/consumer kernels.
    const size_t perrow = 1024 + 1024 + 2048 + 2048;  // X,V bf16 + A bf16 + L f32
    int cr = 16384;
    size_t avail = ws_size > off ? ws_size - off : 0;
    if (avail < (size_t)cr * perrow) {
        cr = (int)((avail / perrow) & ~(size_t)127);
        if (cr < 128) cr = 128;
    }
    u16*   Xb = (u16*)alloc((size_t)cr * Cc * 2);
    u16*   Vb = (u16*)alloc((size_t)cr * Cc * 2);
    u16*   Ab = (u16*)alloc((size_t)cr * AH * 2);
    float* Lb = (float*)alloc((size_t)cr * Cc * 4);

    transpose_kernel<<<dim3(Bc * 40 * 8), dim3(256), 0, stream>>>(feat, feat_db, featT);
    prep_kernel<<<dim3((AH * Cc) / 256), dim3(256), 0, stream>>>(aw1, ab1, ag, abb, am, av, aw2, pw2,
                                                                 W1b, bias1, W2b, PW2b);
    knn_kernel<<<dim3(Bc * Nc / 4), dim3(256), 0, stream>>>(pcd, pcd_db, idxb);
    hker<<<dim3(RT / 256), dim3(256), 0, stream>>>(pcd, pcd_db, idxb, pw1, pb1, pg, pbb, pm, pv, Hb);

    for (int r0 = 0; r0 < RT; r0 += cr) {
        int rows = (RT - r0 < cr) ? (RT - r0) : cr;
        pgemm_fused<<<dim3(rows / 128, Cc / 128), dim3(256), 0, stream>>>(Hb, PW2b, pb2, featT, idxb,
                                                                          Xb, Vb, r0);
        gemm_bt<true, true><<<dim3(rows / 128, AH / 128), dim3(256), 0, stream>>>(Xb, W1b, bias1, Ab, rows, AH, Cc);
        gemm_bt<false, false><<<dim3(rows / 128, Cc / 128), dim3(256), 0, stream>>>(Ab, W2b, ab2, Lb, rows, Cc, AH);
        final_kernel<<<dim3(rows / 64), dim3(256), 0, stream>>>(Lb, Vb, out, r0);
    }
}

// Round 12
// 361.658 us; speedup vs baseline: 2.4700x; 1.1035x over previous
//
#include <hip/hip_runtime.h>

typedef unsigned short u16;
typedef unsigned int   u32;
typedef __attribute__((ext_vector_type(8))) short bf16x8;
typedef __attribute__((ext_vector_type(4))) float f32x4;
typedef __attribute__((ext_vector_type(4))) u32   u32x4;

// Problem constants
constexpr int Bc = 2, Cc = 512, Nc = 2048, Mc = 512, Sc = 2560, Kc = 16, PH = 64, AH = 1024;
constexpr int RT = Bc * Nc * Kc;  // 65536 rows (b,n,k)
constexpr float EPS = 1e-5f;

__device__ __forceinline__ u16 f2bf(float f) {
    u32 u = __float_as_uint(f);
    u32 r = (u + 0x7fffu + ((u >> 16) & 1u)) >> 16;  // RNE
    return (u16)r;
}
__device__ __forceinline__ float bf2f(u16 h) { return __uint_as_float(((u32)h) << 16); }

__device__ __forceinline__ void gload_lds16(const void* g, void* l) {
    __builtin_amdgcn_global_load_lds((const __attribute__((address_space(1))) u32*)g,
                                     (__attribute__((address_space(3))) u32*)l, 16, 0, 0);
}

// Bijective XCD-aware workgroup swizzle (m204 form): same-XCD wgs get a
// contiguous run of linear ids. With bn-fastest linearization this makes an
// XCD reuse one A-panel across all bn tiles (L2 locality).
__device__ __forceinline__ void xcd_tiles(u32& bm, u32& bn) {
    u32 gdx = gridDim.x, gdy = gridDim.y;
    u32 nwg = gdx * gdy;
    u32 wg = blockIdx.x + gdx * blockIdx.y;
    u32 q = nwg >> 3, r8 = nwg & 7;
    u32 xcd = wg & 7, loc = wg >> 3;
    u32 swz = (xcd < r8 ? xcd * (q + 1) : r8 * (q + 1) + (xcd - r8) * q) + loc;
    bn = swz % gdy;   // bn fastest within an XCD's contiguous run
    bm = swz / gdy;
}

// lex-min on (d, s): total order, associative -> tree order == scan order
__device__ __forceinline__ void lmin(float& da, int& sa, float db, int sb) {
    bool better = (db < da) || (db == da && sb < sa);
    da = better ? db : da;
    sa = better ? sb : sa;
}

// ---------------------------------------------------------------------------
// Transpose fusion_feat [B,C,S(split)] f32 -> featT [B,S,C] f32
// ---------------------------------------------------------------------------
__global__ __launch_bounds__(256) void transpose_kernel(const float* __restrict__ feat,
                                                        const float* __restrict__ feat_db,
                                                        float* __restrict__ featT) {
    __shared__ float tile[64][65];
    int bid = blockIdx.x;
    int b = bid / (40 * 8);
    int rem = bid - b * (40 * 8);
    int st = rem >> 3, ct = rem & 7;
    int t = threadIdx.x, lane = t & 63, g = t >> 6;
    int s0 = st * 64, c0 = ct * 64;
    const float* src;
    int sl0, stride;
    if (s0 < Nc) { src = feat + (size_t)b * Cc * Nc; sl0 = s0; stride = Nc; }
    else         { src = feat_db + (size_t)b * Cc * Mc; sl0 = s0 - Nc; stride = Mc; }
#pragma unroll
    for (int i = 0; i < 16; i++) {
        int cl = g * 16 + i;
        tile[cl][lane] = src[(size_t)(c0 + cl) * stride + sl0 + lane];
    }
    __syncthreads();
#pragma unroll
    for (int i = 0; i < 16; i++) {
        int sl = g * 16 + i;
        featT[((size_t)b * Sc + s0 + sl) * Cc + c0 + lane] = tile[lane][sl];
    }
}

// ---------------------------------------------------------------------------
// Weight prep: fold attn BN into W1/bias1, cast attn W1/W2 + pos W2 to bf16
// ---------------------------------------------------------------------------
__global__ __launch_bounds__(256) void prep_kernel(const float* __restrict__ aw1, const float* __restrict__ ab1,
                                                   const float* __restrict__ ag, const float* __restrict__ abb,
                                                   const float* __restrict__ am, const float* __restrict__ av,
                                                   const float* __restrict__ aw2, const float* __restrict__ pw2,
                                                   u16* __restrict__ W1b, float* __restrict__ bias1,
                                                   u16* __restrict__ W2b, u16* __restrict__ PW2b) {
    int i = blockIdx.x * 256 + threadIdx.x;  // grid covers 524288
    if (i < AH * Cc) {
        int o = i >> 9;
        float inv = ag[o] / sqrtf(av[o] + EPS);
        W1b[i] = f2bf(aw1[i] * inv);
    }
    if (i < AH) {
        float inv = ag[i] / sqrtf(av[i] + EPS);
        bias1[i] = ab1[i] * inv + abb[i] - am[i] * inv;
    }
    if (i < Cc * AH) W2b[i] = f2bf(aw2[i]);
    if (i < Cc * PH) PW2b[i] = f2bf(pw2[i]);
}

// ---------------------------------------------------------------------------
// KNN (v1 + tree-scan): one wave per query; distances mirror the reference
// decomposition qq + ss - 2*dot, no fma contraction; ties -> smaller index.
// ---------------------------------------------------------------------------
__global__ __launch_bounds__(256) void knn_kernel(const float* __restrict__ pcd,
                                                  const float* __restrict__ pcd_db,
                                                  int* __restrict__ idxout) {
    int t = threadIdx.x, w = t >> 6, l = t & 63;
    int q = blockIdx.x * 4 + w;  // 0..4095
    int b = q >> 11, n = q & (Nc - 1);
    const float* pc = pcd + (size_t)b * 3 * Nc;
    const float* pd = pcd_db + (size_t)b * 3 * Mc;
    float qx = pc[n], qy = pc[Nc + n], qz = pc[2 * Nc + n];
    float qq = __fadd_rn(__fadd_rn(__fmul_rn(qx, qx), __fmul_rn(qy, qy)), __fmul_rn(qz, qz));
    float dist[40];
#pragma unroll
    for (int j = 0; j < 40; j++) {
        int s = j * 64 + l;
        float sx, sy, sz;
        if (s < Nc) { sx = pc[s]; sy = pc[Nc + s]; sz = pc[2 * Nc + s]; }
        else { int ss = s - Nc; sx = pd[ss]; sy = pd[Mc + ss]; sz = pd[2 * Mc + ss]; }
        float ss2 = __fadd_rn(__fadd_rn(__fmul_rn(sx, sx), __fmul_rn(sy, sy)), __fmul_rn(sz, sz));
        float dt  = __fadd_rn(__fadd_rn(__fmul_rn(qx, sx), __fmul_rn(qy, sy)), __fmul_rn(qz, sz));
        dist[j] = __fsub_rn(__fadd_rn(qq, ss2), __fmul_rn(2.0f, dt));
    }
    for (int r = 0; r < 16; r++) {
        // tree lex-min over the 40 (dist[j], j*64+l) pairs
        float td[20];
        int   ts[20];
#pragma unroll
        for (int i = 0; i < 20; i++) {
            float d0 = dist[2 * i], d1 = dist[2 * i + 1];
            int s0 = (2 * i) * 64 + l, s1 = (2 * i + 1) * 64 + l;
            bool bt = (d1 < d0) || (d1 == d0 && s1 < s0);
            td[i] = bt ? d1 : d0;
            ts[i] = bt ? s1 : s0;
        }
#pragma unroll
        for (int i = 0; i < 10; i++) lmin(td[i], ts[i], td[i + 10], ts[i + 10]);
#pragma unroll
        for (int i = 0; i < 5; i++) lmin(td[i], ts[i], td[i + 5], ts[i + 5]);
        lmin(td[0], ts[0], td[3], ts[3]);
        lmin(td[1], ts[1], td[4], ts[4]);
        lmin(td[0], ts[0], td[2], ts[2]);
        lmin(td[0], ts[0], td[1], ts[1]);
        float bd = td[0];
        int   bs = ts[0];
        for (int off = 32; off; off >>= 1) {
            float od = __shfl_xor(bd, off);
            int   os = __shfl_xor(bs, off);
            bool better = (od < bd) || (od == bd && os < bs);
            bd = better ? od : bd;
            bs = better ? os : bs;
        }
        if (l == 0) idxout[q * 16 + r] = bs;
        int wj = bs >> 6, wl = bs & 63;
        if (l == wl) {
#pragma unroll
            for (int j = 0; j < 40; j++)
                if (j == wj) dist[j] = 1e30f;
        }
    }
}

// ---------------------------------------------------------------------------
// HKER: per row, pos-MLP layer-1: h[r][64] = relu(BN(W1 (q - s) + b1)) bf16
// ---------------------------------------------------------------------------
__global__ __launch_bounds__(256) void hker(const float* __restrict__ pcd, const float* __restrict__ pcd_db,
                                            const int* __restrict__ idxb,
                                            const float* __restrict__ pw1, const float* __restrict__ pb1,
                                            const float* __restrict__ pg, const float* __restrict__ pbb,
                                            const float* __restrict__ pm, const float* __restrict__ pv,
                                            u16* __restrict__ H) {
    __shared__ float W1s[64][4];
    int t = threadIdx.x;
    if (t < 64) {
        float inv = pg[t] / sqrtf(pv[t] + EPS);
        W1s[t][0] = pw1[t * 3 + 0] * inv;
        W1s[t][1] = pw1[t * 3 + 1] * inv;
        W1s[t][2] = pw1[t * 3 + 2] * inv;
        W1s[t][3] = pb1[t] * inv + pbb[t] - pm[t] * inv;
    }
    __syncthreads();
    int r = blockIdx.x * 256 + t;
    int b = r >> 15, n = (r >> 4) & (Nc - 1), s = idxb[r];
    const float* pc = pcd + (size_t)b * 3 * Nc;
    float qx = pc[n], qy = pc[Nc + n], qz = pc[2 * Nc + n];
    float sx, sy, sz;
    if (s < Nc) { sx = pc[s]; sy = pc[Nc + s]; sz = pc[2 * Nc + s]; }
    else {
        const float* pd = pcd_db + (size_t)b * 3 * Mc;
        int ss = s - Nc;
        sx = pd[ss]; sy = pd[Mc + ss]; sz = pd[2 * Mc + ss];
    }
    float dx = qx - sx, dy = qy - sy, dz = qz - sz;
    u16* hp = H + (size_t)r * 64;
#pragma unroll
    for (int u0 = 0; u0 < 64; u0 += 8) {
        u16 e[8];
#pragma unroll
        for (int j = 0; j < 8; j++) {
            int u = u0 + j;
            float hv = fmaxf(0.f, dx * W1s[u][0] + dy * W1s[u][1] + dz * W1s[u][2] + W1s[u][3]);
            e[j] = f2bf(hv);
        }
        u32x4 pk;
        pk.x = (u32)e[0] | ((u32)e[1] << 16); pk.y = (u32)e[2] | ((u32)e[3] << 16);
        pk.z = (u32)e[4] | ((u32)e[5] << 16); pk.w = (u32)e[6] | ((u32)e[7] << 16);
        *(u32x4*)(hp + u0) = pk;
    }
}

// ---------------------------------------------------------------------------
// PGEMM_FUSED: P = H @ PW2^T + pb2 via MFMA (M=rows, N=512, K=64), epilogue
// gathers f,g from featT and emits X = f-g+p, V = g+p (bf16).
// ---------------------------------------------------------------------------
__global__ __launch_bounds__(256) void pgemm_fused(const u16* __restrict__ Hg, const u16* __restrict__ Bg,
                                                   const float* __restrict__ pb2,
                                                   const float* __restrict__ featT, const int* __restrict__ idxb,
                                                   u16* __restrict__ X, u16* __restrict__ V, int row0) {
    __shared__ u16 As[128 * 64];
    __shared__ u16 Bs[128 * 64];
    const int t = threadIdx.x;
    u32 bmu, bnu;
    xcd_tiles(bmu, bnu);
    const int bm = (int)bmu, bn = (int)bnu;
    const int w = t >> 6, l = t & 63;
    const int wr = w >> 1, wc = w & 1;
    const int fr = l & 15, fq = l >> 4;
    f32x4 acc[4][4];
#pragma unroll
    for (int i = 0; i < 4; i++)
#pragma unroll
        for (int j = 0; j < 4; j++) {
            f32x4 z = {0.f, 0.f, 0.f, 0.f};
            acc[i][j] = z;
        }
    const char* Abase = (const char*)Hg + ((size_t)row0 + (size_t)bm * 128) * 64 * 2;
    const char* Bbase = (const char*)Bg + (size_t)bn * 128 * 64 * 2;
#pragma unroll
    for (int i = 0; i < 4; i++) {
        int chunk = i * 256 + t;
        int row = chunk >> 3;
        int cb = (chunk & 7) * 16;
        gload_lds16(Abase + (size_t)row * 128 + cb, (char*)As + chunk * 16);
    }
#pragma unroll
    for (int i = 0; i < 4; i++) {
        int chunk = i * 256 + t;
        int row = chunk >> 3;
        int cb = (chunk & 7) * 16;
        gload_lds16(Bbase + (size_t)row * 128 + cb, (char*)Bs + chunk * 16);
    }
    __syncthreads();
    bf16x8 af[4][2], bfv[4][2];
#pragma unroll
    for (int mf = 0; mf < 4; mf++)
#pragma unroll
        for (int ks = 0; ks < 2; ks++)
            af[mf][ks] = *(const bf16x8*)&As[(wr * 64 + mf * 16 + fr) * 64 + ks * 32 + fq * 8];
#pragma unroll
    for (int nf = 0; nf < 4; nf++)
#pragma unroll
        for (int ks = 0; ks < 2; ks++)
            bfv[nf][ks] = *(const bf16x8*)&Bs[(wc * 64 + nf * 16 + fr) * 64 + ks * 32 + fq * 8];
#pragma unroll
    for (int mf = 0; mf < 4; mf++)
#pragma unroll
        for (int nf = 0; nf < 4; nf++)
#pragma unroll
            for (int ks = 0; ks < 2; ks++)
                acc[mf][nf] = __builtin_amdgcn_mfma_f32_16x16x32_bf16(af[mf][ks], bfv[nf][ks], acc[mf][nf], 0, 0, 0);
    // epilogue: per C-row gather f,g; emit X,V
#pragma unroll
    for (int mf = 0; mf < 4; mf++) {
#pragma unroll
        for (int r = 0; r < 4; r++) {
            int gr = bm * 128 + wr * 64 + mf * 16 + fq * 4 + r;  // chunk-local row
            int grow = row0 + gr;                                 // global row
            int b = grow >> 15;
            int n = (grow >> 4) & (Nc - 1);
            int s = idxb[grow];
            const float* frow = featT + ((size_t)b * Sc + n) * Cc;
            const float* grow_p = featT + ((size_t)b * Sc + s) * Cc;
#pragma unroll
            for (int nf = 0; nf < 4; nf++) {
                int gn = bn * 128 + wc * 64 + nf * 16 + fr;
                float p = acc[mf][nf][r] + pb2[gn];
                float fv = frow[gn];
                float gv = grow_p[gn];
                X[(size_t)gr * Cc + gn] = f2bf(fv - gv + p);
                V[(size_t)gr * Cc + gn] = f2bf(gv + p);
            }
        }
    }
}

// ---------------------------------------------------------------------------
// GEMM (m97 structure + XCD swizzle): C[m][n] = f(sum_k A[m][k]*B[n][k]+bias)
// A [M][Kd] bf16, B [N][Kd] bf16 (i.e. B^T layout), 128x128 tile, BK=64.
// ---------------------------------------------------------------------------
template <bool RELU, bool OBF16>
__global__ __launch_bounds__(256) void gemm_bt(const u16* __restrict__ Ag, const u16* __restrict__ Bg,
                                               const float* __restrict__ bias, void* __restrict__ Cg,
                                               int M, int N, int Kd) {
    __shared__ u16 As[128 * 64];
    __shared__ u16 Bs[128 * 64];
    const int t = threadIdx.x;
    u32 bmu, bnu;
    xcd_tiles(bmu, bnu);
    const int bm = (int)bmu, bn = (int)bnu;
    const int w = t >> 6, l = t & 63;
    const int wr = w >> 1, wc = w & 1;
    const int fr = l & 15, fq = l >> 4;
    f32x4 acc[4][4];
#pragma unroll
    for (int i = 0; i < 4; i++)
#pragma unroll
        for (int j = 0; j < 4; j++) {
            f32x4 z = {0.f, 0.f, 0.f, 0.f};
            acc[i][j] = z;
        }
    const char* Abase = (const char*)Ag + (size_t)bm * 128 * (size_t)Kd * 2;
    const char* Bbase = (const char*)Bg + (size_t)bn * 128 * (size_t)Kd * 2;
    const size_t ldb = (size_t)Kd * 2;

    for (int kt = 0; kt < Kd; kt += 64) {
#pragma unroll
        for (int i = 0; i < 4; i++) {
            int chunk = i * 256 + t;
            int row = chunk >> 3;
            int cb = (chunk & 7) * 16;
            gload_lds16(Abase + (size_t)row * ldb + (size_t)kt * 2 + cb, (char*)As + chunk * 16);
        }
#pragma unroll
        for (int i = 0; i < 4; i++) {
            int chunk = i * 256 + t;
            int row = chunk >> 3;
            int cb = (chunk & 7) * 16;
            gload_lds16(Bbase + (size_t)row * ldb + (size_t)kt * 2 + cb, (char*)Bs + chunk * 16);
        }
        __syncthreads();
        bf16x8 af[4][2], bfv[4][2];
#pragma unroll
        for (int mf = 0; mf < 4; mf++)
#pragma unroll
            for (int ks = 0; ks < 2; ks++)
                af[mf][ks] = *(const bf16x8*)&As[(wr * 64 + mf * 16 + fr) * 64 + ks * 32 + fq * 8];
#pragma unroll
        for (int nf = 0; nf < 4; nf++)
#pragma unroll
            for (int ks = 0; ks < 2; ks++)
                bfv[nf][ks] = *(const bf16x8*)&Bs[(wc * 64 + nf * 16 + fr) * 64 + ks * 32 + fq * 8];
#pragma unroll
        for (int mf = 0; mf < 4; mf++)
#pragma unroll
            for (int nf = 0; nf < 4; nf++)
#pragma unroll
                for (int ks = 0; ks < 2; ks++)
                    acc[mf][nf] = __builtin_amdgcn_mfma_f32_16x16x32_bf16(af[mf][ks], bfv[nf][ks], acc[mf][nf], 0, 0, 0);
        __syncthreads();
    }
#pragma unroll
    for (int mf = 0; mf < 4; mf++) {
#pragma unroll
        for (int nf = 0; nf < 4; nf++) {
            int gn = bn * 128 + wc * 64 + nf * 16 + fr;
            float bi = bias[gn];
            int gm0 = bm * 128 + wr * 64 + mf * 16 + fq * 4;
#pragma unroll
            for (int r = 0; r < 4; r++) {
                float v = acc[mf][nf][r] + bi;
                if (RELU) v = fmaxf(v, 0.f);
                size_t o = (size_t)(gm0 + r) * N + gn;
                if (OBF16) ((u16*)Cg)[o] = f2bf(v);
                else ((float*)Cg)[o] = v;
            }
        }
    }
}

// ---------------------------------------------------------------------------
// GEMM2_FUSED: logits L = A @ W2^T + ab2 (M=rows, N=512, K=1024) with the
// softmax-over-k + weighted-V reduction fused into the epilogue.
// A 128-row tile holds 8 COMPLETE points (16 k-rows each); k = fq*4+r, so
// per-channel softmax over k is 3 local ops + shfl_xor(16) + shfl_xor(32).
// Eliminates the L buffer and final_kernel entirely.
// ---------------------------------------------------------------------------
__global__ __launch_bounds__(256) void gemm2_fused(const u16* __restrict__ Ag, const u16* __restrict__ Bg,
                                                   const float* __restrict__ bias, const u16* __restrict__ Vb,
                                                   float* __restrict__ out, int row0, int Kd) {
    __shared__ u16 As[128 * 64];
    __shared__ u16 Bs[128 * 64];
    const int t = threadIdx.x;
    u32 bmu, bnu;
    xcd_tiles(bmu, bnu);
    const int bm = (int)bmu, bn = (int)bnu;
    const int w = t >> 6, l = t & 63;
    const int wr = w >> 1, wc = w & 1;
    const int fr = l & 15, fq = l >> 4;
    f32x4 acc[4][4];
#pragma unroll
    for (int i = 0; i < 4; i++)
#pragma unroll
        for (int j = 0; j < 4; j++) {
            f32x4 z = {0.f, 0.f, 0.f, 0.f};
            acc[i][j] = z;
        }
    const char* Abase = (const char*)Ag + (size_t)bm * 128 * (size_t)Kd * 2;
    const char* Bbase = (const char*)Bg + (size_t)bn * 128 * (size_t)Kd * 2;
    const size_t ldb = (size_t)Kd * 2;

    for (int kt = 0; kt < Kd; kt += 64) {
#pragma unroll
        for (int i = 0; i < 4; i++) {
            int chunk = i * 256 + t;
            int row = chunk >> 3;
            int cb = (chunk & 7) * 16;
            gload_lds16(Abase + (size_t)row * ldb + (size_t)kt * 2 + cb, (char*)As + chunk * 16);
        }
#pragma unroll
        for (int i = 0; i < 4; i++) {
            int chunk = i * 256 + t;
            int row = chunk >> 3;
            int cb = (chunk & 7) * 16;
            gload_lds16(Bbase + (size_t)row * ldb + (size_t)kt * 2 + cb, (char*)Bs + chunk * 16);
        }
        __syncthreads();
        bf16x8 af[4][2], bfv[4][2];
#pragma unroll
        for (int mf = 0; mf < 4; mf++)
#pragma unroll
            for (int ks = 0; ks < 2; ks++)
                af[mf][ks] = *(const bf16x8*)&As[(wr * 64 + mf * 16 + fr) * 64 + ks * 32 + fq * 8];
#pragma unroll
        for (int nf = 0; nf < 4; nf++)
#pragma unroll
            for (int ks = 0; ks < 2; ks++)
                bfv[nf][ks] = *(const bf16x8*)&Bs[(wc * 64 + nf * 16 + fr) * 64 + ks * 32 + fq * 8];
#pragma unroll
        for (int mf = 0; mf < 4; mf++)
#pragma unroll
            for (int nf = 0; nf < 4; nf++)
#pragma unroll
                for (int ks = 0; ks < 2; ks++)
                    acc[mf][nf] = __builtin_amdgcn_mfma_f32_16x16x32_bf16(af[mf][ks], bfv[nf][ks], acc[mf][nf], 0, 0, 0);
        __syncthreads();
    }
    // fused epilogue: per (point, channel) softmax over k=fq*4+r + V-reduce
#pragma unroll
    for (int mf = 0; mf < 4; mf++) {
        int lp = bm * 8 + wr * 4 + mf;        // chunk-local point
        int gp = row0 / 16 + lp;              // global point
        int bb = gp >> 11, nn = gp & (Nc - 1);
        const u16* vbase = Vb + ((size_t)(lp * 16 + fq * 4)) * Cc;
#pragma unroll
        for (int nf = 0; nf < 4; nf++) {
            int gn = bn * 128 + wc * 64 + nf * 16 + fr;
            float bi = bias[gn];
            float v0 = acc[mf][nf][0] + bi, v1 = acc[mf][nf][1] + bi;
            float v2 = acc[mf][nf][2] + bi, v3 = acc[mf][nf][3] + bi;
            float mx = fmaxf(fmaxf(v0, v1), fmaxf(v2, v3));
            mx = fmaxf(mx, __shfl_xor(mx, 16));
            mx = fmaxf(mx, __shfl_xor(mx, 32));
            float e0 = __expf(v0 - mx), e1 = __expf(v1 - mx);
            float e2 = __expf(v2 - mx), e3 = __expf(v3 - mx);
            float ws = e0 * bf2f(vbase[gn]) + e1 * bf2f(vbase[Cc + gn])
                     + e2 * bf2f(vbase[2 * Cc + gn]) + e3 * bf2f(vbase[3 * Cc + gn]);
            float es = e0 + e1 + e2 + e3;
            ws += __shfl_xor(ws, 16); ws += __shfl_xor(ws, 32);
            es += __shfl_xor(es, 16); es += __shfl_xor(es, 32);
            if (fq == 0) out[((size_t)bb * Cc + gn) * Nc + nn] = ws / es;
        }
    }
}

// ---------------------------------------------------------------------------
extern "C" void kernel_launch(void* const* d_in, const int* in_sizes, int n_in,
                              void* d_out, int out_size, void* d_ws, size_t ws_size,
                              hipStream_t stream) {
    (void)in_sizes; (void)n_in; (void)out_size;
    const float* pcd     = (const float*)d_in[0];
    const float* feat    = (const float*)d_in[1];
    const float* pcd_db  = (const float*)d_in[2];
    const float* feat_db = (const float*)d_in[3];
    const float* pw1 = (const float*)d_in[4];
    const float* pb1 = (const float*)d_in[5];
    const float* pg  = (const float*)d_in[6];
    const float* pbb = (const float*)d_in[7];
    const float* pm  = (const float*)d_in[8];
    const float* pv  = (const float*)d_in[9];
    const float* pw2 = (const float*)d_in[10];
    const float* pb2 = (const float*)d_in[11];
    const float* aw1 = (const float*)d_in[12];
    const float* ab1 = (const float*)d_in[13];
    const float* ag  = (const float*)d_in[14];
    const float* abb = (const float*)d_in[15];
    const float* am  = (const float*)d_in[16];
    const float* av  = (const float*)d_in[17];
    const float* aw2 = (const float*)d_in[18];
    const float* ab2 = (const float*)d_in[19];
    float* out = (float*)d_out;

    char* base = (char*)d_ws;
    size_t off = 0;
    auto alloc = [&](size_t bytes) -> char* {
        char* r = base + off;
        off = (off + bytes + 255) & ~(size_t)255;
        return r;
    };
    int*   idxb  = (int*)alloc((size_t)RT * 4);
    float* featT = (float*)alloc((size_t)Bc * Sc * Cc * 4);
    u16*   W1b   = (u16*)alloc((size_t)AH * Cc * 2);
    float* bias1 = (float*)alloc((size_t)AH * 4);
    u16*   W2b   = (u16*)alloc((size_t)Cc * AH * 2);
    u16*   PW2b  = (u16*)alloc((size_t)Cc * PH * 2);
    u16*   Hb    = (u16*)alloc((size_t)RT * PH * 2);

    // chunked row pipeline: cap chunk at 16384 rows so Xb+Vb+Ab (~64 MB)
    // stays L3-resident between producer/consumer kernels.
    const size_t perrow = 1024 + 1024 + 2048;  // X,V bf16 + A bf16 (L fused away)
    int cr = 16384;
    size_t avail = ws_size > off ? ws_size - off : 0;
    if (avail < (size_t)cr * perrow) {
        cr = (int)((avail / perrow) & ~(size_t)127);
        if (cr < 128) cr = 128;
    }
    u16*   Xb = (u16*)alloc((size_t)cr * Cc * 2);
    u16*   Vb = (u16*)alloc((size_t)cr * Cc * 2);
    u16*   Ab = (u16*)alloc((size_t)cr * AH * 2);

    transpose_kernel<<<dim3(Bc * 40 * 8), dim3(256), 0, stream>>>(feat, feat_db, featT);
    prep_kernel<<<dim3((AH * Cc) / 256), dim3(256), 0, stream>>>(aw1, ab1, ag, abb, am, av, aw2, pw2,
                                                                 W1b, bias1, W2b, PW2b);
    knn_kernel<<<dim3(Bc * Nc / 4), dim3(256), 0, stream>>>(pcd, pcd_db, idxb);
    hker<<<dim3(RT / 256), dim3(256), 0, stream>>>(pcd, pcd_db, idxb, pw1, pb1, pg, pbb, pm, pv, Hb);

    for (int r0 = 0; r0 < RT; r0 += cr) {
        int rows = (RT - r0 < cr) ? (RT - r0) : cr;
        pgemm_fused<<<dim3(rows / 128, Cc / 128), dim3(256), 0, stream>>>(Hb, PW2b, pb2, featT, idxb,
                                                                          Xb, Vb, r0);
        gemm_bt<true, true><<<dim3(rows / 128, AH / 128), dim3(256), 0, stream>>>(Xb, W1b, bias1, Ab, rows, AH, Cc);
        gemm2_fused<<<dim3(rows / 128, Cc / 128), dim3(256), 0, stream>>>(Ab, W2b, ab2, Vb, out, r0, AH);
    }
}

// Round 13
// 361.290 us; speedup vs baseline: 2.4726x; 1.0010x over previous
//
#include <hip/hip_runtime.h>

typedef unsigned short u16;
typedef unsigned int   u32;
typedef __attribute__((ext_vector_type(8))) short bf16x8;
typedef __attribute__((ext_vector_type(4))) float f32x4;
typedef __attribute__((ext_vector_type(4))) u32   u32x4;

// Problem constants
constexpr int Bc = 2, Cc = 512, Nc = 2048, Mc = 512, Sc = 2560, Kc = 16, PH = 64, AH = 1024;
constexpr int RT = Bc * Nc * Kc;  // 65536 rows (b,n,k)
constexpr float EPS = 1e-5f;

__device__ __forceinline__ u16 f2bf(float f) {
    u32 u = __float_as_uint(f);
    u32 r = (u + 0x7fffu + ((u >> 16) & 1u)) >> 16;  // RNE
    return (u16)r;
}
__device__ __forceinline__ float bf2f(u16 h) { return __uint_as_float(((u32)h) << 16); }

__device__ __forceinline__ void gload_lds16(const void* g, void* l) {
    __builtin_amdgcn_global_load_lds((const __attribute__((address_space(1))) u32*)g,
                                     (__attribute__((address_space(3))) u32*)l, 16, 0, 0);
}

// Bijective XCD-aware workgroup swizzle (m204 form): same-XCD wgs get a
// contiguous run of linear ids. With bn-fastest linearization this makes an
// XCD reuse one A-panel across all bn tiles (L2 locality).
__device__ __forceinline__ void xcd_tiles(u32& bm, u32& bn) {
    u32 gdx = gridDim.x, gdy = gridDim.y;
    u32 nwg = gdx * gdy;
    u32 wg = blockIdx.x + gdx * blockIdx.y;
    u32 q = nwg >> 3, r8 = nwg & 7;
    u32 xcd = wg & 7, loc = wg >> 3;
    u32 swz = (xcd < r8 ? xcd * (q + 1) : r8 * (q + 1) + (xcd - r8) * q) + loc;
    bn = swz % gdy;   // bn fastest within an XCD's contiguous run
    bm = swz / gdy;
}

// lex-min on (d, s): total order, associative -> tree order == scan order
__device__ __forceinline__ void lmin(float& da, int& sa, float db, int sb) {
    bool better = (db < da) || (db == da && sb < sa);
    da = better ? db : da;
    sa = better ? sb : sa;
}

// ---------------------------------------------------------------------------
// Transpose fusion_feat [B,C,S(split)] f32 -> featT [B,S,C] f32
// ---------------------------------------------------------------------------
__global__ __launch_bounds__(256) void transpose_kernel(const float* __restrict__ feat,
                                                        const float* __restrict__ feat_db,
                                                        float* __restrict__ featT) {
    __shared__ float tile[64][65];
    int bid = blockIdx.x;
    int b = bid / (40 * 8);
    int rem = bid - b * (40 * 8);
    int st = rem >> 3, ct = rem & 7;
    int t = threadIdx.x, lane = t & 63, g = t >> 6;
    int s0 = st * 64, c0 = ct * 64;
    const float* src;
    int sl0, stride;
    if (s0 < Nc) { src = feat + (size_t)b * Cc * Nc; sl0 = s0; stride = Nc; }
    else         { src = feat_db + (size_t)b * Cc * Mc; sl0 = s0 - Nc; stride = Mc; }
#pragma unroll
    for (int i = 0; i < 16; i++) {
        int cl = g * 16 + i;
        tile[cl][lane] = src[(size_t)(c0 + cl) * stride + sl0 + lane];
    }
    __syncthreads();
#pragma unroll
    for (int i = 0; i < 16; i++) {
        int sl = g * 16 + i;
        featT[((size_t)b * Sc + s0 + sl) * Cc + c0 + lane] = tile[lane][sl];
    }
}

// ---------------------------------------------------------------------------
// Weight prep: fold attn BN into W1/bias1, cast attn W1/W2 + pos W2 to bf16
// ---------------------------------------------------------------------------
__global__ __launch_bounds__(256) void prep_kernel(const float* __restrict__ aw1, const float* __restrict__ ab1,
                                                   const float* __restrict__ ag, const float* __restrict__ abb,
                                                   const float* __restrict__ am, const float* __restrict__ av,
                                                   const float* __restrict__ aw2, const float* __restrict__ pw2,
                                                   u16* __restrict__ W1b, float* __restrict__ bias1,
                                                   u16* __restrict__ W2b, u16* __restrict__ PW2b) {
    int i = blockIdx.x * 256 + threadIdx.x;  // grid covers 524288
    if (i < AH * Cc) {
        int o = i >> 9;
        float inv = ag[o] / sqrtf(av[o] + EPS);
        W1b[i] = f2bf(aw1[i] * inv);
    }
    if (i < AH) {
        float inv = ag[i] / sqrtf(av[i] + EPS);
        bias1[i] = ab1[i] * inv + abb[i] - am[i] * inv;
    }
    if (i < Cc * AH) W2b[i] = f2bf(aw2[i]);
    if (i < Cc * PH) PW2b[i] = f2bf(pw2[i]);
}

// ---------------------------------------------------------------------------
// KNN (v1 + tree-scan): one wave per query; distances mirror the reference
// decomposition qq + ss - 2*dot, no fma contraction; ties -> smaller index.
// ---------------------------------------------------------------------------
__global__ __launch_bounds__(256) void knn_kernel(const float* __restrict__ pcd,
                                                  const float* __restrict__ pcd_db,
                                                  int* __restrict__ idxout) {
    int t = threadIdx.x, w = t >> 6, l = t & 63;
    int q = blockIdx.x * 4 + w;  // 0..4095
    int b = q >> 11, n = q & (Nc - 1);
    const float* pc = pcd + (size_t)b * 3 * Nc;
    const float* pd = pcd_db + (size_t)b * 3 * Mc;
    float qx = pc[n], qy = pc[Nc + n], qz = pc[2 * Nc + n];
    float qq = __fadd_rn(__fadd_rn(__fmul_rn(qx, qx), __fmul_rn(qy, qy)), __fmul_rn(qz, qz));
    float dist[40];
#pragma unroll
    for (int j = 0; j < 40; j++) {
        int s = j * 64 + l;
        float sx, sy, sz;
        if (s < Nc) { sx = pc[s]; sy = pc[Nc + s]; sz = pc[2 * Nc + s]; }
        else { int ss = s - Nc; sx = pd[ss]; sy = pd[Mc + ss]; sz = pd[2 * Mc + ss]; }
        float ss2 = __fadd_rn(__fadd_rn(__fmul_rn(sx, sx), __fmul_rn(sy, sy)), __fmul_rn(sz, sz));
        float dt  = __fadd_rn(__fadd_rn(__fmul_rn(qx, sx), __fmul_rn(qy, sy)), __fmul_rn(qz, sz));
        dist[j] = __fsub_rn(__fadd_rn(qq, ss2), __fmul_rn(2.0f, dt));
    }
    for (int r = 0; r < 16; r++) {
        // tree lex-min over the 40 (dist[j], j*64+l) pairs
        float td[20];
        int   ts[20];
#pragma unroll
        for (int i = 0; i < 20; i++) {
            float d0 = dist[2 * i], d1 = dist[2 * i + 1];
            int s0 = (2 * i) * 64 + l, s1 = (2 * i + 1) * 64 + l;
            bool bt = (d1 < d0) || (d1 == d0 && s1 < s0);
            td[i] = bt ? d1 : d0;
            ts[i] = bt ? s1 : s0;
        }
#pragma unroll
        for (int i = 0; i < 10; i++) lmin(td[i], ts[i], td[i + 10], ts[i + 10]);
#pragma unroll
        for (int i = 0; i < 5; i++) lmin(td[i], ts[i], td[i + 5], ts[i + 5]);
        lmin(td[0], ts[0], td[3], ts[3]);
        lmin(td[1], ts[1], td[4], ts[4]);
        lmin(td[0], ts[0], td[2], ts[2]);
        lmin(td[0], ts[0], td[1], ts[1]);
        float bd = td[0];
        int   bs = ts[0];
        for (int off = 32; off; off >>= 1) {
            float od = __shfl_xor(bd, off);
            int   os = __shfl_xor(bs, off);
            bool better = (od < bd) || (od == bd && os < bs);
            bd = better ? od : bd;
            bs = better ? os : bs;
        }
        if (l == 0) idxout[q * 16 + r] = bs;
        int wj = bs >> 6, wl = bs & 63;
        if (l == wl) {
#pragma unroll
            for (int j = 0; j < 40; j++)
                if (j == wj) dist[j] = 1e30f;
        }
    }
}

// ---------------------------------------------------------------------------
// HKER: per row, pos-MLP layer-1: h[r][64] = relu(BN(W1 (q - s) + b1)) bf16
// ---------------------------------------------------------------------------
__global__ __launch_bounds__(256) void hker(const float* __restrict__ pcd, const float* __restrict__ pcd_db,
                                            const int* __restrict__ idxb,
                                            const float* __restrict__ pw1, const float* __restrict__ pb1,
                                            const float* __restrict__ pg, const float* __restrict__ pbb,
                                            const float* __restrict__ pm, const float* __restrict__ pv,
                                            u16* __restrict__ H) {
    __shared__ float W1s[64][4];
    int t = threadIdx.x;
    if (t < 64) {
        float inv = pg[t] / sqrtf(pv[t] + EPS);
        W1s[t][0] = pw1[t * 3 + 0] * inv;
        W1s[t][1] = pw1[t * 3 + 1] * inv;
        W1s[t][2] = pw1[t * 3 + 2] * inv;
        W1s[t][3] = pb1[t] * inv + pbb[t] - pm[t] * inv;
    }
    __syncthreads();
    int r = blockIdx.x * 256 + t;
    int b = r >> 15, n = (r >> 4) & (Nc - 1), s = idxb[r];
    const float* pc = pcd + (size_t)b * 3 * Nc;
    float qx = pc[n], qy = pc[Nc + n], qz = pc[2 * Nc + n];
    float sx, sy, sz;
    if (s < Nc) { sx = pc[s]; sy = pc[Nc + s]; sz = pc[2 * Nc + s]; }
    else {
        const float* pd = pcd_db + (size_t)b * 3 * Mc;
        int ss = s - Nc;
        sx = pd[ss]; sy = pd[Mc + ss]; sz = pd[2 * Mc + ss];
    }
    float dx = qx - sx, dy = qy - sy, dz = qz - sz;
    u16* hp = H + (size_t)r * 64;
#pragma unroll
    for (int u0 = 0; u0 < 64; u0 += 8) {
        u16 e[8];
#pragma unroll
        for (int j = 0; j < 8; j++) {
            int u = u0 + j;
            float hv = fmaxf(0.f, dx * W1s[u][0] + dy * W1s[u][1] + dz * W1s[u][2] + W1s[u][3]);
            e[j] = f2bf(hv);
        }
        u32x4 pk;
        pk.x = (u32)e[0] | ((u32)e[1] << 16); pk.y = (u32)e[2] | ((u32)e[3] << 16);
        pk.z = (u32)e[4] | ((u32)e[5] << 16); pk.w = (u32)e[6] | ((u32)e[7] << 16);
        *(u32x4*)(hp + u0) = pk;
    }
}

// ---------------------------------------------------------------------------
// PGEMM_FUSED: P = H @ PW2^T + pb2 via MFMA (M=rows, N=512, K=64), epilogue
// gathers f,g from featT and emits X = f-g+p, V = g+p (bf16).
// ---------------------------------------------------------------------------
__global__ __launch_bounds__(256) void pgemm_fused(const u16* __restrict__ Hg, const u16* __restrict__ Bg,
                                                   const float* __restrict__ pb2,
                                                   const float* __restrict__ featT, const int* __restrict__ idxb,
                                                   u16* __restrict__ X, u16* __restrict__ V, int row0) {
    __shared__ u16 As[128 * 64];
    __shared__ u16 Bs[128 * 64];
    const int t = threadIdx.x;
    u32 bmu, bnu;
    xcd_tiles(bmu, bnu);
    const int bm = (int)bmu, bn = (int)bnu;
    const int w = t >> 6, l = t & 63;
    const int wr = w >> 1, wc = w & 1;
    const int fr = l & 15, fq = l >> 4;
    f32x4 acc[4][4];
#pragma unroll
    for (int i = 0; i < 4; i++)
#pragma unroll
        for (int j = 0; j < 4; j++) {
            f32x4 z = {0.f, 0.f, 0.f, 0.f};
            acc[i][j] = z;
        }
    const char* Abase = (const char*)Hg + ((size_t)row0 + (size_t)bm * 128) * 64 * 2;
    const char* Bbase = (const char*)Bg + (size_t)bn * 128 * 64 * 2;
#pragma unroll
    for (int i = 0; i < 4; i++) {
        int chunk = i * 256 + t;
        int row = chunk >> 3;
        int cb = (chunk & 7) * 16;
        gload_lds16(Abase + (size_t)row * 128 + cb, (char*)As + chunk * 16);
    }
#pragma unroll
    for (int i = 0; i < 4; i++) {
        int chunk = i * 256 + t;
        int row = chunk >> 3;
        int cb = (chunk & 7) * 16;
        gload_lds16(Bbase + (size_t)row * 128 + cb, (char*)Bs + chunk * 16);
    }
    __syncthreads();
    bf16x8 af[4][2], bfv[4][2];
#pragma unroll
    for (int mf = 0; mf < 4; mf++)
#pragma unroll
        for (int ks = 0; ks < 2; ks++)
            af[mf][ks] = *(const bf16x8*)&As[(wr * 64 + mf * 16 + fr) * 64 + ks * 32 + fq * 8];
#pragma unroll
    for (int nf = 0; nf < 4; nf++)
#pragma unroll
        for (int ks = 0; ks < 2; ks++)
            bfv[nf][ks] = *(const bf16x8*)&Bs[(wc * 64 + nf * 16 + fr) * 64 + ks * 32 + fq * 8];
#pragma unroll
    for (int mf = 0; mf < 4; mf++)
#pragma unroll
        for (int nf = 0; nf < 4; nf++)
#pragma unroll
            for (int ks = 0; ks < 2; ks++)
                acc[mf][nf] = __builtin_amdgcn_mfma_f32_16x16x32_bf16(af[mf][ks], bfv[nf][ks], acc[mf][nf], 0, 0, 0);
    // epilogue: per C-row gather f,g; emit X,V
#pragma unroll
    for (int mf = 0; mf < 4; mf++) {
#pragma unroll
        for (int r = 0; r < 4; r++) {
            int gr = bm * 128 + wr * 64 + mf * 16 + fq * 4 + r;  // chunk-local row
            int grow = row0 + gr;                                 // global row
            int b = grow >> 15;
            int n = (grow >> 4) & (Nc - 1);
            int s = idxb[grow];
            const float* frow = featT + ((size_t)b * Sc + n) * Cc;
            const float* grow_p = featT + ((size_t)b * Sc + s) * Cc;
#pragma unroll
            for (int nf = 0; nf < 4; nf++) {
                int gn = bn * 128 + wc * 64 + nf * 16 + fr;
                float p = acc[mf][nf][r] + pb2[gn];
                float fv = frow[gn];
                float gv = grow_p[gn];
                X[(size_t)gr * Cc + gn] = f2bf(fv - gv + p);
                V[(size_t)gr * Cc + gn] = f2bf(gv + p);
            }
        }
    }
}

// ---------------------------------------------------------------------------
// GEMM (m97 structure + XCD swizzle): C[m][n] = f(sum_k A[m][k]*B[n][k]+bias)
// A [M][Kd] bf16, B [N][Kd] bf16 (i.e. B^T layout), 128x128 tile, BK=64.
// ---------------------------------------------------------------------------
template <bool RELU, bool OBF16>
__global__ __launch_bounds__(256) void gemm_bt(const u16* __restrict__ Ag, const u16* __restrict__ Bg,
                                               const float* __restrict__ bias, void* __restrict__ Cg,
                                               int M, int N, int Kd) {
    __shared__ u16 As[128 * 64];
    __shared__ u16 Bs[128 * 64];
    const int t = threadIdx.x;
    u32 bmu, bnu;
    xcd_tiles(bmu, bnu);
    const int bm = (int)bmu, bn = (int)bnu;
    const int w = t >> 6, l = t & 63;
    const int wr = w >> 1, wc = w & 1;
    const int fr = l & 15, fq = l >> 4;
    f32x4 acc[4][4];
#pragma unroll
    for (int i = 0; i < 4; i++)
#pragma unroll
        for (int j = 0; j < 4; j++) {
            f32x4 z = {0.f, 0.f, 0.f, 0.f};
            acc[i][j] = z;
        }
    const char* Abase = (const char*)Ag + (size_t)bm * 128 * (size_t)Kd * 2;
    const char* Bbase = (const char*)Bg + (size_t)bn * 128 * (size_t)Kd * 2;
    const size_t ldb = (size_t)Kd * 2;

    for (int kt = 0; kt < Kd; kt += 64) {
#pragma unroll
        for (int i = 0; i < 4; i++) {
            int chunk = i * 256 + t;
            int row = chunk >> 3;
            int cb = (chunk & 7) * 16;
            gload_lds16(Abase + (size_t)row * ldb + (size_t)kt * 2 + cb, (char*)As + chunk * 16);
        }
#pragma unroll
        for (int i = 0; i < 4; i++) {
            int chunk = i * 256 + t;
            int row = chunk >> 3;
            int cb = (chunk & 7) * 16;
            gload_lds16(Bbase + (size_t)row * ldb + (size_t)kt * 2 + cb, (char*)Bs + chunk * 16);
        }
        __syncthreads();
        bf16x8 af[4][2], bfv[4][2];
#pragma unroll
        for (int mf = 0; mf < 4; mf++)
#pragma unroll
            for (int ks = 0; ks < 2; ks++)
                af[mf][ks] = *(const bf16x8*)&As[(wr * 64 + mf * 16 + fr) * 64 + ks * 32 + fq * 8];
#pragma unroll
        for (int nf = 0; nf < 4; nf++)
#pragma unroll
            for (int ks = 0; ks < 2; ks++)
                bfv[nf][ks] = *(const bf16x8*)&Bs[(wc * 64 + nf * 16 + fr) * 64 + ks * 32 + fq * 8];
#pragma unroll
        for (int mf = 0; mf < 4; mf++)
#pragma unroll
            for (int nf = 0; nf < 4; nf++)
#pragma unroll
                for (int ks = 0; ks < 2; ks++)
                    acc[mf][nf] = __builtin_amdgcn_mfma_f32_16x16x32_bf16(af[mf][ks], bfv[nf][ks], acc[mf][nf], 0, 0, 0);
        __syncthreads();
    }
#pragma unroll
    for (int mf = 0; mf < 4; mf++) {
#pragma unroll
        for (int nf = 0; nf < 4; nf++) {
            int gn = bn * 128 + wc * 64 + nf * 16 + fr;
            float bi = bias[gn];
            int gm0 = bm * 128 + wr * 64 + mf * 16 + fq * 4;
#pragma unroll
            for (int r = 0; r < 4; r++) {
                float v = acc[mf][nf][r] + bi;
                if (RELU) v = fmaxf(v, 0.f);
                size_t o = (size_t)(gm0 + r) * N + gn;
                if (OBF16) ((u16*)Cg)[o] = f2bf(v);
                else ((float*)Cg)[o] = v;
            }
        }
    }
}

// ---------------------------------------------------------------------------
// GEMM2_FUSED: logits L = A @ W2^T + ab2 (M=rows, N=512, K=1024) with the
// softmax-over-k + weighted-V reduction fused into the epilogue.
// V tile (128 rows x 128 ch = 32 KB) is LDS-staged (coalesced) after the
// K-loop, reusing the As/Bs space, replacing 64 scattered 2B global loads
// per thread with LDS reads.
// ---------------------------------------------------------------------------
__global__ __launch_bounds__(256) void gemm2_fused(const u16* __restrict__ Ag, const u16* __restrict__ Bg,
                                                   const float* __restrict__ bias, const u16* __restrict__ Vb,
                                                   float* __restrict__ out, int row0, int Kd) {
    __shared__ u16 smem[128 * 128];  // As (16KB) + Bs (16KB); reused as V tile
    u16* As = smem;
    u16* Bs = smem + 128 * 64;
    const int t = threadIdx.x;
    u32 bmu, bnu;
    xcd_tiles(bmu, bnu);
    const int bm = (int)bmu, bn = (int)bnu;
    const int w = t >> 6, l = t & 63;
    const int wr = w >> 1, wc = w & 1;
    const int fr = l & 15, fq = l >> 4;
    f32x4 acc[4][4];
#pragma unroll
    for (int i = 0; i < 4; i++)
#pragma unroll
        for (int j = 0; j < 4; j++) {
            f32x4 z = {0.f, 0.f, 0.f, 0.f};
            acc[i][j] = z;
        }
    const char* Abase = (const char*)Ag + (size_t)bm * 128 * (size_t)Kd * 2;
    const char* Bbase = (const char*)Bg + (size_t)bn * 128 * (size_t)Kd * 2;
    const size_t ldb = (size_t)Kd * 2;

    for (int kt = 0; kt < Kd; kt += 64) {
#pragma unroll
        for (int i = 0; i < 4; i++) {
            int chunk = i * 256 + t;
            int row = chunk >> 3;
            int cb = (chunk & 7) * 16;
            gload_lds16(Abase + (size_t)row * ldb + (size_t)kt * 2 + cb, (char*)As + chunk * 16);
        }
#pragma unroll
        for (int i = 0; i < 4; i++) {
            int chunk = i * 256 + t;
            int row = chunk >> 3;
            int cb = (chunk & 7) * 16;
            gload_lds16(Bbase + (size_t)row * ldb + (size_t)kt * 2 + cb, (char*)Bs + chunk * 16);
        }
        __syncthreads();
        bf16x8 af[4][2], bfv[4][2];
#pragma unroll
        for (int mf = 0; mf < 4; mf++)
#pragma unroll
            for (int ks = 0; ks < 2; ks++)
                af[mf][ks] = *(const bf16x8*)&As[(wr * 64 + mf * 16 + fr) * 64 + ks * 32 + fq * 8];
#pragma unroll
        for (int nf = 0; nf < 4; nf++)
#pragma unroll
            for (int ks = 0; ks < 2; ks++)
                bfv[nf][ks] = *(const bf16x8*)&Bs[(wc * 64 + nf * 16 + fr) * 64 + ks * 32 + fq * 8];
#pragma unroll
        for (int mf = 0; mf < 4; mf++)
#pragma unroll
            for (int nf = 0; nf < 4; nf++)
#pragma unroll
                for (int ks = 0; ks < 2; ks++)
                    acc[mf][nf] = __builtin_amdgcn_mfma_f32_16x16x32_bf16(af[mf][ks], bfv[nf][ks], acc[mf][nf], 0, 0, 0);
        __syncthreads();
    }
    // stage V tile [bm*128 .. +128)[bn*128 .. +128) into LDS (coalesced)
    const char* Vbase = (const char*)Vb + (size_t)bm * 128 * Cc * 2 + (size_t)bn * 256;
#pragma unroll
    for (int i = 0; i < 8; i++) {
        int chunk = i * 256 + t;       // 0..2047
        int row = chunk >> 4;          // 0..127
        int cb = (chunk & 15) * 16;    // byte offset in row (256B rows)
        gload_lds16(Vbase + (size_t)row * (Cc * 2) + cb, (char*)smem + chunk * 16);
    }
    __syncthreads();
    // fused epilogue: per (point, channel) softmax over k=fq*4+r + V-reduce
#pragma unroll
    for (int mf = 0; mf < 4; mf++) {
        int lp = bm * 8 + wr * 4 + mf;        // chunk-local point
        int gp = row0 / 16 + lp;              // global point
        int bb = gp >> 11, nn = gp & (Nc - 1);
        int vrow = (wr * 4 + mf) * 16 + fq * 4;  // tile-local V row for r=0
#pragma unroll
        for (int nf = 0; nf < 4; nf++) {
            int gn = bn * 128 + wc * 64 + nf * 16 + fr;
            int vch = wc * 64 + nf * 16 + fr;
            float bi = bias[gn];
            float v0 = acc[mf][nf][0] + bi, v1 = acc[mf][nf][1] + bi;
            float v2 = acc[mf][nf][2] + bi, v3 = acc[mf][nf][3] + bi;
            float mx = fmaxf(fmaxf(v0, v1), fmaxf(v2, v3));
            mx = fmaxf(mx, __shfl_xor(mx, 16));
            mx = fmaxf(mx, __shfl_xor(mx, 32));
            float e0 = __expf(v0 - mx), e1 = __expf(v1 - mx);
            float e2 = __expf(v2 - mx), e3 = __expf(v3 - mx);
            float ws = e0 * bf2f(smem[(size_t)vrow * 128 + vch])
                     + e1 * bf2f(smem[(size_t)(vrow + 1) * 128 + vch])
                     + e2 * bf2f(smem[(size_t)(vrow + 2) * 128 + vch])
                     + e3 * bf2f(smem[(size_t)(vrow + 3) * 128 + vch]);
            float es = e0 + e1 + e2 + e3;
            ws += __shfl_xor(ws, 16); ws += __shfl_xor(ws, 32);
            es += __shfl_xor(es, 16); es += __shfl_xor(es, 32);
            if (fq == 0) out[((size_t)bb * Cc + gn) * Nc + nn] = ws / es;
        }
    }
}

// ---------------------------------------------------------------------------
extern "C" void kernel_launch(void* const* d_in, const int* in_sizes, int n_in,
                              void* d_out, int out_size, void* d_ws, size_t ws_size,
                              hipStream_t stream) {
    (void)in_sizes; (void)n_in; (void)out_size;
    const float* pcd     = (const float*)d_in[0];
    const float* feat    = (const float*)d_in[1];
    const float* pcd_db  = (const float*)d_in[2];
    const float* feat_db = (const float*)d_in[3];
    const float* pw1 = (const float*)d_in[4];
    const float* pb1 = (const float*)d_in[5];
    const float* pg  = (const float*)d_in[6];
    const float* pbb = (const float*)d_in[7];
    const float* pm  = (const float*)d_in[8];
    const float* pv  = (const float*)d_in[9];
    const float* pw2 = (const float*)d_in[10];
    const float* pb2 = (const float*)d_in[11];
    const float* aw1 = (const float*)d_in[12];
    const float* ab1 = (const float*)d_in[13];
    const float* ag  = (const float*)d_in[14];
    const float* abb = (const float*)d_in[15];
    const float* am  = (const float*)d_in[16];
    const float* av  = (const float*)d_in[17];
    const float* aw2 = (const float*)d_in[18];
    const float* ab2 = (const float*)d_in[19];
    float* out = (float*)d_out;

    char* base = (char*)d_ws;
    size_t off = 0;
    auto alloc = [&](size_t bytes) -> char* {
        char* r = base + off;
        off = (off + bytes + 255) & ~(size_t)255;
        return r;
    };
    int*   idxb  = (int*)alloc((size_t)RT * 4);
    float* featT = (float*)alloc((size_t)Bc * Sc * Cc * 4);
    u16*   W1b   = (u16*)alloc((size_t)AH * Cc * 2);
    float* bias1 = (float*)alloc((size_t)AH * 4);
    u16*   W2b   = (u16*)alloc((size_t)Cc * AH * 2);
    u16*   PW2b  = (u16*)alloc((size_t)Cc * PH * 2);
    u16*   Hb    = (u16*)alloc((size_t)RT * PH * 2);

    // chunked row pipeline: cap chunk at 16384 rows so Xb+Vb+Ab (~64 MB)
    // stays L3-resident between producer/consumer kernels.
    const size_t perrow = 1024 + 1024 + 2048;  // X,V bf16 + A bf16 (L fused away)
    int cr = 16384;
    size_t avail = ws_size > off ? ws_size - off : 0;
    if (avail < (size_t)cr * perrow) {
        cr = (int)((avail / perrow) & ~(size_t)127);
        if (cr < 128) cr = 128;
    }
    u16*   Xb = (u16*)alloc((size_t)cr * Cc * 2);
    u16*   Vb = (u16*)alloc((size_t)cr * Cc * 2);
    u16*   Ab = (u16*)alloc((size_t)cr * AH * 2);

    transpose_kernel<<<dim3(Bc * 40 * 8), dim3(256), 0, stream>>>(feat, feat_db, featT);
    prep_kernel<<<dim3((AH * Cc) / 256), dim3(256), 0, stream>>>(aw1, ab1, ag, abb, am, av, aw2, pw2,
                                                                 W1b, bias1, W2b, PW2b);
    knn_kernel<<<dim3(Bc * Nc / 4), dim3(256), 0, stream>>>(pcd, pcd_db, idxb);
    hker<<<dim3(RT / 256), dim3(256), 0, stream>>>(pcd, pcd_db, idxb, pw1, pb1, pg, pbb, pm, pv, Hb);

    for (int r0 = 0; r0 < RT; r0 += cr) {
        int rows = (RT - r0 < cr) ? (RT - r0) : cr;
        pgemm_fused<<<dim3(rows / 128, Cc / 128), dim3(256), 0, stream>>>(Hb, PW2b, pb2, featT, idxb,
                                                                          Xb, Vb, r0);
        gemm_bt<true, true><<<dim3(rows / 128, AH / 128), dim3(256), 0, stream>>>(Xb, W1b, bias1, Ab, rows, AH, Cc);
        gemm2_fused<<<dim3(rows / 128, Cc / 128), dim3(256), 0, stream>>>(Ab, W2b, ab2, Vb, out, r0, AH);
    }
}

// Round 14
// 337.943 us; speedup vs baseline: 2.6434x; 1.0691x over previous
//
#include <hip/hip_runtime.h>

typedef unsigned short u16;
typedef unsigned int   u32;
typedef __attribute__((ext_vector_type(8))) short bf16x8;
typedef __attribute__((ext_vector_type(4))) float f32x4;
typedef __attribute__((ext_vector_type(4))) u32   u32x4;

// Problem constants
constexpr int Bc = 2, Cc = 512, Nc = 2048, Mc = 512, Sc = 2560, Kc = 16, PH = 64, AH = 1024;
constexpr int RT = Bc * Nc * Kc;  // 65536 rows (b,n,k)
constexpr float EPS = 1e-5f;

__device__ __forceinline__ u16 f2bf(float f) {
    u32 u = __float_as_uint(f);
    u32 r = (u + 0x7fffu + ((u >> 16) & 1u)) >> 16;  // RNE
    return (u16)r;
}
__device__ __forceinline__ float bf2f(u16 h) { return __uint_as_float(((u32)h) << 16); }

__device__ __forceinline__ void gload_lds16(const void* g, void* l) {
    __builtin_amdgcn_global_load_lds((const __attribute__((address_space(1))) u32*)g,
                                     (__attribute__((address_space(3))) u32*)l, 16, 0, 0);
}

// Bijective XCD-aware workgroup swizzle (m204 form): same-XCD wgs get a
// contiguous run of linear ids. With bn-fastest linearization this makes an
// XCD reuse one A-panel across all bn tiles (L2 locality).
__device__ __forceinline__ void xcd_tiles(u32& bm, u32& bn) {
    u32 gdx = gridDim.x, gdy = gridDim.y;
    u32 nwg = gdx * gdy;
    u32 wg = blockIdx.x + gdx * blockIdx.y;
    u32 q = nwg >> 3, r8 = nwg & 7;
    u32 xcd = wg & 7, loc = wg >> 3;
    u32 swz = (xcd < r8 ? xcd * (q + 1) : r8 * (q + 1) + (xcd - r8) * q) + loc;
    bn = swz % gdy;   // bn fastest within an XCD's contiguous run
    bm = swz / gdy;
}

// lex-min on (d, s): total order, associative -> tree order == scan order
__device__ __forceinline__ void lmin(float& da, int& sa, float db, int sb) {
    bool better = (db < da) || (db == da && sb < sa);
    da = better ? db : da;
    sa = better ? sb : sa;
}

// ---------------------------------------------------------------------------
// Transpose fusion_feat [B,C,S(split)] f32 -> featT [B,S,C] f32
// ---------------------------------------------------------------------------
__global__ __launch_bounds__(256) void transpose_kernel(const float* __restrict__ feat,
                                                        const float* __restrict__ feat_db,
                                                        float* __restrict__ featT) {
    __shared__ float tile[64][65];
    int bid = blockIdx.x;
    int b = bid / (40 * 8);
    int rem = bid - b * (40 * 8);
    int st = rem >> 3, ct = rem & 7;
    int t = threadIdx.x, lane = t & 63, g = t >> 6;
    int s0 = st * 64, c0 = ct * 64;
    const float* src;
    int sl0, stride;
    if (s0 < Nc) { src = feat + (size_t)b * Cc * Nc; sl0 = s0; stride = Nc; }
    else         { src = feat_db + (size_t)b * Cc * Mc; sl0 = s0 - Nc; stride = Mc; }
#pragma unroll
    for (int i = 0; i < 16; i++) {
        int cl = g * 16 + i;
        tile[cl][lane] = src[(size_t)(c0 + cl) * stride + sl0 + lane];
    }
    __syncthreads();
#pragma unroll
    for (int i = 0; i < 16; i++) {
        int sl = g * 16 + i;
        featT[((size_t)b * Sc + s0 + sl) * Cc + c0 + lane] = tile[lane][sl];
    }
}

// ---------------------------------------------------------------------------
// Weight prep: fold attn BN into W1/bias1, cast attn W1/W2 + pos W2 to bf16
// ---------------------------------------------------------------------------
__global__ __launch_bounds__(256) void prep_kernel(const float* __restrict__ aw1, const float* __restrict__ ab1,
                                                   const float* __restrict__ ag, const float* __restrict__ abb,
                                                   const float* __restrict__ am, const float* __restrict__ av,
                                                   const float* __restrict__ aw2, const float* __restrict__ pw2,
                                                   u16* __restrict__ W1b, float* __restrict__ bias1,
                                                   u16* __restrict__ W2b, u16* __restrict__ PW2b) {
    int i = blockIdx.x * 256 + threadIdx.x;  // grid covers 524288
    if (i < AH * Cc) {
        int o = i >> 9;
        float inv = ag[o] / sqrtf(av[o] + EPS);
        W1b[i] = f2bf(aw1[i] * inv);
    }
    if (i < AH) {
        float inv = ag[i] / sqrtf(av[i] + EPS);
        bias1[i] = ab1[i] * inv + abb[i] - am[i] * inv;
    }
    if (i < Cc * AH) W2b[i] = f2bf(aw2[i]);
    if (i < Cc * PH) PW2b[i] = f2bf(pw2[i]);
}

// ---------------------------------------------------------------------------
// KNN (v1 + tree-scan): one wave per query; distances mirror the reference
// decomposition qq + ss - 2*dot, no fma contraction; ties -> smaller index.
// ---------------------------------------------------------------------------
__global__ __launch_bounds__(256) void knn_kernel(const float* __restrict__ pcd,
                                                  const float* __restrict__ pcd_db,
                                                  int* __restrict__ idxout) {
    int t = threadIdx.x, w = t >> 6, l = t & 63;
    int q = blockIdx.x * 4 + w;  // 0..4095
    int b = q >> 11, n = q & (Nc - 1);
    const float* pc = pcd + (size_t)b * 3 * Nc;
    const float* pd = pcd_db + (size_t)b * 3 * Mc;
    float qx = pc[n], qy = pc[Nc + n], qz = pc[2 * Nc + n];
    float qq = __fadd_rn(__fadd_rn(__fmul_rn(qx, qx), __fmul_rn(qy, qy)), __fmul_rn(qz, qz));
    float dist[40];
#pragma unroll
    for (int j = 0; j < 40; j++) {
        int s = j * 64 + l;
        float sx, sy, sz;
        if (s < Nc) { sx = pc[s]; sy = pc[Nc + s]; sz = pc[2 * Nc + s]; }
        else { int ss = s - Nc; sx = pd[ss]; sy = pd[Mc + ss]; sz = pd[2 * Mc + ss]; }
        float ss2 = __fadd_rn(__fadd_rn(__fmul_rn(sx, sx), __fmul_rn(sy, sy)), __fmul_rn(sz, sz));
        float dt  = __fadd_rn(__fadd_rn(__fmul_rn(qx, sx), __fmul_rn(qy, sy)), __fmul_rn(qz, sz));
        dist[j] = __fsub_rn(__fadd_rn(qq, ss2), __fmul_rn(2.0f, dt));
    }
    for (int r = 0; r < 16; r++) {
        // tree lex-min over the 40 (dist[j], j*64+l) pairs
        float td[20];
        int   ts[20];
#pragma unroll
        for (int i = 0; i < 20; i++) {
            float d0 = dist[2 * i], d1 = dist[2 * i + 1];
            int s0 = (2 * i) * 64 + l, s1 = (2 * i + 1) * 64 + l;
            bool bt = (d1 < d0) || (d1 == d0 && s1 < s0);
            td[i] = bt ? d1 : d0;
            ts[i] = bt ? s1 : s0;
        }
#pragma unroll
        for (int i = 0; i < 10; i++) lmin(td[i], ts[i], td[i + 10], ts[i + 10]);
#pragma unroll
        for (int i = 0; i < 5; i++) lmin(td[i], ts[i], td[i + 5], ts[i + 5]);
        lmin(td[0], ts[0], td[3], ts[3]);
        lmin(td[1], ts[1], td[4], ts[4]);
        lmin(td[0], ts[0], td[2], ts[2]);
        lmin(td[0], ts[0], td[1], ts[1]);
        float bd = td[0];
        int   bs = ts[0];
        for (int off = 32; off; off >>= 1) {
            float od = __shfl_xor(bd, off);
            int   os = __shfl_xor(bs, off);
            bool better = (od < bd) || (od == bd && os < bs);
            bd = better ? od : bd;
            bs = better ? os : bs;
        }
        if (l == 0) idxout[q * 16 + r] = bs;
        int wj = bs >> 6, wl = bs & 63;
        if (l == wl) {
#pragma unroll
            for (int j = 0; j < 40; j++)
                if (j == wj) dist[j] = 1e30f;
        }
    }
}

// ---------------------------------------------------------------------------
// HKER: per row, pos-MLP layer-1: h[r][64] = relu(BN(W1 (q - s) + b1)) bf16
// ---------------------------------------------------------------------------
__global__ __launch_bounds__(256) void hker(const float* __restrict__ pcd, const float* __restrict__ pcd_db,
                                            const int* __restrict__ idxb,
                                            const float* __restrict__ pw1, const float* __restrict__ pb1,
                                            const float* __restrict__ pg, const float* __restrict__ pbb,
                                            const float* __restrict__ pm, const float* __restrict__ pv,
                                            u16* __restrict__ H) {
    __shared__ float W1s[64][4];
    int t = threadIdx.x;
    if (t < 64) {
        float inv = pg[t] / sqrtf(pv[t] + EPS);
        W1s[t][0] = pw1[t * 3 + 0] * inv;
        W1s[t][1] = pw1[t * 3 + 1] * inv;
        W1s[t][2] = pw1[t * 3 + 2] * inv;
        W1s[t][3] = pb1[t] * inv + pbb[t] - pm[t] * inv;
    }
    __syncthreads();
    int r = blockIdx.x * 256 + t;
    int b = r >> 15, n = (r >> 4) & (Nc - 1), s = idxb[r];
    const float* pc = pcd + (size_t)b * 3 * Nc;
    float qx = pc[n], qy = pc[Nc + n], qz = pc[2 * Nc + n];
    float sx, sy, sz;
    if (s < Nc) { sx = pc[s]; sy = pc[Nc + s]; sz = pc[2 * Nc + s]; }
    else {
        const float* pd = pcd_db + (size_t)b * 3 * Mc;
        int ss = s - Nc;
        sx = pd[ss]; sy = pd[Mc + ss]; sz = pd[2 * Mc + ss];
    }
    float dx = qx - sx, dy = qy - sy, dz = qz - sz;
    u16* hp = H + (size_t)r * 64;
#pragma unroll
    for (int u0 = 0; u0 < 64; u0 += 8) {
        u16 e[8];
#pragma unroll
        for (int j = 0; j < 8; j++) {
            int u = u0 + j;
            float hv = fmaxf(0.f, dx * W1s[u][0] + dy * W1s[u][1] + dz * W1s[u][2] + W1s[u][3]);
            e[j] = f2bf(hv);
        }
        u32x4 pk;
        pk.x = (u32)e[0] | ((u32)e[1] << 16); pk.y = (u32)e[2] | ((u32)e[3] << 16);
        pk.z = (u32)e[4] | ((u32)e[5] << 16); pk.w = (u32)e[6] | ((u32)e[7] << 16);
        *(u32x4*)(hp + u0) = pk;
    }
}

// ---------------------------------------------------------------------------
// PGEMM_FUSED: P = H @ PW2^T + pb2 via MFMA (M=rows, N=512, K=64), epilogue
// gathers f,g from featT and emits X = f-g+p, V = g+p (bf16).
// ---------------------------------------------------------------------------
__global__ __launch_bounds__(256) void pgemm_fused(const u16* __restrict__ Hg, const u16* __restrict__ Bg,
                                                   const float* __restrict__ pb2,
                                                   const float* __restrict__ featT, const int* __restrict__ idxb,
                                                   u16* __restrict__ X, u16* __restrict__ V, int row0) {
    __shared__ u16 As[128 * 64];
    __shared__ u16 Bs[128 * 64];
    const int t = threadIdx.x;
    u32 bmu, bnu;
    xcd_tiles(bmu, bnu);
    const int bm = (int)bmu, bn = (int)bnu;
    const int w = t >> 6, l = t & 63;
    const int wr = w >> 1, wc = w & 1;
    const int fr = l & 15, fq = l >> 4;
    f32x4 acc[4][4];
#pragma unroll
    for (int i = 0; i < 4; i++)
#pragma unroll
        for (int j = 0; j < 4; j++) {
            f32x4 z = {0.f, 0.f, 0.f, 0.f};
            acc[i][j] = z;
        }
    const char* Abase = (const char*)Hg + ((size_t)row0 + (size_t)bm * 128) * 64 * 2;
    const char* Bbase = (const char*)Bg + (size_t)bn * 128 * 64 * 2;
#pragma unroll
    for (int i = 0; i < 4; i++) {
        int chunk = i * 256 + t;
        int row = chunk >> 3;
        int cb = (chunk & 7) * 16;
        gload_lds16(Abase + (size_t)row * 128 + cb, (char*)As + chunk * 16);
    }
#pragma unroll
    for (int i = 0; i < 4; i++) {
        int chunk = i * 256 + t;
        int row = chunk >> 3;
        int cb = (chunk & 7) * 16;
        gload_lds16(Bbase + (size_t)row * 128 + cb, (char*)Bs + chunk * 16);
    }
    __syncthreads();
    bf16x8 af[4][2], bfv[4][2];
#pragma unroll
    for (int mf = 0; mf < 4; mf++)
#pragma unroll
        for (int ks = 0; ks < 2; ks++)
            af[mf][ks] = *(const bf16x8*)&As[(wr * 64 + mf * 16 + fr) * 64 + ks * 32 + fq * 8];
#pragma unroll
    for (int nf = 0; nf < 4; nf++)
#pragma unroll
        for (int ks = 0; ks < 2; ks++)
            bfv[nf][ks] = *(const bf16x8*)&Bs[(wc * 64 + nf * 16 + fr) * 64 + ks * 32 + fq * 8];
#pragma unroll
    for (int mf = 0; mf < 4; mf++)
#pragma unroll
        for (int nf = 0; nf < 4; nf++)
#pragma unroll
            for (int ks = 0; ks < 2; ks++)
                acc[mf][nf] = __builtin_amdgcn_mfma_f32_16x16x32_bf16(af[mf][ks], bfv[nf][ks], acc[mf][nf], 0, 0, 0);
    // epilogue: per C-row gather f,g; emit X,V
#pragma unroll
    for (int mf = 0; mf < 4; mf++) {
#pragma unroll
        for (int r = 0; r < 4; r++) {
            int gr = bm * 128 + wr * 64 + mf * 16 + fq * 4 + r;  // chunk-local row
            int grow = row0 + gr;                                 // global row
            int b = grow >> 15;
            int n = (grow >> 4) & (Nc - 1);
            int s = idxb[grow];
            const float* frow = featT + ((size_t)b * Sc + n) * Cc;
            const float* grow_p = featT + ((size_t)b * Sc + s) * Cc;
#pragma unroll
            for (int nf = 0; nf < 4; nf++) {
                int gn = bn * 128 + wc * 64 + nf * 16 + fr;
                float p = acc[mf][nf][r] + pb2[gn];
                float fv = frow[gn];
                float gv = grow_p[gn];
                X[(size_t)gr * Cc + gn] = f2bf(fv - gv + p);
                V[(size_t)gr * Cc + gn] = f2bf(gv + p);
            }
        }
    }
}

// ---------------------------------------------------------------------------
// GEMM (m97 structure + XCD swizzle): C[m][n] = f(sum_k A[m][k]*B[n][k]+bias)
// A [M][Kd] bf16, B [N][Kd] bf16 (i.e. B^T layout), 128x128 tile, BK=64.
// ---------------------------------------------------------------------------
template <bool RELU, bool OBF16>
__global__ __launch_bounds__(256) void gemm_bt(const u16* __restrict__ Ag, const u16* __restrict__ Bg,
                                               const float* __restrict__ bias, void* __restrict__ Cg,
                                               int M, int N, int Kd) {
    __shared__ u16 As[128 * 64];
    __shared__ u16 Bs[128 * 64];
    const int t = threadIdx.x;
    u32 bmu, bnu;
    xcd_tiles(bmu, bnu);
    const int bm = (int)bmu, bn = (int)bnu;
    const int w = t >> 6, l = t & 63;
    const int wr = w >> 1, wc = w & 1;
    const int fr = l & 15, fq = l >> 4;
    f32x4 acc[4][4];
#pragma unroll
    for (int i = 0; i < 4; i++)
#pragma unroll
        for (int j = 0; j < 4; j++) {
            f32x4 z = {0.f, 0.f, 0.f, 0.f};
            acc[i][j] = z;
        }
    const char* Abase = (const char*)Ag + (size_t)bm * 128 * (size_t)Kd * 2;
    const char* Bbase = (const char*)Bg + (size_t)bn * 128 * (size_t)Kd * 2;
    const size_t ldb = (size_t)Kd * 2;

    for (int kt = 0; kt < Kd; kt += 64) {
#pragma unroll
        for (int i = 0; i < 4; i++) {
            int chunk = i * 256 + t;
            int row = chunk >> 3;
            int cb = (chunk & 7) * 16;
            gload_lds16(Abase + (size_t)row * ldb + (size_t)kt * 2 + cb, (char*)As + chunk * 16);
        }
#pragma unroll
        for (int i = 0; i < 4; i++) {
            int chunk = i * 256 + t;
            int row = chunk >> 3;
            int cb = (chunk & 7) * 16;
            gload_lds16(Bbase + (size_t)row * ldb + (size_t)kt * 2 + cb, (char*)Bs + chunk * 16);
        }
        __syncthreads();
        bf16x8 af[4][2], bfv[4][2];
#pragma unroll
        for (int mf = 0; mf < 4; mf++)
#pragma unroll
            for (int ks = 0; ks < 2; ks++)
                af[mf][ks] = *(const bf16x8*)&As[(wr * 64 + mf * 16 + fr) * 64 + ks * 32 + fq * 8];
#pragma unroll
        for (int nf = 0; nf < 4; nf++)
#pragma unroll
            for (int ks = 0; ks < 2; ks++)
                bfv[nf][ks] = *(const bf16x8*)&Bs[(wc * 64 + nf * 16 + fr) * 64 + ks * 32 + fq * 8];
#pragma unroll
        for (int mf = 0; mf < 4; mf++)
#pragma unroll
            for (int nf = 0; nf < 4; nf++)
#pragma unroll
                for (int ks = 0; ks < 2; ks++)
                    acc[mf][nf] = __builtin_amdgcn_mfma_f32_16x16x32_bf16(af[mf][ks], bfv[nf][ks], acc[mf][nf], 0, 0, 0);
        __syncthreads();
    }
#pragma unroll
    for (int mf = 0; mf < 4; mf++) {
#pragma unroll
        for (int nf = 0; nf < 4; nf++) {
            int gn = bn * 128 + wc * 64 + nf * 16 + fr;
            float bi = bias[gn];
            int gm0 = bm * 128 + wr * 64 + mf * 16 + fq * 4;
#pragma unroll
            for (int r = 0; r < 4; r++) {
                float v = acc[mf][nf][r] + bi;
                if (RELU) v = fmaxf(v, 0.f);
                size_t o = (size_t)(gm0 + r) * N + gn;
                if (OBF16) ((u16*)Cg)[o] = f2bf(v);
                else ((float*)Cg)[o] = v;
            }
        }
    }
}

// ---------------------------------------------------------------------------
// GEMM2_FUSED: logits L = A @ W2^T + ab2 (M=rows, N=512, K=1024) with the
// softmax-over-k + weighted-V reduction fused into the epilogue.
// V tile (128 rows x 128 ch = 32 KB) is LDS-staged (coalesced) after the
// K-loop, reusing the As/Bs space.
// ---------------------------------------------------------------------------
__global__ __launch_bounds__(256) void gemm2_fused(const u16* __restrict__ Ag, const u16* __restrict__ Bg,
                                                   const float* __restrict__ bias, const u16* __restrict__ Vb,
                                                   float* __restrict__ out, int row0, int Kd) {
    __shared__ u16 smem[128 * 128];  // As (16KB) + Bs (16KB); reused as V tile
    u16* As = smem;
    u16* Bs = smem + 128 * 64;
    const int t = threadIdx.x;
    u32 bmu, bnu;
    xcd_tiles(bmu, bnu);
    const int bm = (int)bmu, bn = (int)bnu;
    const int w = t >> 6, l = t & 63;
    const int wr = w >> 1, wc = w & 1;
    const int fr = l & 15, fq = l >> 4;
    f32x4 acc[4][4];
#pragma unroll
    for (int i = 0; i < 4; i++)
#pragma unroll
        for (int j = 0; j < 4; j++) {
            f32x4 z = {0.f, 0.f, 0.f, 0.f};
            acc[i][j] = z;
        }
    const char* Abase = (const char*)Ag + (size_t)bm * 128 * (size_t)Kd * 2;
    const char* Bbase = (const char*)Bg + (size_t)bn * 128 * (size_t)Kd * 2;
    const size_t ldb = (size_t)Kd * 2;

    for (int kt = 0; kt < Kd; kt += 64) {
#pragma unroll
        for (int i = 0; i < 4; i++) {
            int chunk = i * 256 + t;
            int row = chunk >> 3;
            int cb = (chunk & 7) * 16;
            gload_lds16(Abase + (size_t)row * ldb + (size_t)kt * 2 + cb, (char*)As + chunk * 16);
        }
#pragma unroll
        for (int i = 0; i < 4; i++) {
            int chunk = i * 256 + t;
            int row = chunk >> 3;
            int cb = (chunk & 7) * 16;
            gload_lds16(Bbase + (size_t)row * ldb + (size_t)kt * 2 + cb, (char*)Bs + chunk * 16);
        }
        __syncthreads();
        bf16x8 af[4][2], bfv[4][2];
#pragma unroll
        for (int mf = 0; mf < 4; mf++)
#pragma unroll
            for (int ks = 0; ks < 2; ks++)
                af[mf][ks] = *(const bf16x8*)&As[(wr * 64 + mf * 16 + fr) * 64 + ks * 32 + fq * 8];
#pragma unroll
        for (int nf = 0; nf < 4; nf++)
#pragma unroll
            for (int ks = 0; ks < 2; ks++)
                bfv[nf][ks] = *(const bf16x8*)&Bs[(wc * 64 + nf * 16 + fr) * 64 + ks * 32 + fq * 8];
#pragma unroll
        for (int mf = 0; mf < 4; mf++)
#pragma unroll
            for (int nf = 0; nf < 4; nf++)
#pragma unroll
                for (int ks = 0; ks < 2; ks++)
                    acc[mf][nf] = __builtin_amdgcn_mfma_f32_16x16x32_bf16(af[mf][ks], bfv[nf][ks], acc[mf][nf], 0, 0, 0);
        __syncthreads();
    }
    // stage V tile [bm*128 .. +128)[bn*128 .. +128) into LDS (coalesced)
    const char* Vbase = (const char*)Vb + (size_t)bm * 128 * Cc * 2 + (size_t)bn * 256;
#pragma unroll
    for (int i = 0; i < 8; i++) {
        int chunk = i * 256 + t;       // 0..2047
        int row = chunk >> 4;          // 0..127
        int cb = (chunk & 15) * 16;    // byte offset in row (256B rows)
        gload_lds16(Vbase + (size_t)row * (Cc * 2) + cb, (char*)smem + chunk * 16);
    }
    __syncthreads();
    // fused epilogue: per (point, channel) softmax over k=fq*4+r + V-reduce
#pragma unroll
    for (int mf = 0; mf < 4; mf++) {
        int lp = bm * 8 + wr * 4 + mf;        // chunk-local point
        int gp = row0 / 16 + lp;              // global point
        int bb = gp >> 11, nn = gp & (Nc - 1);
        int vrow = (wr * 4 + mf) * 16 + fq * 4;  // tile-local V row for r=0
#pragma unroll
        for (int nf = 0; nf < 4; nf++) {
            int gn = bn * 128 + wc * 64 + nf * 16 + fr;
            int vch = wc * 64 + nf * 16 + fr;
            float bi = bias[gn];
            float v0 = acc[mf][nf][0] + bi, v1 = acc[mf][nf][1] + bi;
            float v2 = acc[mf][nf][2] + bi, v3 = acc[mf][nf][3] + bi;
            float mx = fmaxf(fmaxf(v0, v1), fmaxf(v2, v3));
            mx = fmaxf(mx, __shfl_xor(mx, 16));
            mx = fmaxf(mx, __shfl_xor(mx, 32));
            float e0 = __expf(v0 - mx), e1 = __expf(v1 - mx);
            float e2 = __expf(v2 - mx), e3 = __expf(v3 - mx);
            float ws = e0 * bf2f(smem[(size_t)vrow * 128 + vch])
                     + e1 * bf2f(smem[(size_t)(vrow + 1) * 128 + vch])
                     + e2 * bf2f(smem[(size_t)(vrow + 2) * 128 + vch])
                     + e3 * bf2f(smem[(size_t)(vrow + 3) * 128 + vch]);
            float es = e0 + e1 + e2 + e3;
            ws += __shfl_xor(ws, 16); ws += __shfl_xor(ws, 32);
            es += __shfl_xor(es, 16); es += __shfl_xor(es, 32);
            if (fq == 0) out[((size_t)bb * Cc + gn) * Nc + nn] = ws / es;
        }
    }
}

// ---------------------------------------------------------------------------
extern "C" void kernel_launch(void* const* d_in, const int* in_sizes, int n_in,
                              void* d_out, int out_size, void* d_ws, size_t ws_size,
                              hipStream_t stream) {
    (void)in_sizes; (void)n_in; (void)out_size;
    const float* pcd     = (const float*)d_in[0];
    const float* feat    = (const float*)d_in[1];
    const float* pcd_db  = (const float*)d_in[2];
    const float* feat_db = (const float*)d_in[3];
    const float* pw1 = (const float*)d_in[4];
    const float* pb1 = (const float*)d_in[5];
    const float* pg  = (const float*)d_in[6];
    const float* pbb = (const float*)d_in[7];
    const float* pm  = (const float*)d_in[8];
    const float* pv  = (const float*)d_in[9];
    const float* pw2 = (const float*)d_in[10];
    const float* pb2 = (const float*)d_in[11];
    const float* aw1 = (const float*)d_in[12];
    const float* ab1 = (const float*)d_in[13];
    const float* ag  = (const float*)d_in[14];
    const float* abb = (const float*)d_in[15];
    const float* am  = (const float*)d_in[16];
    const float* av  = (const float*)d_in[17];
    const float* aw2 = (const float*)d_in[18];
    const float* ab2 = (const float*)d_in[19];
    float* out = (float*)d_out;

    char* base = (char*)d_ws;
    size_t off = 0;
    auto alloc = [&](size_t bytes) -> char* {
        char* r = base + off;
        off = (off + bytes + 255) & ~(size_t)255;
        return r;
    };
    int*   idxb  = (int*)alloc((size_t)RT * 4);
    float* featT = (float*)alloc((size_t)Bc * Sc * Cc * 4);
    u16*   W1b   = (u16*)alloc((size_t)AH * Cc * 2);
    float* bias1 = (float*)alloc((size_t)AH * 4);
    u16*   W2b   = (u16*)alloc((size_t)Cc * AH * 2);
    u16*   PW2b  = (u16*)alloc((size_t)Cc * PH * 2);
    u16*   Hb    = (u16*)alloc((size_t)RT * PH * 2);

    // chunked row pipeline: cr=32768 doubles per-dispatch grids (gemm2:
    // 512->1024 wgs = 4 blocks/CU) for latency hiding; Xb+Vb+Ab = 134 MB
    // + featT 20 MB still < 256 MB L3.
    const size_t perrow = 1024 + 1024 + 2048;  // X,V bf16 + A bf16
    int cr = 32768;
    size_t avail = ws_size > off ? ws_size - off : 0;
    if (avail < (size_t)cr * perrow) {
        cr = (int)((avail / perrow) & ~(size_t)127);
        if (cr < 128) cr = 128;
    }
    u16*   Xb = (u16*)alloc((size_t)cr * Cc * 2);
    u16*   Vb = (u16*)alloc((size_t)cr * Cc * 2);
    u16*   Ab = (u16*)alloc((size_t)cr * AH * 2);

    transpose_kernel<<<dim3(Bc * 40 * 8), dim3(256), 0, stream>>>(feat, feat_db, featT);
    prep_kernel<<<dim3((AH * Cc) / 256), dim3(256), 0, stream>>>(aw1, ab1, ag, abb, am, av, aw2, pw2,
                                                                 W1b, bias1, W2b, PW2b);
    knn_kernel<<<dim3(Bc * Nc / 4), dim3(256), 0, stream>>>(pcd, pcd_db, idxb);
    hker<<<dim3(RT / 256), dim3(256), 0, stream>>>(pcd, pcd_db, idxb, pw1, pb1, pg, pbb, pm, pv, Hb);

    for (int r0 = 0; r0 < RT; r0 += cr) {
        int rows = (RT - r0 < cr) ? (RT - r0) : cr;
        pgemm_fused<<<dim3(rows / 128, Cc / 128), dim3(256), 0, stream>>>(Hb, PW2b, pb2, featT, idxb,
                                                                          Xb, Vb, r0);
        gemm_bt<true, true><<<dim3(rows / 128, AH / 128), dim3(256), 0, stream>>>(Xb, W1b, bias1, Ab, rows, AH, Cc);
        gemm2_fused<<<dim3(rows / 128, Cc / 128), dim3(256), 0, stream>>>(Ab, W2b, ab2, Vb, out, r0, AH);
    }
}